// Round 1
// baseline (454.344 us; speedup 1.0000x reference)
//
#include <hip/hip_runtime.h>
#include <hip/hip_bf16.h>

#define L_ 2048
#define B_ 2
#define E_ 1024
#define H_ 16
#define HD_ 64
#define TOPK_ 64
#define MROWS (B_*L_)
#define SCALE 0.125f

typedef __attribute__((ext_vector_type(8))) short short8;
typedef __attribute__((ext_vector_type(4))) short short4v;
typedef __attribute__((ext_vector_type(4))) float f32x4;

static __device__ __forceinline__ short f2bf(float f) {
    __hip_bfloat16 h = __float2bfloat16(f);
    return *reinterpret_cast<short*>(&h);
}

// ---- transpose [L,B,E] f32 -> [B,L,E] bf16 ----
__global__ void k_prep_x(const float* __restrict__ q, short* __restrict__ xb) {
    int i = blockIdx.x * 256 + threadIdx.x;
    int idx = i * 4;
    int e = idx & (E_ - 1);
    int l = (idx >> 10) & (L_ - 1);
    int b = idx >> 21;
    float4 v = *reinterpret_cast<const float4*>(q + l * (B_ * E_) + b * E_ + e);
    short4v o;
    o[0] = f2bf(v.x); o[1] = f2bf(v.y); o[2] = f2bf(v.z); o[3] = f2bf(v.w);
    *reinterpret_cast<short4v*>(xb + idx) = o;
}

// ---- cast f32 -> bf16 ----
__global__ void k_cast(const float* __restrict__ w, short* __restrict__ o) {
    int i = blockIdx.x * 256 + threadIdx.x;
    float4 v = *reinterpret_cast<const float4*>(w + i * 4);
    short4v s;
    s[0] = f2bf(v.x); s[1] = f2bf(v.y); s[2] = f2bf(v.z); s[3] = f2bf(v.w);
    *reinterpret_cast<short4v*>(o + i * 4) = s;
}

// ---- xsum[b][e] = sum_l query[l,b,e]  (f32 exact path) ----
__global__ void k_xsum(const float* __restrict__ q, float* __restrict__ xsum) {
    int t = blockIdx.x * 256 + threadIdx.x;  // 0..2047
    int b = t >> 10, e = t & 1023;
    float s = 0.f;
    for (int l = 0; l < L_; ++l) s += q[l * (B_ * E_) + b * E_ + e];
    xsum[t] = s;
}

// ---- GEMM: C[M,N] = A[M,K](bf16) * Bw[N,K](bf16)^T + bias ----
// MODE 0: C = f32 [M][E_].  MODE 1: out[l,b,e] = acc + bias + ident (o-proj epilogue)
template<int MODE>
__global__ __launch_bounds__(256) void k_gemm(const short* __restrict__ A,
                                              const short* __restrict__ Bw,
                                              const float* __restrict__ bias,
                                              float* __restrict__ C,
                                              const float* __restrict__ ident) {
    const int K = E_;
    __shared__ short As[128][40];  // +8 pad: 2-way bank conflict only (free)
    __shared__ short Bs[128][40];
    int tid = threadIdx.x;
    int lane = tid & 63;
    int wid = tid >> 6;
    int wr = wid >> 1, wc = wid & 1;
    int lrow = lane & 15;
    int kg = (lane >> 4) * 8;
    int mBase = blockIdx.y * 128;
    int nBase = blockIdx.x * 128;

    f32x4 acc[4][4];
#pragma unroll
    for (int i = 0; i < 4; ++i)
#pragma unroll
        for (int j = 0; j < 4; ++j) acc[i][j] = (f32x4){0.f, 0.f, 0.f, 0.f};

    for (int k0 = 0; k0 < K; k0 += 32) {
        __syncthreads();
#pragma unroll
        for (int it = 0; it < 2; ++it) {
            int idx = tid + it * 256;
            int r = idx >> 2, c = (idx & 3) * 8;
            *reinterpret_cast<short8*>(&As[r][c]) =
                *reinterpret_cast<const short8*>(&A[(size_t)(mBase + r) * K + k0 + c]);
            *reinterpret_cast<short8*>(&Bs[r][c]) =
                *reinterpret_cast<const short8*>(&Bw[(size_t)(nBase + r) * K + k0 + c]);
        }
        __syncthreads();
        short8 af[4], bfr[4];
#pragma unroll
        for (int mi = 0; mi < 4; ++mi)
            af[mi] = *reinterpret_cast<const short8*>(&As[wr * 64 + mi * 16 + lrow][kg]);
#pragma unroll
        for (int ni = 0; ni < 4; ++ni)
            bfr[ni] = *reinterpret_cast<const short8*>(&Bs[wc * 64 + ni * 16 + lrow][kg]);
#pragma unroll
        for (int mi = 0; mi < 4; ++mi)
#pragma unroll
            for (int ni = 0; ni < 4; ++ni)
                acc[mi][ni] = __builtin_amdgcn_mfma_f32_16x16x32_bf16(af[mi], bfr[ni], acc[mi][ni], 0, 0, 0);
    }

    int rowq = (lane >> 4) * 4;
    int coll = lane & 15;
#pragma unroll
    for (int mi = 0; mi < 4; ++mi) {
#pragma unroll
        for (int ni = 0; ni < 4; ++ni) {
            int col = nBase + wc * 64 + ni * 16 + coll;
            float bv = bias[col];
#pragma unroll
            for (int r = 0; r < 4; ++r) {
                int row = mBase + wr * 64 + mi * 16 + rowq + r;
                float v = acc[mi][ni][r] + bv;
                if (MODE == 0) {
                    C[(size_t)row * E_ + col] = v;
                } else {
                    int b = row >> 11, l = row & (L_ - 1);
                    size_t oi = (size_t)l * (B_ * E_) + b * E_ + col;
                    C[oi] = v + ident[oi];
                }
            }
        }
    }
}

// ---- qsum[b][f] = xsum[b]. dot q_w[f] + L*q_b[f]  (f32 exact) ----
__global__ void k_qsum(const float* __restrict__ xsum, const float* __restrict__ qw,
                       const float* __restrict__ qb, float* __restrict__ qsum) {
    int wid = threadIdx.x >> 6, lane = threadIdx.x & 63;
    int gid = blockIdx.x * 4 + wid;  // 0..2047
    int b = gid >> 10, f = gid & 1023;
    float s = 0.f;
    for (int e = lane; e < E_; e += 64) s += xsum[b * E_ + e] * qw[f * E_ + e];
#pragma unroll
    for (int off = 32; off; off >>= 1) s += __shfl_xor(s, off);
    if (lane == 0) qsum[gid] = s + (float)L_ * qb[f];
}

// ---- t[b,h,e] = sum_d qsum[b,h*64+d] * k_w[h*64+d, e] ----
__global__ void k_t(const float* __restrict__ qsum, const float* __restrict__ kw,
                    float* __restrict__ tb) {
    int i = blockIdx.x * 256 + threadIdx.x;  // 0..32767
    int e = i & 1023, bh = i >> 10;
    int b = bh >> 4, h = bh & 15;
    float s = 0.f;
#pragma unroll
    for (int d = 0; d < HD_; ++d)
        s += qsum[b * E_ + h * HD_ + d] * kw[(size_t)(h * HD_ + d) * E_ + e];
    tb[i] = s;
}

// ---- score[b,h,n] = scale * x[b,n,:].t[b,h,:]  (f32 exact) ----
__global__ void k_score(const float* __restrict__ query, const float* __restrict__ tb,
                        float* __restrict__ score) {
    int wid = threadIdx.x >> 6, lane = threadIdx.x & 63;
    int gid = blockIdx.x * 4 + wid;  // 0..65535
    int bh = gid >> 11, n = gid & 2047;
    int b = bh >> 4;
    float s = 0.f;
    for (int e = lane; e < E_; e += 64)
        s += query[(size_t)n * (B_ * E_) + b * E_ + e] * tb[bh * E_ + e];
#pragma unroll
    for (int off = 32; off; off >>= 1) s += __shfl_xor(s, off);
    if (lane == 0) score[bh * L_ + n] = SCALE * s;
}

// ---- top-64 per (b,h) by iterative argmax, then gather selected k rows ----
__global__ __launch_bounds__(256) void k_topk(const float* __restrict__ score,
                                              const float* __restrict__ kf,
                                              float* __restrict__ selk) {
    __shared__ float sc[L_];
    __shared__ float rv[256];
    __shared__ int ri[256];
    __shared__ int sel[TOPK_];
    int bh = blockIdx.x;
    int b = bh >> 4, h = bh & 15;
    int tid = threadIdx.x;
    for (int j = tid; j < L_; j += 256) sc[j] = score[bh * L_ + j];
    __syncthreads();
    for (int it = 0; it < TOPK_; ++it) {
        float best = -INFINITY;
        int bi = 0x7fffffff;
        for (int j = tid; j < L_; j += 256) {
            float v = sc[j];
            if (v > best) { best = v; bi = j; }
        }
        rv[tid] = best; ri[tid] = bi;
        __syncthreads();
        for (int off = 128; off; off >>= 1) {
            if (tid < off) {
                if (rv[tid + off] > rv[tid] ||
                    (rv[tid + off] == rv[tid] && ri[tid + off] < ri[tid])) {
                    rv[tid] = rv[tid + off]; ri[tid] = ri[tid + off];
                }
            }
            __syncthreads();
        }
        if (tid == 0) { sel[it] = ri[0]; sc[ri[0]] = -INFINITY; }
        __syncthreads();
    }
    for (int j = tid; j < TOPK_ * HD_; j += 256) {
        int m = j >> 6, d = j & 63;
        selk[((size_t)bh * TOPK_ + m) * HD_ + d] = kf[((size_t)b * L_ + sel[m]) * E_ + h * HD_ + d];
    }
}

// ---- sim[b,h,l,m] = softmax_m(scale * X[b,l,h*64+:].selk[b,h,m,:]) ----
__global__ __launch_bounds__(256) void k_sim(const float* __restrict__ X,
                                             const float* __restrict__ selk,
                                             float* __restrict__ sim) {
    __shared__ float xl[64][65];
    __shared__ float sk[64][65];
    int bh = blockIdx.x >> 5;
    int l0 = (blockIdx.x & 31) * 64;
    int b = bh >> 4, h = bh & 15;
    int tid = threadIdx.x;
    for (int j = tid; j < 64 * 64; j += 256) {
        int i = j >> 6, d = j & 63;
        xl[i][d] = X[((size_t)b * L_ + l0 + i) * E_ + h * HD_ + d];
        sk[i][d] = selk[((size_t)bh * TOPK_ + i) * HD_ + d];
    }
    __syncthreads();
    int wid = tid >> 6, m = tid & 63;
    for (int i = wid * 16; i < wid * 16 + 16; ++i) {
        float s = 0.f;
#pragma unroll
        for (int d = 0; d < 64; ++d) s += xl[i][d] * sk[m][d];
        s *= SCALE;
        float mx = s;
#pragma unroll
        for (int off = 32; off; off >>= 1) mx = fmaxf(mx, __shfl_xor(mx, off));
        float e = __expf(s - mx);
        float sum = e;
#pragma unroll
        for (int off = 32; off; off >>= 1) sum += __shfl_xor(sum, off);
        sim[((size_t)bh * L_ + l0 + i) * TOPK_ + m] = e / sum;
    }
}

// ---- wpart[ch,bh,m,d] = sum_{l in chunk} sim_km[l,m] * v[l,d] ----
__global__ __launch_bounds__(256) void k_wpart(const float* __restrict__ simkm,
                                               const float* __restrict__ vf,
                                               float* __restrict__ wpart) {
    __shared__ float km[16][64];
    __shared__ float vv[16][64];
    int bh = blockIdx.x & 31;
    int ch = blockIdx.x >> 5;
    int b = bh >> 4, h = bh & 15;
    int tid = threadIdx.x;
    int d = tid & 63, mg = (tid >> 6) * 16;
    float acc[16];
#pragma unroll
    for (int j = 0; j < 16; ++j) acc[j] = 0.f;
    for (int l0 = ch * 256; l0 < ch * 256 + 256; l0 += 16) {
        __syncthreads();
        for (int j = tid; j < 1024; j += 256) {
            int i = j >> 6, c = j & 63;
            km[i][c] = simkm[((size_t)bh * L_ + l0 + i) * TOPK_ + c];
            vv[i][c] = vf[((size_t)b * L_ + l0 + i) * E_ + h * HD_ + c];
        }
        __syncthreads();
#pragma unroll
        for (int i = 0; i < 16; ++i) {
            float vx = vv[i][d];
#pragma unroll
            for (int j = 0; j < 16; ++j) acc[j] += km[i][mg + j] * vx;
        }
    }
#pragma unroll
    for (int j = 0; j < 16; ++j)
        wpart[(((size_t)ch * 32 + bh) * TOPK_ + mg + j) * HD_ + d] = acc[j];
}

__global__ void k_wreduce(const float* __restrict__ wpart, float* __restrict__ W) {
    int i = blockIdx.x * 256 + threadIdx.x;  // 0..131071
    float s = 0.f;
#pragma unroll
    for (int c = 0; c < 8; ++c) s += wpart[(size_t)c * 131072 + i];
    W[i] = s;
}

// ---- att[b,l,h*64+d] = sum_m sim_qn[l,m] * W[m,d]  -> bf16 for o-proj ----
__global__ __launch_bounds__(256) void k_outhead(const float* __restrict__ simqn,
                                                 const float* __restrict__ W,
                                                 short* __restrict__ att) {
    __shared__ float Wl[64][65];
    __shared__ float qn[32][65];
    int bh = blockIdx.x >> 6;
    int l0 = (blockIdx.x & 63) * 32;
    int b = bh >> 4, h = bh & 15;
    int tid = threadIdx.x;
    for (int j = tid; j < 4096; j += 256) { int m = j >> 6, d = j & 63; Wl[m][d] = W[(size_t)bh * 4096 + j]; }
    for (int j = tid; j < 2048; j += 256) { int i = j >> 6, m = j & 63; qn[i][m] = simqn[((size_t)bh * L_ + l0 + i) * TOPK_ + m]; }
    __syncthreads();
    int d = tid & 63;
    int i0 = tid >> 6;
    for (int i = i0; i < 32; i += 4) {
        float s = 0.f;
#pragma unroll
        for (int m = 0; m < 64; ++m) s += qn[i][m] * Wl[m][d];
        att[((size_t)b * L_ + l0 + i) * E_ + h * HD_ + d] = f2bf(s);
    }
}

extern "C" void kernel_launch(void* const* d_in, const int* in_sizes, int n_in,
                              void* d_out, int out_size, void* d_ws, size_t ws_size,
                              hipStream_t stream) {
    const float* query = (const float*)d_in[0];
    const float* q_w = (const float*)d_in[1];
    const float* q_b = (const float*)d_in[2];
    const float* k_w = (const float*)d_in[3];
    const float* k_b = (const float*)d_in[4];
    const float* v_w = (const float*)d_in[5];
    const float* v_b = (const float*)d_in[6];
    const float* o_w = (const float*)d_in[7];
    const float* o_b = (const float*)d_in[8];
    float* out = (float*)d_out;

    char* p = (char*)d_ws;
    auto alloc = [&](size_t bytes) {
        char* r = p;
        p += (bytes + 255) & ~(size_t)255;
        return r;
    };
    short* xb   = (short*)alloc((size_t)MROWS * E_ * 2);
    short* qwb  = (short*)alloc((size_t)E_ * E_ * 2);
    short* kwb  = (short*)alloc((size_t)E_ * E_ * 2);
    short* vwb  = (short*)alloc((size_t)E_ * E_ * 2);
    short* owb  = (short*)alloc((size_t)E_ * E_ * 2);
    float* qf   = (float*)alloc((size_t)MROWS * E_ * 4);
    float* kf   = (float*)alloc((size_t)MROWS * E_ * 4);
    float* vf   = (float*)alloc((size_t)MROWS * E_ * 4);
    float* xsum = (float*)alloc((size_t)B_ * E_ * 4);
    float* qsum = (float*)alloc((size_t)B_ * E_ * 4);
    float* tb   = (float*)alloc((size_t)B_ * H_ * E_ * 4);
    float* scor = (float*)alloc((size_t)B_ * H_ * L_ * 4);
    float* selk = (float*)alloc((size_t)B_ * H_ * TOPK_ * HD_ * 4);
    float* sqn  = (float*)alloc((size_t)B_ * H_ * L_ * TOPK_ * 4);
    float* skm  = (float*)alloc((size_t)B_ * H_ * L_ * TOPK_ * 4);
    float* wpart = (float*)alloc((size_t)8 * 32 * TOPK_ * HD_ * 4);
    float* Wb   = (float*)alloc((size_t)32 * TOPK_ * HD_ * 4);
    short* att  = (short*)alloc((size_t)MROWS * E_ * 2);

    // stage 1: casts / transpose / exact sums
    k_prep_x<<<4096, 256, 0, stream>>>(query, xb);
    k_cast<<<1024, 256, 0, stream>>>(q_w, qwb);
    k_cast<<<1024, 256, 0, stream>>>(k_w, kwb);
    k_cast<<<1024, 256, 0, stream>>>(v_w, vwb);
    k_cast<<<1024, 256, 0, stream>>>(o_w, owb);
    k_xsum<<<8, 256, 0, stream>>>(query, xsum);

    // stage 2: the three projections (bf16 MFMA)
    dim3 gg(E_ / 128, MROWS / 128);
    k_gemm<0><<<gg, 256, 0, stream>>>(xb, qwb, q_b, qf, nullptr);
    k_gemm<0><<<gg, 256, 0, stream>>>(xb, kwb, k_b, kf, nullptr);
    k_gemm<0><<<gg, 256, 0, stream>>>(xb, vwb, v_b, vf, nullptr);

    // stage 3: exact f32 scores + top-k selection
    k_qsum<<<512, 256, 0, stream>>>(xsum, q_w, q_b, qsum);
    k_t<<<128, 256, 0, stream>>>(qsum, k_w, tb);
    k_score<<<16384, 256, 0, stream>>>(query, tb, scor);
    k_topk<<<32, 256, 0, stream>>>(scor, kf, selk);

    // stage 4: softmaxes, W = sim_km^T v, out_head = sim_qn W
    k_sim<<<1024, 256, 0, stream>>>(qf, selk, sqn);
    k_sim<<<1024, 256, 0, stream>>>(kf, selk, skm);
    k_wpart<<<256, 256, 0, stream>>>(skm, vf, wpart);
    k_wreduce<<<512, 256, 0, stream>>>(wpart, Wb);
    k_outhead<<<2048, 256, 0, stream>>>(sqn, Wb, att);

    // stage 5: o-projection fused with bias + residual + transpose back
    k_gemm<1><<<gg, 256, 0, stream>>>(att, owb, o_b, out, query);
}

// Round 2
// 335.098 us; speedup vs baseline: 1.3559x; 1.3559x over previous
//
#include <hip/hip_runtime.h>
#include <hip/hip_bf16.h>

#define L_ 2048
#define B_ 2
#define E_ 1024
#define H_ 16
#define HD_ 64
#define TOPK_ 64
#define MROWS (B_*L_)
#define SCALE 0.125f

typedef __attribute__((ext_vector_type(8))) short short8;
typedef __attribute__((ext_vector_type(4))) short short4v;
typedef __attribute__((ext_vector_type(4))) float f32x4;

static __device__ __forceinline__ short f2bf(float f) {
    __hip_bfloat16 h = __float2bfloat16(f);
    return *reinterpret_cast<short*>(&h);
}

// ---- transpose [L,B,E] f32 -> [B,L,E] bf16 ----
__global__ void k_prep_x(const float* __restrict__ q, short* __restrict__ xb) {
    int i = blockIdx.x * 256 + threadIdx.x;
    int idx = i * 4;
    int e = idx & (E_ - 1);
    int l = (idx >> 10) & (L_ - 1);
    int b = idx >> 21;
    float4 v = *reinterpret_cast<const float4*>(q + l * (B_ * E_) + b * E_ + e);
    short4v o;
    o[0] = f2bf(v.x); o[1] = f2bf(v.y); o[2] = f2bf(v.z); o[3] = f2bf(v.w);
    *reinterpret_cast<short4v*>(xb + idx) = o;
}

// ---- cast all 4 weight matrices f32 -> bf16 in one dispatch ----
__global__ void k_castw(const float* __restrict__ w0, const float* __restrict__ w1,
                        const float* __restrict__ w2, const float* __restrict__ w3,
                        short* __restrict__ o0, short* __restrict__ o1,
                        short* __restrict__ o2, short* __restrict__ o3) {
    int blk = blockIdx.x & 1023, sel = blockIdx.x >> 10;
    const float* w = sel == 0 ? w0 : sel == 1 ? w1 : sel == 2 ? w2 : w3;
    short* o = sel == 0 ? o0 : sel == 1 ? o1 : sel == 2 ? o2 : o3;
    int i = blk * 256 + threadIdx.x;
    float4 v = *reinterpret_cast<const float4*>(w + i * 4);
    short4v s;
    s[0] = f2bf(v.x); s[1] = f2bf(v.y); s[2] = f2bf(v.z); s[3] = f2bf(v.w);
    *reinterpret_cast<short4v*>(o + i * 4) = s;
}

// ---- xpart[ch][col] = sum over 128 l of query[l*2048 + col]  (col = b*E+e) ----
__global__ void k_xsum(const float* __restrict__ q, float* __restrict__ xpart) {
    int cg = blockIdx.x & 7, ch = blockIdx.x >> 3;  // grid 128
    int col = cg * 256 + threadIdx.x;
    float s = 0.f;
    for (int l = ch * 128; l < (ch + 1) * 128; ++l) s += q[(size_t)l * (B_ * E_) + col];
    xpart[ch * (B_ * E_) + col] = s;
}
__global__ void k_xred(const float* __restrict__ xpart, float* __restrict__ xsum) {
    int col = blockIdx.x * 256 + threadIdx.x;  // grid 8
    float s = 0.f;
#pragma unroll
    for (int c = 0; c < 16; ++c) s += xpart[c * (B_ * E_) + col];
    xsum[col] = s;
}

// ---- GEMM core: C[M,N] = A[M,K](bf16) * Bw[N,K](bf16)^T + bias ----
// m97 structure: BK=64, global_load_lds width 16, linear LDS, ds_read_b128 frags.
// MODE 0: C = f32 [M][E_].  MODE 1: out[l,b,e] = acc + bias + ident.
template<int MODE, int BM, int BN>
__device__ __forceinline__ void gemm_body(const short* __restrict__ A,
                                          const short* __restrict__ Bw,
                                          const float* __restrict__ bias,
                                          float* __restrict__ C,
                                          const float* __restrict__ ident,
                                          int bx, int by) {
    const int K = E_;
    constexpr int MI = BM / 32;  // wave tile = (BM/2) x (BN/2), frags 16x16
    constexpr int NI = BN / 32;
    __shared__ short As[BM * 64];
    __shared__ short Bs[BN * 64];
    int tid = threadIdx.x;
    int lane = tid & 63;
    int wid = tid >> 6;
    int wr = wid >> 1, wc = wid & 1;
    int lrow = lane & 15;
    int kg = lane >> 4;          // 0..3
    int lr8 = lane >> 3;         // row within 8-row chunk
    int lc8 = (lane & 7) * 8;    // col (elements) within row
    int mBase = by * BM, nBase = bx * BN;

    f32x4 acc[MI][NI];
#pragma unroll
    for (int i = 0; i < MI; ++i)
#pragma unroll
        for (int j = 0; j < NI; ++j) acc[i][j] = (f32x4){0.f, 0.f, 0.f, 0.f};

    for (int k0 = 0; k0 < K; k0 += 64) {
        __syncthreads();
        // stage A: BM/8 chunks of 8 rows x 64 cols (1KB); wave-uniform LDS base
#pragma unroll
        for (int i = 0; i < BM / 32; ++i) {
            int r0 = (wid * (BM / 32) + i) * 8;
            const short* ga = A + (size_t)(mBase + r0 + lr8) * K + k0 + lc8;
            __builtin_amdgcn_global_load_lds(
                (const __attribute__((address_space(1))) void*)ga,
                (__attribute__((address_space(3))) void*)(As + r0 * 64), 16, 0, 0);
        }
#pragma unroll
        for (int i = 0; i < BN / 32; ++i) {
            int r0 = (wid * (BN / 32) + i) * 8;
            const short* gb = Bw + (size_t)(nBase + r0 + lr8) * K + k0 + lc8;
            __builtin_amdgcn_global_load_lds(
                (const __attribute__((address_space(1))) void*)gb,
                (__attribute__((address_space(3))) void*)(Bs + r0 * 64), 16, 0, 0);
        }
        __syncthreads();  // compiler emits vmcnt(0) drain before barrier

        short8 af[2][MI], bf[2][NI];
#pragma unroll
        for (int kk = 0; kk < 2; ++kk) {
#pragma unroll
            for (int mi = 0; mi < MI; ++mi)
                af[kk][mi] = *reinterpret_cast<const short8*>(
                    As + (wr * (MI * 16) + mi * 16 + lrow) * 64 + kk * 32 + kg * 8);
#pragma unroll
            for (int ni = 0; ni < NI; ++ni)
                bf[kk][ni] = *reinterpret_cast<const short8*>(
                    Bs + (wc * (NI * 16) + ni * 16 + lrow) * 64 + kk * 32 + kg * 8);
        }
#pragma unroll
        for (int kk = 0; kk < 2; ++kk)
#pragma unroll
            for (int mi = 0; mi < MI; ++mi)
#pragma unroll
                for (int ni = 0; ni < NI; ++ni)
                    acc[mi][ni] = __builtin_amdgcn_mfma_f32_16x16x32_bf16(
                        af[kk][mi], bf[kk][ni], acc[mi][ni], 0, 0, 0);
    }

    int rowq = (lane >> 4) * 4;
    int coll = lane & 15;
#pragma unroll
    for (int mi = 0; mi < MI; ++mi) {
#pragma unroll
        for (int ni = 0; ni < NI; ++ni) {
            int col = nBase + wc * (NI * 16) + ni * 16 + coll;
            float bv = bias[col];
#pragma unroll
            for (int r = 0; r < 4; ++r) {
                int row = mBase + wr * (MI * 16) + mi * 16 + rowq + r;
                float v = acc[mi][ni][r] + bv;
                if (MODE == 0) {
                    C[(size_t)row * E_ + col] = v;
                } else {
                    int b = row >> 11, l = row & (L_ - 1);
                    size_t oi = (size_t)l * (B_ * E_) + b * E_ + col;
                    C[oi] = v + ident[oi];
                }
            }
        }
    }
}

// fused q/k/v projections: z selects weight/bias/output (3 blocks/CU co-residency)
__global__ __launch_bounds__(256) void k_gemm3(const short* __restrict__ A,
    const short* __restrict__ W0, const short* __restrict__ W1, const short* __restrict__ W2,
    const float* __restrict__ b0, const float* __restrict__ b1, const float* __restrict__ b2,
    float* __restrict__ C0, float* __restrict__ C1, float* __restrict__ C2) {
    int z = blockIdx.z;
    const short* Bw = z == 0 ? W0 : (z == 1 ? W1 : W2);
    const float* bias = z == 0 ? b0 : (z == 1 ? b1 : b2);
    float* C = z == 0 ? C0 : (z == 1 ? C1 : C2);
    gemm_body<0, 128, 128>(A, Bw, bias, C, nullptr, blockIdx.x, blockIdx.y);
}

__global__ __launch_bounds__(256) void k_gemmo(const short* __restrict__ A,
                                               const short* __restrict__ Bw,
                                               const float* __restrict__ bias,
                                               float* __restrict__ C,
                                               const float* __restrict__ ident) {
    gemm_body<1, 128, 64>(A, Bw, bias, C, ident, blockIdx.x, blockIdx.y);
}

// ---- qsum[b][f] = xsum[b]. dot q_w[f] + L*q_b[f]  (f32 exact) ----
__global__ void k_qsum(const float* __restrict__ xsum, const float* __restrict__ qw,
                       const float* __restrict__ qb, float* __restrict__ qsum) {
    int wid = threadIdx.x >> 6, lane = threadIdx.x & 63;
    int gid = blockIdx.x * 4 + wid;  // 0..2047
    int b = gid >> 10, f = gid & 1023;
    float s = 0.f;
    for (int e = lane; e < E_; e += 64) s += xsum[b * E_ + e] * qw[f * E_ + e];
#pragma unroll
    for (int off = 32; off; off >>= 1) s += __shfl_xor(s, off);
    if (lane == 0) qsum[gid] = s + (float)L_ * qb[f];
}

// ---- t[b,h,e] = sum_d qsum[b,h*64+d] * k_w[h*64+d, e] ----
__global__ void k_t(const float* __restrict__ qsum, const float* __restrict__ kw,
                    float* __restrict__ tb) {
    int i = blockIdx.x * 256 + threadIdx.x;  // 0..32767
    int e = i & 1023, bh = i >> 10;
    int b = bh >> 4, h = bh & 15;
    float s = 0.f;
#pragma unroll
    for (int d = 0; d < HD_; ++d)
        s += qsum[b * E_ + h * HD_ + d] * kw[(size_t)(h * HD_ + d) * E_ + e];
    tb[i] = s;
}

// ---- score[b,h,n]: query read once; 128 rows x 16 h per block, t in LDS ----
__global__ __launch_bounds__(256) void k_score(const float* __restrict__ query,
                                               const float* __restrict__ tb,
                                               float* __restrict__ score) {
    __shared__ float xs[128][65];
    __shared__ float ts[16][65];
    int b = blockIdx.x >> 4;
    int n0 = (blockIdx.x & 15) * 128;
    int tid = threadIdx.x;
    int hg = tid & 3;        // h = hg + 4*j
    int rg = tid >> 2;       // rows rg*2, rg*2+1
    float acc[4][2];
#pragma unroll
    for (int j = 0; j < 4; ++j) { acc[j][0] = 0.f; acc[j][1] = 0.f; }
    for (int e0 = 0; e0 < E_; e0 += 64) {
        __syncthreads();
#pragma unroll
        for (int it = 0; it < 8; ++it) {
            int flat = (it * 256 + tid) * 4;
            int r = flat >> 6, c = flat & 63;
            float4 v = *reinterpret_cast<const float4*>(
                &query[(size_t)(n0 + r) * (B_ * E_) + b * E_ + e0 + c]);
            xs[r][c] = v.x; xs[r][c + 1] = v.y; xs[r][c + 2] = v.z; xs[r][c + 3] = v.w;
        }
        {
            int flat = tid * 4;
            int hh = flat >> 6, c = flat & 63;
            float4 v = *reinterpret_cast<const float4*>(&tb[(size_t)(b * 16 + hh) * E_ + e0 + c]);
            ts[hh][c] = v.x; ts[hh][c + 1] = v.y; ts[hh][c + 2] = v.z; ts[hh][c + 3] = v.w;
        }
        __syncthreads();
#pragma unroll
        for (int c = 0; c < 64; ++c) {
            float x0 = xs[rg * 2][c], x1 = xs[rg * 2 + 1][c];
#pragma unroll
            for (int j = 0; j < 4; ++j) {
                float tv = ts[hg + 4 * j][c];
                acc[j][0] += x0 * tv;
                acc[j][1] += x1 * tv;
            }
        }
    }
#pragma unroll
    for (int j = 0; j < 4; ++j) {
        int h = hg + 4 * j;
        score[(size_t)(b * 16 + h) * L_ + n0 + rg * 2] = SCALE * acc[j][0];
        score[(size_t)(b * 16 + h) * L_ + n0 + rg * 2 + 1] = SCALE * acc[j][1];
    }
}

// ---- top-64 per (b,h): wave radix-select (no serial argmax), gather k rows ----
__global__ __launch_bounds__(256) void k_topk(const float* __restrict__ score,
                                              const float* __restrict__ kf,
                                              float* __restrict__ selk) {
    __shared__ int sel[4][64];
    int wid = threadIdx.x >> 6, lane = threadIdx.x & 63;
    int bh = blockIdx.x * 4 + wid;  // grid 8
    int b = bh >> 4, h = bh & 15;

    unsigned u[32];
#pragma unroll
    for (int j = 0; j < 32; ++j) {
        unsigned bits = __float_as_uint(score[bh * L_ + j * 64 + lane]);
        u[j] = (bits & 0x80000000u) ? ~bits : (bits | 0x80000000u);
    }
    // radix select: T = 64th-largest orderable uint
    unsigned prefix = 0;
    int k = TOPK_;
    for (int bit = 31; bit >= 0; --bit) {
        unsigned cand = prefix | (1u << bit);
        int c = 0;
#pragma unroll
        for (int j = 0; j < 32; ++j) c += ((u[j] >> bit) == (cand >> bit)) ? 1 : 0;
#pragma unroll
        for (int off = 32; off; off >>= 1) c += __shfl_xor(c, off);
        if (c >= k) prefix = cand; else k -= c;
    }
    unsigned T = prefix;
    int nStrict = 0;
#pragma unroll
    for (int j = 0; j < 32; ++j) nStrict += (u[j] > T) ? 1 : 0;
#pragma unroll
    for (int off = 32; off; off >>= 1) nStrict += __shfl_xor(nStrict, off);
    int nTies = TOPK_ - nStrict;

    // rank assignment: strict first (any order), ties by ascending index (= lax.top_k)
    int strictBase = 0, tieBase = 0;
    unsigned long long below = (lane == 0) ? 0ull : ((~0ull) >> (64 - lane));
#pragma unroll
    for (int j = 0; j < 32; ++j) {
        unsigned long long mS = __ballot(u[j] > T);
        unsigned long long mT = __ballot(u[j] == T);
        if (u[j] > T) {
            int slot = strictBase + __popcll(mS & below);
            sel[wid][slot] = j * 64 + lane;
        } else if (u[j] == T) {
            int r = tieBase + __popcll(mT & below);
            if (r < nTies) sel[wid][nStrict + r] = j * 64 + lane;
        }
        strictBase += __popcll(mS);
        tieBase += __popcll(mT);
    }
    __syncthreads();
    for (int m = 0; m < TOPK_; ++m) {
        int idx = sel[wid][m];
        selk[((size_t)bh * TOPK_ + m) * HD_ + lane] =
            kf[((size_t)b * L_ + idx) * E_ + h * HD_ + lane];
    }
}

// ---- sim[b,h,l,m] = softmax_m(scale * X[b,l,h*64+:].selk[b,h,m,:]); z picks q/k ----
__global__ __launch_bounds__(256) void k_sim(const float* __restrict__ qf,
                                             const float* __restrict__ kf,
                                             const float* __restrict__ selk,
                                             float* __restrict__ sqn,
                                             float* __restrict__ skm) {
    const float* X = blockIdx.y ? kf : qf;
    float* sim = blockIdx.y ? skm : sqn;
    __shared__ float xl[64][65];
    __shared__ float sk[64][65];
    int bh = blockIdx.x >> 5;
    int l0 = (blockIdx.x & 31) * 64;
    int b = bh >> 4, h = bh & 15;
    int tid = threadIdx.x;
    for (int j = tid; j < 64 * 64; j += 256) {
        int i = j >> 6, d = j & 63;
        xl[i][d] = X[((size_t)b * L_ + l0 + i) * E_ + h * HD_ + d];
        sk[i][d] = selk[((size_t)bh * TOPK_ + i) * HD_ + d];
    }
    __syncthreads();
    int wid = tid >> 6, m = tid & 63;
    for (int i = wid * 16; i < wid * 16 + 16; ++i) {
        float s = 0.f;
#pragma unroll
        for (int d = 0; d < 64; ++d) s += xl[i][d] * sk[m][d];
        s *= SCALE;
        float mx = s;
#pragma unroll
        for (int off = 32; off; off >>= 1) mx = fmaxf(mx, __shfl_xor(mx, off));
        float e = __expf(s - mx);
        float sum = e;
#pragma unroll
        for (int off = 32; off; off >>= 1) sum += __shfl_xor(sum, off);
        sim[((size_t)bh * L_ + l0 + i) * TOPK_ + m] = e / sum;
    }
}

// ---- wpart[ch,bh,m,d] = sum_{l in chunk} sim_km[l,m] * v[l,d] ----
__global__ __launch_bounds__(256) void k_wpart(const float* __restrict__ simkm,
                                               const float* __restrict__ vf,
                                               float* __restrict__ wpart) {
    __shared__ float km[16][64];
    __shared__ float vv[16][64];
    int bh = blockIdx.x & 31;
    int ch = blockIdx.x >> 5;
    int b = bh >> 4, h = bh & 15;
    int tid = threadIdx.x;
    int d = tid & 63, mg = (tid >> 6) * 16;
    float acc[16];
#pragma unroll
    for (int j = 0; j < 16; ++j) acc[j] = 0.f;
    for (int l0 = ch * 256; l0 < ch * 256 + 256; l0 += 16) {
        __syncthreads();
        for (int j = tid; j < 1024; j += 256) {
            int i = j >> 6, c = j & 63;
            km[i][c] = simkm[((size_t)bh * L_ + l0 + i) * TOPK_ + c];
            vv[i][c] = vf[((size_t)b * L_ + l0 + i) * E_ + h * HD_ + c];
        }
        __syncthreads();
#pragma unroll
        for (int i = 0; i < 16; ++i) {
            float vx = vv[i][d];
#pragma unroll
            for (int j = 0; j < 16; ++j) acc[j] += km[i][mg + j] * vx;
        }
    }
#pragma unroll
    for (int j = 0; j < 16; ++j)
        wpart[(((size_t)ch * 32 + bh) * TOPK_ + mg + j) * HD_ + d] = acc[j];
}

__global__ void k_wreduce(const float* __restrict__ wpart, float* __restrict__ W) {
    int i = blockIdx.x * 256 + threadIdx.x;  // 0..131071
    float s = 0.f;
#pragma unroll
    for (int c = 0; c < 8; ++c) s += wpart[(size_t)c * 131072 + i];
    W[i] = s;
}

// ---- att[b,l,h*64+d] = sum_m sim_qn[l,m] * W[m,d]  -> bf16 for o-proj ----
__global__ __launch_bounds__(256) void k_outhead(const float* __restrict__ simqn,
                                                 const float* __restrict__ W,
                                                 short* __restrict__ att) {
    __shared__ float Wl[64][65];
    __shared__ float qn[32][65];
    int bh = blockIdx.x >> 6;
    int l0 = (blockIdx.x & 63) * 32;
    int b = bh >> 4, h = bh & 15;
    int tid = threadIdx.x;
    for (int j = tid; j < 4096; j += 256) { int m = j >> 6, d = j & 63; Wl[m][d] = W[(size_t)bh * 4096 + j]; }
    for (int j = tid; j < 2048; j += 256) { int i = j >> 6, m = j & 63; qn[i][m] = simqn[((size_t)bh * L_ + l0 + i) * TOPK_ + m]; }
    __syncthreads();
    int d = tid & 63;
    int i0 = tid >> 6;
    for (int i = i0; i < 32; i += 4) {
        float s = 0.f;
#pragma unroll
        for (int m = 0; m < 64; ++m) s += qn[i][m] * Wl[m][d];
        att[((size_t)b * L_ + l0 + i) * E_ + h * HD_ + d] = f2bf(s);
    }
}

extern "C" void kernel_launch(void* const* d_in, const int* in_sizes, int n_in,
                              void* d_out, int out_size, void* d_ws, size_t ws_size,
                              hipStream_t stream) {
    const float* query = (const float*)d_in[0];
    const float* q_w = (const float*)d_in[1];
    const float* q_b = (const float*)d_in[2];
    const float* k_w = (const float*)d_in[3];
    const float* k_b = (const float*)d_in[4];
    const float* v_w = (const float*)d_in[5];
    const float* v_b = (const float*)d_in[6];
    const float* o_w = (const float*)d_in[7];
    const float* o_b = (const float*)d_in[8];
    float* out = (float*)d_out;

    char* p = (char*)d_ws;
    auto alloc = [&](size_t bytes) {
        char* r = p;
        p += (bytes + 255) & ~(size_t)255;
        return r;
    };
    short* xb   = (short*)alloc((size_t)MROWS * E_ * 2);
    short* qwb  = (short*)alloc((size_t)E_ * E_ * 2);
    short* kwb  = (short*)alloc((size_t)E_ * E_ * 2);
    short* vwb  = (short*)alloc((size_t)E_ * E_ * 2);
    short* owb  = (short*)alloc((size_t)E_ * E_ * 2);
    float* qf   = (float*)alloc((size_t)MROWS * E_ * 4);
    float* kf   = (float*)alloc((size_t)MROWS * E_ * 4);
    float* vf   = (float*)alloc((size_t)MROWS * E_ * 4);
    float* xpart= (float*)alloc((size_t)16 * B_ * E_ * 4);
    float* xsum = (float*)alloc((size_t)B_ * E_ * 4);
    float* qsum = (float*)alloc((size_t)B_ * E_ * 4);
    float* tb   = (float*)alloc((size_t)B_ * H_ * E_ * 4);
    float* scor = (float*)alloc((size_t)B_ * H_ * L_ * 4);
    float* selk = (float*)alloc((size_t)B_ * H_ * TOPK_ * HD_ * 4);
    float* sqn  = (float*)alloc((size_t)B_ * H_ * L_ * TOPK_ * 4);
    float* skm  = (float*)alloc((size_t)B_ * H_ * L_ * TOPK_ * 4);
    float* wpart = (float*)alloc((size_t)8 * 32 * TOPK_ * HD_ * 4);
    float* Wb   = (float*)alloc((size_t)32 * TOPK_ * HD_ * 4);
    short* att  = (short*)alloc((size_t)MROWS * E_ * 2);

    // stage 1: casts / transpose / exact sums
    k_prep_x<<<4096, 256, 0, stream>>>(query, xb);
    k_castw<<<4096, 256, 0, stream>>>(q_w, k_w, v_w, o_w, qwb, kwb, vwb, owb);
    k_xsum<<<128, 256, 0, stream>>>(query, xpart);
    k_xred<<<8, 256, 0, stream>>>(xpart, xsum);

    // stage 2: fused q/k/v projections (bf16 MFMA, global_load_lds)
    k_gemm3<<<dim3(E_ / 128, MROWS / 128, 3), 256, 0, stream>>>(
        xb, qwb, kwb, vwb, q_b, k_b, v_b, qf, kf, vf);

    // stage 3: exact f32 scores + top-k selection
    k_qsum<<<512, 256, 0, stream>>>(xsum, q_w, q_b, qsum);
    k_t<<<128, 256, 0, stream>>>(qsum, k_w, tb);
    k_score<<<32, 256, 0, stream>>>(query, tb, scor);
    k_topk<<<8, 256, 0, stream>>>(scor, kf, selk);

    // stage 4: softmaxes, W = sim_km^T v, out_head = sim_qn W
    k_sim<<<dim3(1024, 2), 256, 0, stream>>>(qf, kf, selk, sqn, skm);
    k_wpart<<<256, 256, 0, stream>>>(skm, vf, wpart);
    k_wreduce<<<512, 256, 0, stream>>>(wpart, Wb);
    k_outhead<<<2048, 256, 0, stream>>>(sqn, Wb, att);

    // stage 5: o-projection fused with bias + residual + transpose back
    k_gemmo<<<dim3(E_ / 64, MROWS / 128), 256, 0, stream>>>(att, owb, o_b, out, query);
}

// Round 3
// 244.612 us; speedup vs baseline: 1.8574x; 1.3699x over previous
//
#include <hip/hip_runtime.h>
#include <hip/hip_bf16.h>

#define L_ 2048
#define B_ 2
#define E_ 1024
#define H_ 16
#define HD_ 64
#define TOPK_ 64
#define MROWS (B_*L_)
#define SCALE 0.125f

typedef __attribute__((ext_vector_type(8))) short short8;
typedef __attribute__((ext_vector_type(4))) short short4v;
typedef __attribute__((ext_vector_type(4))) float f32x4;

static __device__ __forceinline__ short f2bf(float f) {
    __hip_bfloat16 h = __float2bfloat16(f);
    return *reinterpret_cast<short*>(&h);
}
static __device__ __forceinline__ float bf2f(short s) {
    unsigned u = ((unsigned)(unsigned short)s) << 16;
    return __uint_as_float(u);
}

// ---- transpose [L,B,E] f32 -> [B,L,E] bf16 ----
__global__ void k_prep_x(const float* __restrict__ q, short* __restrict__ xb) {
    int i = blockIdx.x * 256 + threadIdx.x;
    int idx = i * 4;
    int e = idx & (E_ - 1);
    int l = (idx >> 10) & (L_ - 1);
    int b = idx >> 21;
    float4 v = *reinterpret_cast<const float4*>(q + l * (B_ * E_) + b * E_ + e);
    short4v o;
    o[0] = f2bf(v.x); o[1] = f2bf(v.y); o[2] = f2bf(v.z); o[3] = f2bf(v.w);
    *reinterpret_cast<short4v*>(xb + idx) = o;
}

// ---- cast all 4 weight matrices f32 -> bf16 in one dispatch ----
__global__ void k_castw(const float* __restrict__ w0, const float* __restrict__ w1,
                        const float* __restrict__ w2, const float* __restrict__ w3,
                        short* __restrict__ o0, short* __restrict__ o1,
                        short* __restrict__ o2, short* __restrict__ o3) {
    int blk = blockIdx.x & 1023, sel = blockIdx.x >> 10;
    const float* w = sel == 0 ? w0 : sel == 1 ? w1 : sel == 2 ? w2 : w3;
    short* o = sel == 0 ? o0 : sel == 1 ? o1 : sel == 2 ? o2 : o3;
    int i = blk * 256 + threadIdx.x;
    float4 v = *reinterpret_cast<const float4*>(w + i * 4);
    short4v s;
    s[0] = f2bf(v.x); s[1] = f2bf(v.y); s[2] = f2bf(v.z); s[3] = f2bf(v.w);
    *reinterpret_cast<short4v*>(o + i * 4) = s;
}

// ---- xpart[ch][col] = sum over 128 l of query[l*2048 + col] ----
__global__ void k_xsum(const float* __restrict__ q, float* __restrict__ xpart) {
    int cg = blockIdx.x & 7, ch = blockIdx.x >> 3;  // grid 128
    int col = cg * 256 + threadIdx.x;
    float s = 0.f;
    for (int l = ch * 128; l < (ch + 1) * 128; ++l) s += q[(size_t)l * (B_ * E_) + col];
    xpart[ch * (B_ * E_) + col] = s;
}
__global__ void k_xred(const float* __restrict__ xpart, float* __restrict__ xsum) {
    int col = blockIdx.x * 256 + threadIdx.x;  // grid 8
    float s = 0.f;
#pragma unroll
    for (int c = 0; c < 16; ++c) s += xpart[c * (B_ * E_) + col];
    xsum[col] = s;
}

// ---- GEMM core: C[M,N] = A[M,K](bf16) * Bw[N,K](bf16)^T + bias ----
// MODE 0: C bf16 [M][E_].  MODE 1: out f32 [l,b,e] = acc + bias + ident.
template<int MODE, int BM, int BN>
__device__ __forceinline__ void gemm_body(const short* __restrict__ A,
                                          const short* __restrict__ Bw,
                                          const float* __restrict__ bias,
                                          short* __restrict__ Cb,
                                          float* __restrict__ Cf,
                                          const float* __restrict__ ident,
                                          int bx, int by) {
    const int K = E_;
    constexpr int MI = BM / 32;
    constexpr int NI = BN / 32;
    __shared__ short As[BM * 64];
    __shared__ short Bs[BN * 64];
    int tid = threadIdx.x;
    int lane = tid & 63;
    int wid = tid >> 6;
    int wr = wid >> 1, wc = wid & 1;
    int lrow = lane & 15;
    int kg = lane >> 4;
    int lr8 = lane >> 3;
    int lc8 = (lane & 7) * 8;
    int mBase = by * BM, nBase = bx * BN;

    f32x4 acc[MI][NI];
#pragma unroll
    for (int i = 0; i < MI; ++i)
#pragma unroll
        for (int j = 0; j < NI; ++j) acc[i][j] = (f32x4){0.f, 0.f, 0.f, 0.f};

    for (int k0 = 0; k0 < K; k0 += 64) {
        __syncthreads();
#pragma unroll
        for (int i = 0; i < BM / 32; ++i) {
            int r0 = (wid * (BM / 32) + i) * 8;
            const short* ga = A + (size_t)(mBase + r0 + lr8) * K + k0 + lc8;
            __builtin_amdgcn_global_load_lds(
                (const __attribute__((address_space(1))) void*)ga,
                (__attribute__((address_space(3))) void*)(As + r0 * 64), 16, 0, 0);
        }
#pragma unroll
        for (int i = 0; i < BN / 32; ++i) {
            int r0 = (wid * (BN / 32) + i) * 8;
            const short* gb = Bw + (size_t)(nBase + r0 + lr8) * K + k0 + lc8;
            __builtin_amdgcn_global_load_lds(
                (const __attribute__((address_space(1))) void*)gb,
                (__attribute__((address_space(3))) void*)(Bs + r0 * 64), 16, 0, 0);
        }
        __syncthreads();

        short8 af[2][MI], bf[2][NI];
#pragma unroll
        for (int kk = 0; kk < 2; ++kk) {
#pragma unroll
            for (int mi = 0; mi < MI; ++mi)
                af[kk][mi] = *reinterpret_cast<const short8*>(
                    As + (wr * (MI * 16) + mi * 16 + lrow) * 64 + kk * 32 + kg * 8);
#pragma unroll
            for (int ni = 0; ni < NI; ++ni)
                bf[kk][ni] = *reinterpret_cast<const short8*>(
                    Bs + (wc * (NI * 16) + ni * 16 + lrow) * 64 + kk * 32 + kg * 8);
        }
#pragma unroll
        for (int kk = 0; kk < 2; ++kk)
#pragma unroll
            for (int mi = 0; mi < MI; ++mi)
#pragma unroll
                for (int ni = 0; ni < NI; ++ni)
                    acc[mi][ni] = __builtin_amdgcn_mfma_f32_16x16x32_bf16(
                        af[kk][mi], bf[kk][ni], acc[mi][ni], 0, 0, 0);
    }

    int rowq = (lane >> 4) * 4;
    int coll = lane & 15;
#pragma unroll
    for (int mi = 0; mi < MI; ++mi) {
#pragma unroll
        for (int ni = 0; ni < NI; ++ni) {
            int col = nBase + wc * (NI * 16) + ni * 16 + coll;
            float bv = bias[col];
#pragma unroll
            for (int r = 0; r < 4; ++r) {
                int row = mBase + wr * (MI * 16) + mi * 16 + rowq + r;
                float v = acc[mi][ni][r] + bv;
                if (MODE == 0) {
                    Cb[(size_t)row * E_ + col] = f2bf(v);
                } else {
                    int b = row >> 11, l = row & (L_ - 1);
                    size_t oi = (size_t)l * (B_ * E_) + b * E_ + col;
                    Cf[oi] = v + ident[oi];
                }
            }
        }
    }
}

// fused q/k/v projections; 1D grid 768 with bijective XCD swizzle (768%8==0)
__global__ __launch_bounds__(256) void k_gemm3(const short* __restrict__ A,
    const short* __restrict__ W0, const short* __restrict__ W1, const short* __restrict__ W2,
    const float* __restrict__ b0, const float* __restrict__ b1, const float* __restrict__ b2,
    short* __restrict__ C0, short* __restrict__ C1, short* __restrict__ C2) {
    int wg = blockIdx.x;
    int sw = (wg & 7) * 96 + (wg >> 3);   // contiguous chunk per XCD
    int bx = sw & 7, by = (sw >> 3) & 31, z = sw >> 8;
    const short* Bw = z == 0 ? W0 : (z == 1 ? W1 : W2);
    const float* bias = z == 0 ? b0 : (z == 1 ? b1 : b2);
    short* C = z == 0 ? C0 : (z == 1 ? C1 : C2);
    gemm_body<0, 128, 128>(A, Bw, bias, C, nullptr, nullptr, bx, by);
}

__global__ __launch_bounds__(256) void k_gemmo(const short* __restrict__ A,
                                               const short* __restrict__ Bw,
                                               const float* __restrict__ bias,
                                               float* __restrict__ C,
                                               const float* __restrict__ ident) {
    int wg = blockIdx.x;
    int sw = (wg & 7) * 64 + (wg >> 3);   // 512 blocks
    int bx = sw & 15, by = sw >> 4;
    gemm_body<1, 128, 64>(A, Bw, bias, nullptr, C, ident, bx, by);
}

// ---- qsum[b][f] = xsum[b]. dot q_w[f] + L*q_b[f]  (f32 exact) ----
__global__ void k_qsum(const float* __restrict__ xsum, const float* __restrict__ qw,
                       const float* __restrict__ qb, float* __restrict__ qsum) {
    int wid = threadIdx.x >> 6, lane = threadIdx.x & 63;
    int gid = blockIdx.x * 4 + wid;  // 0..2047
    int b = gid >> 10, f = gid & 1023;
    float s = 0.f;
    for (int e = lane; e < E_; e += 64) s += xsum[b * E_ + e] * qw[f * E_ + e];
#pragma unroll
    for (int off = 32; off; off >>= 1) s += __shfl_xor(s, off);
    if (lane == 0) qsum[gid] = s + (float)L_ * qb[f];
}

// ---- t[b,h,e] = sum_d qsum[b,h*64+d] * k_w[h*64+d, e] ----
__global__ void k_t(const float* __restrict__ qsum, const float* __restrict__ kw,
                    float* __restrict__ tb) {
    int i = blockIdx.x * 256 + threadIdx.x;  // 0..32767
    int e = i & 1023, bh = i >> 10;
    int b = bh >> 4, h = bh & 15;
    float s = 0.f;
#pragma unroll
    for (int d = 0; d < HD_; ++d)
        s += qsum[b * E_ + h * HD_ + d] * kw[(size_t)(h * HD_ + d) * E_ + e];
    tb[i] = s;
}

// ---- partial scores over e-quarters: 256 blocks ----
__global__ __launch_bounds__(256) void k_score(const float* __restrict__ query,
                                               const float* __restrict__ tb,
                                               float* __restrict__ scorp) {
    __shared__ float xs[64][68];
    __shared__ float ts[16][68];
    int id = blockIdx.x;
    int eq = id >> 6;       // 0..3
    int b = (id >> 5) & 1;
    int n0 = (id & 31) * 64;
    int tid = threadIdx.x;
    int hg = tid & 3, rg = tid >> 2;  // rg = row 0..63
    float acc[4] = {0.f, 0.f, 0.f, 0.f};
    for (int e0 = eq * 256; e0 < eq * 256 + 256; e0 += 64) {
        __syncthreads();
        for (int j = tid; j < 1024; j += 256) {
            int r = j >> 4, c4 = (j & 15) * 4;
            float4 v = *reinterpret_cast<const float4*>(
                &query[(size_t)(n0 + r) * (B_ * E_) + b * E_ + e0 + c4]);
            *reinterpret_cast<float4*>(&xs[r][c4]) = v;
        }
        if (tid < 256) {
            int hh = tid >> 4, c4 = (tid & 15) * 4;
            float4 v = *reinterpret_cast<const float4*>(&tb[(size_t)(b * 16 + hh) * E_ + e0 + c4]);
            *reinterpret_cast<float4*>(&ts[hh][c4]) = v;
        }
        __syncthreads();
        for (int c = 0; c < 64; ++c) {
            float x0 = xs[rg][c];
#pragma unroll
            for (int j = 0; j < 4; ++j) acc[j] += x0 * ts[hg + 4 * j][c];
        }
    }
#pragma unroll
    for (int j = 0; j < 4; ++j) {
        int h = hg + 4 * j;
        scorp[(size_t)eq * 65536 + (size_t)(b * 16 + h) * L_ + n0 + rg] = acc[j];
    }
}

__global__ void k_scred(const float* __restrict__ scorp, float* __restrict__ scor) {
    int i = blockIdx.x * 256 + threadIdx.x;  // 65536
    float s = ((scorp[i] + scorp[65536 + i]) + scorp[131072 + i]) + scorp[196608 + i];
    scor[i] = SCALE * s;
}

// ---- top-64 per (b,h): wave radix-select, gather k rows (bf16 -> f32 selk) ----
__global__ __launch_bounds__(256) void k_topk(const float* __restrict__ score,
                                              const short* __restrict__ kb,
                                              float* __restrict__ selk) {
    __shared__ int sel[4][64];
    int wid = threadIdx.x >> 6, lane = threadIdx.x & 63;
    int bh = blockIdx.x * 4 + wid;  // grid 8
    int b = bh >> 4, h = bh & 15;

    unsigned u[32];
#pragma unroll
    for (int j = 0; j < 32; ++j) {
        unsigned bits = __float_as_uint(score[bh * L_ + j * 64 + lane]);
        u[j] = (bits & 0x80000000u) ? ~bits : (bits | 0x80000000u);
    }
    unsigned prefix = 0;
    int k = TOPK_;
    for (int bit = 31; bit >= 0; --bit) {
        unsigned cand = prefix | (1u << bit);
        int c = 0;
#pragma unroll
        for (int j = 0; j < 32; ++j) c += ((u[j] >> bit) == (cand >> bit)) ? 1 : 0;
#pragma unroll
        for (int off = 32; off; off >>= 1) c += __shfl_xor(c, off);
        if (c >= k) prefix = cand; else k -= c;
    }
    unsigned T = prefix;
    int nStrict = 0;
#pragma unroll
    for (int j = 0; j < 32; ++j) nStrict += (u[j] > T) ? 1 : 0;
#pragma unroll
    for (int off = 32; off; off >>= 1) nStrict += __shfl_xor(nStrict, off);
    int nTies = TOPK_ - nStrict;

    int strictBase = 0, tieBase = 0;
    unsigned long long below = (lane == 0) ? 0ull : ((~0ull) >> (64 - lane));
#pragma unroll
    for (int j = 0; j < 32; ++j) {
        unsigned long long mS = __ballot(u[j] > T);
        unsigned long long mT = __ballot(u[j] == T);
        if (u[j] > T) {
            int slot = strictBase + __popcll(mS & below);
            sel[wid][slot] = j * 64 + lane;
        } else if (u[j] == T) {
            int r = tieBase + __popcll(mT & below);
            if (r < nTies) sel[wid][nStrict + r] = j * 64 + lane;
        }
        strictBase += __popcll(mS);
        tieBase += __popcll(mT);
    }
    __syncthreads();
    for (int m = 0; m < TOPK_; ++m) {
        int idx = sel[wid][m];
        selk[((size_t)bh * TOPK_ + m) * HD_ + lane] =
            bf2f(kb[((size_t)b * L_ + idx) * E_ + h * HD_ + lane]);
    }
}

// ---- fused: sim_km (softmax) + partial W = sim_km^T v ----
// selk in LDS with XOR-swizzle on (m>>3)&7 so 8-rows-apart float4 reads are conflict-free
__global__ __launch_bounds__(256) void k_attW(const short* __restrict__ kb,
                                              const short* __restrict__ vb,
                                              const float* __restrict__ selk,
                                              float* __restrict__ wpart) {
    __shared__ float sk[64][64];   // swizzled
    __shared__ float kv[32][68];
    __shared__ float vv[32][68];
    __shared__ float km[32][68];
    int wg = blockIdx.x;
    int sw = (wg & 7) * 64 + (wg >> 3);  // XCD swizzle, 512 blocks
    int bh = sw & 31, ch = sw >> 5;      // ch 0..15
    int b = bh >> 4, h = bh & 15;
    int tid = threadIdx.x;
    for (int j = tid; j < 4096; j += 256) {
        int m = j >> 6, d0 = j & 63;
        sk[m][d0 ^ (((m >> 3) & 7) << 2)] = selk[(size_t)bh * 4096 + j];
    }
    int d = tid & 63, mg = (tid >> 6) * 16;
    int i8 = tid >> 3, m8 = (tid & 7) * 8;
    float acc[16];
#pragma unroll
    for (int j = 0; j < 16; ++j) acc[j] = 0.f;

    for (int l0 = ch * 128; l0 < ch * 128 + 128; l0 += 32) {
        __syncthreads();
        for (int j = tid; j < 2048; j += 256) {
            int i = j >> 6, c = j & 63;
            size_t base = ((size_t)b * L_ + l0 + i) * E_ + h * HD_ + c;
            kv[i][c] = bf2f(kb[base]);
            vv[i][c] = bf2f(vb[base]);
        }
        __syncthreads();
        float s[8];
#pragma unroll
        for (int j = 0; j < 8; ++j) s[j] = 0.f;
        for (int c = 0; c < 64; c += 4) {
            float4 a = *reinterpret_cast<const float4*>(&kv[i8][c]);
#pragma unroll
            for (int j = 0; j < 8; ++j) {
                int m = m8 + j;
                float4 bm = *reinterpret_cast<const float4*>(&sk[m][c ^ (((m >> 3) & 7) << 2)]);
                s[j] += a.x * bm.x + a.y * bm.y + a.z * bm.z + a.w * bm.w;
            }
        }
        float mx = -INFINITY;
#pragma unroll
        for (int j = 0; j < 8; ++j) { s[j] *= SCALE; mx = fmaxf(mx, s[j]); }
        mx = fmaxf(mx, __shfl_xor(mx, 1));
        mx = fmaxf(mx, __shfl_xor(mx, 2));
        mx = fmaxf(mx, __shfl_xor(mx, 4));
        float e[8], sum = 0.f;
#pragma unroll
        for (int j = 0; j < 8; ++j) { e[j] = __expf(s[j] - mx); sum += e[j]; }
        sum += __shfl_xor(sum, 1);
        sum += __shfl_xor(sum, 2);
        sum += __shfl_xor(sum, 4);
        float inv = 1.f / sum;
#pragma unroll
        for (int j = 0; j < 8; ++j) km[i8][m8 + j] = e[j] * inv;
        __syncthreads();
#pragma unroll
        for (int i = 0; i < 32; ++i) {
            float vx = vv[i][d];
#pragma unroll
            for (int j = 0; j < 16; ++j) acc[j] += km[i][mg + j] * vx;
        }
    }
#pragma unroll
    for (int j = 0; j < 16; ++j)
        wpart[((size_t)(ch * 32 + bh)) * 4096 + (size_t)(mg + j) * 64 + d] = acc[j];
}

__global__ void k_wreduce(const float* __restrict__ wpart, float* __restrict__ W) {
    int i = blockIdx.x * 256 + threadIdx.x;  // 131072, grid 512
    float s = 0.f;
#pragma unroll
    for (int c = 0; c < 16; ++c) s += wpart[(size_t)c * 131072 + i];
    W[i] = s;
}

// ---- fused: sim_qn (softmax) + att = sim_qn W -> bf16 ----
__global__ __launch_bounds__(256) void k_attO(const short* __restrict__ qb,
                                              const float* __restrict__ selk,
                                              const float* __restrict__ Wb,
                                              short* __restrict__ att) {
    __shared__ float sk[64][64];   // swizzled
    __shared__ float Wl[64][68];
    __shared__ float qv[32][68];
    __shared__ float qn[32][68];
    int wg = blockIdx.x;
    int sw = (wg & 7) * 64 + (wg >> 3);
    int bh = sw & 31, ch = sw >> 5;
    int b = bh >> 4, h = bh & 15;
    int tid = threadIdx.x;
    for (int j = tid; j < 4096; j += 256) {
        int m = j >> 6, d0 = j & 63;
        sk[m][d0 ^ (((m >> 3) & 7) << 2)] = selk[(size_t)bh * 4096 + j];
        Wl[m][d0] = Wb[(size_t)bh * 4096 + j];
    }
    int i8 = tid >> 3, m8 = (tid & 7) * 8;
    int d = tid & 63, g = tid >> 6;
    for (int l0 = ch * 128; l0 < ch * 128 + 128; l0 += 32) {
        __syncthreads();
        for (int j = tid; j < 2048; j += 256) {
            int i = j >> 6, c = j & 63;
            qv[i][c] = bf2f(qb[((size_t)b * L_ + l0 + i) * E_ + h * HD_ + c]);
        }
        __syncthreads();
        float s[8];
#pragma unroll
        for (int j = 0; j < 8; ++j) s[j] = 0.f;
        for (int c = 0; c < 64; c += 4) {
            float4 a = *reinterpret_cast<const float4*>(&qv[i8][c]);
#pragma unroll
            for (int j = 0; j < 8; ++j) {
                int m = m8 + j;
                float4 bm = *reinterpret_cast<const float4*>(&sk[m][c ^ (((m >> 3) & 7) << 2)]);
                s[j] += a.x * bm.x + a.y * bm.y + a.z * bm.z + a.w * bm.w;
            }
        }
        float mx = -INFINITY;
#pragma unroll
        for (int j = 0; j < 8; ++j) { s[j] *= SCALE; mx = fmaxf(mx, s[j]); }
        mx = fmaxf(mx, __shfl_xor(mx, 1));
        mx = fmaxf(mx, __shfl_xor(mx, 2));
        mx = fmaxf(mx, __shfl_xor(mx, 4));
        float e[8], sum = 0.f;
#pragma unroll
        for (int j = 0; j < 8; ++j) { e[j] = __expf(s[j] - mx); sum += e[j]; }
        sum += __shfl_xor(sum, 1);
        sum += __shfl_xor(sum, 2);
        sum += __shfl_xor(sum, 4);
        float inv = 1.f / sum;
#pragma unroll
        for (int j = 0; j < 8; ++j) qn[i8][m8 + j] = e[j] * inv;
        __syncthreads();
        for (int i = g * 8; i < g * 8 + 8; ++i) {
            float o = 0.f;
#pragma unroll
            for (int m = 0; m < 64; ++m) o += qn[i][m] * Wl[m][d];
            att[((size_t)b * L_ + l0 + i) * E_ + h * HD_ + d] = f2bf(o);
        }
    }
}

extern "C" void kernel_launch(void* const* d_in, const int* in_sizes, int n_in,
                              void* d_out, int out_size, void* d_ws, size_t ws_size,
                              hipStream_t stream) {
    const float* query = (const float*)d_in[0];
    const float* q_w = (const float*)d_in[1];
    const float* q_b = (const float*)d_in[2];
    const float* k_w = (const float*)d_in[3];
    const float* k_b = (const float*)d_in[4];
    const float* v_w = (const float*)d_in[5];
    const float* v_b = (const float*)d_in[6];
    const float* o_w = (const float*)d_in[7];
    const float* o_b = (const float*)d_in[8];
    float* out = (float*)d_out;

    char* p = (char*)d_ws;
    auto alloc = [&](size_t bytes) {
        char* r = p;
        p += (bytes + 255) & ~(size_t)255;
        return r;
    };
    short* xb    = (short*)alloc((size_t)MROWS * E_ * 2);
    short* qwb   = (short*)alloc((size_t)E_ * E_ * 2);
    short* kwb   = (short*)alloc((size_t)E_ * E_ * 2);
    short* vwb   = (short*)alloc((size_t)E_ * E_ * 2);
    short* owb   = (short*)alloc((size_t)E_ * E_ * 2);
    short* qbuf  = (short*)alloc((size_t)MROWS * E_ * 2);
    short* kbuf  = (short*)alloc((size_t)MROWS * E_ * 2);
    short* vbuf  = (short*)alloc((size_t)MROWS * E_ * 2);
    float* xpart = (float*)alloc((size_t)16 * B_ * E_ * 4);
    float* xsum  = (float*)alloc((size_t)B_ * E_ * 4);
    float* qsum  = (float*)alloc((size_t)B_ * E_ * 4);
    float* tb    = (float*)alloc((size_t)B_ * H_ * E_ * 4);
    float* scorp = (float*)alloc((size_t)4 * B_ * H_ * L_ * 4);
    float* scor  = (float*)alloc((size_t)B_ * H_ * L_ * 4);
    float* selk  = (float*)alloc((size_t)B_ * H_ * TOPK_ * HD_ * 4);
    float* wpart = (float*)alloc((size_t)16 * 32 * TOPK_ * HD_ * 4);
    float* Wb    = (float*)alloc((size_t)32 * TOPK_ * HD_ * 4);
    short* att   = (short*)alloc((size_t)MROWS * E_ * 2);

    // stage 1: casts / transpose / exact sums
    k_prep_x<<<4096, 256, 0, stream>>>(query, xb);
    k_castw<<<4096, 256, 0, stream>>>(q_w, k_w, v_w, o_w, qwb, kwb, vwb, owb);
    k_xsum<<<128, 256, 0, stream>>>(query, xpart);
    k_xred<<<8, 256, 0, stream>>>(xpart, xsum);

    // stage 2: fused q/k/v projections (bf16 out)
    k_gemm3<<<768, 256, 0, stream>>>(xb, qwb, kwb, vwb, q_b, k_b, v_b, qbuf, kbuf, vbuf);

    // stage 3: exact f32 scores + top-k selection
    k_qsum<<<512, 256, 0, stream>>>(xsum, q_w, q_b, qsum);
    k_t<<<128, 256, 0, stream>>>(qsum, k_w, tb);
    k_score<<<256, 256, 0, stream>>>(query, tb, scorp);
    k_scred<<<256, 256, 0, stream>>>(scorp, scor);
    k_topk<<<8, 256, 0, stream>>>(scor, kbuf, selk);

    // stage 4: fused attention core
    k_attW<<<512, 256, 0, stream>>>(kbuf, vbuf, selk, wpart);
    k_wreduce<<<512, 256, 0, stream>>>(wpart, Wb);
    k_attO<<<512, 256, 0, stream>>>(qbuf, selk, Wb, att);

    // stage 5: o-projection fused with bias + residual + transpose back
    k_gemmo<<<512, 256, 0, stream>>>(att, owb, o_b, out, query);
}

// Round 4
// 194.579 us; speedup vs baseline: 2.3350x; 1.2571x over previous
//
#include <hip/hip_runtime.h>
#include <hip/hip_bf16.h>

#define L_ 2048
#define B_ 2
#define E_ 1024
#define H_ 16
#define HD_ 64
#define TOPK_ 64
#define MROWS (B_*L_)
#define SCALE 0.125f

typedef __attribute__((ext_vector_type(8))) short short8;
typedef __attribute__((ext_vector_type(4))) short short4v;
typedef __attribute__((ext_vector_type(4))) float f32x4;

static __device__ __forceinline__ short f2bf(float f) {
    __hip_bfloat16 h = __float2bfloat16(f);
    return *reinterpret_cast<short*>(&h);
}
static __device__ __forceinline__ float bf2f(short s) {
    unsigned u = ((unsigned)(unsigned short)s) << 16;
    return __uint_as_float(u);
}

// ---- transpose [L,B,E] f32 -> [B,L,E] bf16 ----
__global__ void k_prep_x(const float* __restrict__ q, short* __restrict__ xb) {
    int i = blockIdx.x * 256 + threadIdx.x;
    int idx = i * 4;
    int e = idx & (E_ - 1);
    int l = (idx >> 10) & (L_ - 1);
    int b = idx >> 21;
    float4 v = *reinterpret_cast<const float4*>(q + l * (B_ * E_) + b * E_ + e);
    short4v o;
    o[0] = f2bf(v.x); o[1] = f2bf(v.y); o[2] = f2bf(v.z); o[3] = f2bf(v.w);
    *reinterpret_cast<short4v*>(xb + idx) = o;
}

// ---- cast all 4 weight matrices f32 -> bf16 in one dispatch ----
__global__ void k_castw(const float* __restrict__ w0, const float* __restrict__ w1,
                        const float* __restrict__ w2, const float* __restrict__ w3,
                        short* __restrict__ o0, short* __restrict__ o1,
                        short* __restrict__ o2, short* __restrict__ o3) {
    int blk = blockIdx.x & 1023, sel = blockIdx.x >> 10;
    const float* w = sel == 0 ? w0 : sel == 1 ? w1 : sel == 2 ? w2 : w3;
    short* o = sel == 0 ? o0 : sel == 1 ? o1 : sel == 2 ? o2 : o3;
    int i = blk * 256 + threadIdx.x;
    float4 v = *reinterpret_cast<const float4*>(w + i * 4);
    short4v s;
    s[0] = f2bf(v.x); s[1] = f2bf(v.y); s[2] = f2bf(v.z); s[3] = f2bf(v.w);
    *reinterpret_cast<short4v*>(o + i * 4) = s;
}

// ---- xpart[ch][col] = sum over 128 l of query[l*2048 + col] ----
__global__ void k_xsum(const float* __restrict__ q, float* __restrict__ xpart) {
    int cg = blockIdx.x & 7, ch = blockIdx.x >> 3;  // grid 128
    int col = cg * 256 + threadIdx.x;
    float s = 0.f;
    for (int l = ch * 128; l < (ch + 1) * 128; ++l) s += q[(size_t)l * (B_ * E_) + col];
    xpart[ch * (B_ * E_) + col] = s;
}
__global__ void k_xred(const float* __restrict__ xpart, float* __restrict__ xsum) {
    int col = blockIdx.x * 256 + threadIdx.x;  // grid 8
    float s = 0.f;
#pragma unroll
    for (int c = 0; c < 16; ++c) s += xpart[c * (B_ * E_) + col];
    xsum[col] = s;
}

// ---- GEMM core: C[M,N] = A[M,K](bf16) * Bw[N,K](bf16)^T + bias ----
template<int MODE, int BM, int BN>
__device__ __forceinline__ void gemm_body(const short* __restrict__ A,
                                          const short* __restrict__ Bw,
                                          const float* __restrict__ bias,
                                          short* __restrict__ Cb,
                                          float* __restrict__ Cf,
                                          const float* __restrict__ ident,
                                          int bx, int by) {
    const int K = E_;
    constexpr int MI = BM / 32;
    constexpr int NI = BN / 32;
    __shared__ short As[BM * 64];
    __shared__ short Bs[BN * 64];
    int tid = threadIdx.x;
    int lane = tid & 63;
    int wid = tid >> 6;
    int wr = wid >> 1, wc = wid & 1;
    int lrow = lane & 15;
    int kg = lane >> 4;
    int lr8 = lane >> 3;
    int lc8 = (lane & 7) * 8;
    int mBase = by * BM, nBase = bx * BN;

    f32x4 acc[MI][NI];
#pragma unroll
    for (int i = 0; i < MI; ++i)
#pragma unroll
        for (int j = 0; j < NI; ++j) acc[i][j] = (f32x4){0.f, 0.f, 0.f, 0.f};

    for (int k0 = 0; k0 < K; k0 += 64) {
        __syncthreads();
#pragma unroll
        for (int i = 0; i < BM / 32; ++i) {
            int r0 = (wid * (BM / 32) + i) * 8;
            const short* ga = A + (size_t)(mBase + r0 + lr8) * K + k0 + lc8;
            __builtin_amdgcn_global_load_lds(
                (const __attribute__((address_space(1))) void*)ga,
                (__attribute__((address_space(3))) void*)(As + r0 * 64), 16, 0, 0);
        }
#pragma unroll
        for (int i = 0; i < BN / 32; ++i) {
            int r0 = (wid * (BN / 32) + i) * 8;
            const short* gb = Bw + (size_t)(nBase + r0 + lr8) * K + k0 + lc8;
            __builtin_amdgcn_global_load_lds(
                (const __attribute__((address_space(1))) void*)gb,
                (__attribute__((address_space(3))) void*)(Bs + r0 * 64), 16, 0, 0);
        }
        __syncthreads();

        short8 af[2][MI], bf[2][NI];
#pragma unroll
        for (int kk = 0; kk < 2; ++kk) {
#pragma unroll
            for (int mi = 0; mi < MI; ++mi)
                af[kk][mi] = *reinterpret_cast<const short8*>(
                    As + (wr * (MI * 16) + mi * 16 + lrow) * 64 + kk * 32 + kg * 8);
#pragma unroll
            for (int ni = 0; ni < NI; ++ni)
                bf[kk][ni] = *reinterpret_cast<const short8*>(
                    Bs + (wc * (NI * 16) + ni * 16 + lrow) * 64 + kk * 32 + kg * 8);
        }
#pragma unroll
        for (int kk = 0; kk < 2; ++kk)
#pragma unroll
            for (int mi = 0; mi < MI; ++mi)
#pragma unroll
                for (int ni = 0; ni < NI; ++ni)
                    acc[mi][ni] = __builtin_amdgcn_mfma_f32_16x16x32_bf16(
                        af[kk][mi], bf[kk][ni], acc[mi][ni], 0, 0, 0);
    }

    int rowq = (lane >> 4) * 4;
    int coll = lane & 15;
#pragma unroll
    for (int mi = 0; mi < MI; ++mi) {
#pragma unroll
        for (int ni = 0; ni < NI; ++ni) {
            int col = nBase + wc * (NI * 16) + ni * 16 + coll;
            float bv = bias[col];
#pragma unroll
            for (int r = 0; r < 4; ++r) {
                int row = mBase + wr * (MI * 16) + mi * 16 + rowq + r;
                float v = acc[mi][ni][r] + bv;
                if (MODE == 0) {
                    Cb[(size_t)row * E_ + col] = f2bf(v);
                } else {
                    int b = row >> 11, l = row & (L_ - 1);
                    size_t oi = (size_t)l * (B_ * E_) + b * E_ + col;
                    Cf[oi] = v + ident[oi];
                }
            }
        }
    }
}

__global__ __launch_bounds__(256) void k_gemm3(const short* __restrict__ A,
    const short* __restrict__ W0, const short* __restrict__ W1, const short* __restrict__ W2,
    const float* __restrict__ b0, const float* __restrict__ b1, const float* __restrict__ b2,
    short* __restrict__ C0, short* __restrict__ C1, short* __restrict__ C2) {
    int wg = blockIdx.x;
    int sw = (wg & 7) * 96 + (wg >> 3);
    int bx = sw & 7, by = (sw >> 3) & 31, z = sw >> 8;
    const short* Bw = z == 0 ? W0 : (z == 1 ? W1 : W2);
    const float* bias = z == 0 ? b0 : (z == 1 ? b1 : b2);
    short* C = z == 0 ? C0 : (z == 1 ? C1 : C2);
    gemm_body<0, 128, 128>(A, Bw, bias, C, nullptr, nullptr, bx, by);
}

__global__ __launch_bounds__(256) void k_gemmo(const short* __restrict__ A,
                                               const short* __restrict__ Bw,
                                               const float* __restrict__ bias,
                                               float* __restrict__ C,
                                               const float* __restrict__ ident) {
    int wg = blockIdx.x;
    int sw = (wg & 7) * 64 + (wg >> 3);
    int bx = sw & 15, by = sw >> 4;
    gemm_body<1, 128, 64>(A, Bw, bias, nullptr, C, ident, bx, by);
}

// ---- qsum[b][f] = xsum[b]. dot q_w[f] + L*q_b[f]  (f32 exact) ----
__global__ void k_qsum(const float* __restrict__ xsum, const float* __restrict__ qw,
                       const float* __restrict__ qb, float* __restrict__ qsum) {
    int wid = threadIdx.x >> 6, lane = threadIdx.x & 63;
    int gid = blockIdx.x * 4 + wid;
    int b = gid >> 10, f = gid & 1023;
    float s = 0.f;
    for (int e = lane; e < E_; e += 64) s += xsum[b * E_ + e] * qw[f * E_ + e];
#pragma unroll
    for (int off = 32; off; off >>= 1) s += __shfl_xor(s, off);
    if (lane == 0) qsum[gid] = s + (float)L_ * qb[f];
}

// ---- t[b,h,e] = sum_d qsum[b,h*64+d] * k_w[h*64+d, e] ----
__global__ void k_t(const float* __restrict__ qsum, const float* __restrict__ kw,
                    float* __restrict__ tb) {
    int i = blockIdx.x * 256 + threadIdx.x;
    int e = i & 1023, bh = i >> 10;
    int b = bh >> 4, h = bh & 15;
    float s = 0.f;
#pragma unroll
    for (int d = 0; d < HD_; ++d)
        s += qsum[b * E_ + h * HD_ + d] * kw[(size_t)(h * HD_ + d) * E_ + e];
    tb[i] = s;
}

// ---- partial scores over e-quarters ----
__global__ __launch_bounds__(256) void k_score(const float* __restrict__ query,
                                               const float* __restrict__ tb,
                                               float* __restrict__ scorp) {
    __shared__ float xs[64][68];
    __shared__ float ts[16][68];
    int id = blockIdx.x;
    int eq = id >> 6;
    int b = (id >> 5) & 1;
    int n0 = (id & 31) * 64;
    int tid = threadIdx.x;
    int hg = tid & 3, rg = tid >> 2;
    float acc[4] = {0.f, 0.f, 0.f, 0.f};
    for (int e0 = eq * 256; e0 < eq * 256 + 256; e0 += 64) {
        __syncthreads();
        for (int j = tid; j < 1024; j += 256) {
            int r = j >> 4, c4 = (j & 15) * 4;
            float4 v = *reinterpret_cast<const float4*>(
                &query[(size_t)(n0 + r) * (B_ * E_) + b * E_ + e0 + c4]);
            *reinterpret_cast<float4*>(&xs[r][c4]) = v;
        }
        {
            int hh = tid >> 4, c4 = (tid & 15) * 4;
            float4 v = *reinterpret_cast<const float4*>(&tb[(size_t)(b * 16 + hh) * E_ + e0 + c4]);
            *reinterpret_cast<float4*>(&ts[hh][c4]) = v;
        }
        __syncthreads();
        for (int c = 0; c < 64; ++c) {
            float x0 = xs[rg][c];
#pragma unroll
            for (int j = 0; j < 4; ++j) acc[j] += x0 * ts[hg + 4 * j][c];
        }
    }
#pragma unroll
    for (int j = 0; j < 4; ++j) {
        int h = hg + 4 * j;
        scorp[(size_t)eq * 65536 + (size_t)(b * 16 + h) * L_ + n0 + rg] = acc[j];
    }
}

__global__ void k_scred(const float* __restrict__ scorp, float* __restrict__ scor) {
    int i = blockIdx.x * 256 + threadIdx.x;
    float s = ((scorp[i] + scorp[65536 + i]) + scorp[131072 + i]) + scorp[196608 + i];
    scor[i] = SCALE * s;
}

// ---- top-64 per (b,h): wave radix-select; gather selected k rows into
// pre-swizzled bf16 selkb[bh][m][slot^ (m&7)][...] for MFMA staging ----
__global__ __launch_bounds__(256) void k_topk(const float* __restrict__ score,
                                              const short* __restrict__ kb,
                                              short* __restrict__ selkb) {
    __shared__ int sel[4][64];
    int wid = threadIdx.x >> 6, lane = threadIdx.x & 63;
    int bh = blockIdx.x * 4 + wid;  // grid 8
    int b = bh >> 4, h = bh & 15;

    unsigned u[32];
#pragma unroll
    for (int j = 0; j < 32; ++j) {
        unsigned bits = __float_as_uint(score[bh * L_ + j * 64 + lane]);
        u[j] = (bits & 0x80000000u) ? ~bits : (bits | 0x80000000u);
    }
    unsigned prefix = 0;
    int k = TOPK_;
    for (int bit = 31; bit >= 0; --bit) {
        unsigned cand = prefix | (1u << bit);
        int c = 0;
#pragma unroll
        for (int j = 0; j < 32; ++j) c += ((u[j] >> bit) == (cand >> bit)) ? 1 : 0;
#pragma unroll
        for (int off = 32; off; off >>= 1) c += __shfl_xor(c, off);
        if (c >= k) prefix = cand; else k -= c;
    }
    unsigned T = prefix;
    int nStrict = 0;
#pragma unroll
    for (int j = 0; j < 32; ++j) nStrict += (u[j] > T) ? 1 : 0;
#pragma unroll
    for (int off = 32; off; off >>= 1) nStrict += __shfl_xor(nStrict, off);
    int nTies = TOPK_ - nStrict;

    int strictBase = 0, tieBase = 0;
    unsigned long long below = (lane == 0) ? 0ull : ((~0ull) >> (64 - lane));
#pragma unroll
    for (int j = 0; j < 32; ++j) {
        unsigned long long mS = __ballot(u[j] > T);
        unsigned long long mT = __ballot(u[j] == T);
        if (u[j] > T) {
            int slot = strictBase + __popcll(mS & below);
            sel[wid][slot] = j * 64 + lane;
        } else if (u[j] == T) {
            int r = tieBase + __popcll(mT & below);
            if (r < nTies) sel[wid][nStrict + r] = j * 64 + lane;
        }
        strictBase += __popcll(mS);
        tieBase += __popcll(mT);
    }
    __syncthreads();
    for (int m = 0; m < TOPK_; ++m) {
        int idx = sel[wid][m];
        short v = kb[((size_t)b * L_ + idx) * E_ + h * HD_ + lane];
        selkb[(size_t)bh * 4096 + m * 64 + (((lane >> 3) ^ (m & 7)) * 8) + (lane & 7)] = v;
    }
}

// ---- vtb[bh*64+d][l] = v[b,l,h*64+d]  (bf16 transpose for W-MFMA B-operand) ----
__global__ __launch_bounds__(256) void k_vt(const short* __restrict__ vb,
                                            short* __restrict__ vtb) {
    __shared__ short ts[64][68];
    int blk = blockIdx.x;             // 1024 = 32 bh x 32 l-tiles
    int bh = blk >> 5, l0 = (blk & 31) * 64;
    int b = bh >> 4, h = bh & 15;
    int tid = threadIdx.x;
    int l = tid >> 2, d0 = (tid & 3) * 16;
    const short* src = vb + ((size_t)(b * L_ + l0 + l)) * E_ + h * 64 + d0;
    short8 v0 = *reinterpret_cast<const short8*>(src);
    short8 v1 = *reinterpret_cast<const short8*>(src + 8);
#pragma unroll
    for (int j = 0; j < 8; ++j) ts[d0 + j][l] = v0[j];
#pragma unroll
    for (int j = 0; j < 8; ++j) ts[d0 + 8 + j][l] = v1[j];
    __syncthreads();
    int d = tid >> 2, lp = (tid & 3) * 16;
    short* dst = vtb + ((size_t)(bh * 64 + d)) * 2048 + l0 + lp;
#pragma unroll
    for (int j = 0; j < 4; ++j)
        *reinterpret_cast<short4v*>(dst + j * 4) =
            *reinterpret_cast<const short4v*>(&ts[d][lp + j * 4]);
}

// ---- attW: S_k = k.selk^T (MFMA) -> softmax -> Wpart = P2^T v (MFMA) ----
__global__ __launch_bounds__(256) void k_attW(const short* __restrict__ kb,
                                              const short* __restrict__ vtb,
                                              const short* __restrict__ selkb,
                                              float* __restrict__ wpart) {
    __shared__ short sk[4096], kt[4096], vt[4096], pt[4096];
    int wg = blockIdx.x;
    int sw = (wg & 7) * 64 + (wg >> 3);   // XCD swizzle, 512 blocks
    int bh = sw & 31, ch = sw >> 5;       // ch 0..15, chunk = 128 l
    int b = bh >> 4, h = bh & 15;
    int tid = threadIdx.x, w = tid >> 6, lane = tid & 63;
    int lr = lane & 15, kg = lane >> 4;

    // stage selk (pre-swizzled in global; linear copy)
#pragma unroll
    for (int j = 0; j < 2; ++j) {
        int off = (w * 2 + j) * 512;
        __builtin_amdgcn_global_load_lds(
            (const __attribute__((address_space(1))) void*)(selkb + (size_t)bh * 4096 + off + lane * 8),
            (__attribute__((address_space(3))) void*)(sk + off), 16, 0, 0);
    }

    f32x4 accw[4];
#pragma unroll
    for (int i = 0; i < 4; ++i) accw[i] = (f32x4){0.f, 0.f, 0.f, 0.f};

    for (int t = 0; t < 2; ++t) {
        int lt = ch * 128 + t * 64;
        // stage k tile rows (pre-swizzled source -> linear LDS -> swizzled reads)
#pragma unroll
        for (int j = 0; j < 2; ++j) {
            int r = w * 16 + j * 8 + (lane >> 3);
            int s = lane & 7;
            const short* src = kb + ((size_t)(b * L_ + lt + r)) * E_ + h * 64 + ((s ^ (r & 7)) * 8);
            __builtin_amdgcn_global_load_lds(
                (const __attribute__((address_space(1))) void*)src,
                (__attribute__((address_space(3))) void*)(kt + (w * 16 + j * 8) * 64), 16, 0, 0);
        }
        __syncthreads();

        f32x4 s4[4];
#pragma unroll
        for (int i = 0; i < 4; ++i) s4[i] = (f32x4){0.f, 0.f, 0.f, 0.f};
#pragma unroll
        for (int kk = 0; kk < 2; ++kk) {
            int row = w * 16 + lr;
            short8 a = *reinterpret_cast<const short8*>(
                kt + row * 64 + (((kk * 4 + kg) ^ (row & 7)) * 8));
#pragma unroll
            for (int ni = 0; ni < 4; ++ni) {
                int m = ni * 16 + lr;
                short8 bb = *reinterpret_cast<const short8*>(
                    sk + m * 64 + (((kk * 4 + kg) ^ (m & 7)) * 8));
                s4[ni] = __builtin_amdgcn_mfma_f32_16x16x32_bf16(a, bb, s4[ni], 0, 0, 0);
            }
        }
        // softmax over m (rows: C-layout row = kg*4 + r)
        float p[4][4];
#pragma unroll
        for (int r = 0; r < 4; ++r) {
            float v0 = s4[0][r] * SCALE, v1 = s4[1][r] * SCALE;
            float v2 = s4[2][r] * SCALE, v3 = s4[3][r] * SCALE;
            float mx = fmaxf(fmaxf(v0, v1), fmaxf(v2, v3));
            mx = fmaxf(mx, __shfl_xor(mx, 1));
            mx = fmaxf(mx, __shfl_xor(mx, 2));
            mx = fmaxf(mx, __shfl_xor(mx, 4));
            mx = fmaxf(mx, __shfl_xor(mx, 8));
            float e0 = __expf(v0 - mx), e1 = __expf(v1 - mx);
            float e2 = __expf(v2 - mx), e3 = __expf(v3 - mx);
            float sm = e0 + e1 + e2 + e3;
            sm += __shfl_xor(sm, 1);
            sm += __shfl_xor(sm, 2);
            sm += __shfl_xor(sm, 4);
            sm += __shfl_xor(sm, 8);
            float inv = 1.f / sm;
            p[0][r] = e0 * inv; p[1][r] = e1 * inv; p[2][r] = e2 * inv; p[3][r] = e3 * inv;
        }
        // scatter P2^T (bf16, slot-swizzled): pt[m][l]
#pragma unroll
        for (int ni = 0; ni < 4; ++ni)
#pragma unroll
            for (int r = 0; r < 4; ++r) {
                int m = ni * 16 + lr;
                int ll = w * 16 + kg * 4 + r;
                pt[m * 64 + (((ll >> 3) ^ (m & 7)) * 8) + (ll & 7)] = f2bf(p[ni][r]);
            }
        // stage v^T tile rows d (pre-swizzled source)
#pragma unroll
        for (int j = 0; j < 2; ++j) {
            int d = w * 16 + j * 8 + (lane >> 3);
            int s = lane & 7;
            const short* src = vtb + ((size_t)(bh * 64 + d)) * 2048 + lt + ((s ^ (d & 7)) * 8);
            __builtin_amdgcn_global_load_lds(
                (const __attribute__((address_space(1))) void*)src,
                (__attribute__((address_space(3))) void*)(vt + (w * 16 + j * 8) * 64), 16, 0, 0);
        }
        __syncthreads();
        // W-MFMA: W[m][d] += P2^T . v  (A = pt rows m, B = vt rows d, K = l)
#pragma unroll
        for (int kk = 0; kk < 2; ++kk) {
            int mm = w * 16 + lr;
            short8 a = *reinterpret_cast<const short8*>(
                pt + mm * 64 + (((kk * 4 + kg) ^ (mm & 7)) * 8));
#pragma unroll
            for (int ni = 0; ni < 4; ++ni) {
                int d = ni * 16 + lr;
                short8 bb = *reinterpret_cast<const short8*>(
                    vt + d * 64 + (((kk * 4 + kg) ^ (d & 7)) * 8));
                accw[ni] = __builtin_amdgcn_mfma_f32_16x16x32_bf16(a, bb, accw[ni], 0, 0, 0);
            }
        }
    }
#pragma unroll
    for (int ni = 0; ni < 4; ++ni)
#pragma unroll
        for (int r = 0; r < 4; ++r) {
            int m = w * 16 + kg * 4 + r;
            int d = ni * 16 + lr;
            wpart[((size_t)(ch * 32 + bh)) * 4096 + m * 64 + d] = accw[ni][r];
        }
}

// ---- reduce wpart chunks -> Wt global bf16, transposed + pre-swizzled ----
__global__ void k_wreduce(const float* __restrict__ wpart, short* __restrict__ wtg) {
    int i = blockIdx.x * 256 + threadIdx.x;  // 131072, grid 512
    float s = 0.f;
#pragma unroll
    for (int c = 0; c < 16; ++c) s += wpart[(size_t)c * 131072 + i];
    int bh = i >> 12, m = (i >> 6) & 63, d = i & 63;
    wtg[(size_t)bh * 4096 + d * 64 + (((m >> 3) ^ (d & 7)) * 8) + (m & 7)] = f2bf(s);
}

// ---- attO: S_q = q.selk^T (MFMA) -> softmax -> att = P1.W (MFMA) -> bf16 ----
__global__ __launch_bounds__(256) void k_attO(const short* __restrict__ qb,
                                              const short* __restrict__ selkb,
                                              const short* __restrict__ wtg,
                                              short* __restrict__ att) {
    __shared__ short sk[4096], wt[4096], qt[4096], p1[4096];
    int wg = blockIdx.x;
    int sw = (wg & 7) * 64 + (wg >> 3);
    int bh = sw & 31, ch = sw >> 5;
    int b = bh >> 4, h = bh & 15;
    int tid = threadIdx.x, w = tid >> 6, lane = tid & 63;
    int lr = lane & 15, kg = lane >> 4;

#pragma unroll
    for (int j = 0; j < 2; ++j) {
        int off = (w * 2 + j) * 512;
        __builtin_amdgcn_global_load_lds(
            (const __attribute__((address_space(1))) void*)(selkb + (size_t)bh * 4096 + off + lane * 8),
            (__attribute__((address_space(3))) void*)(sk + off), 16, 0, 0);
        __builtin_amdgcn_global_load_lds(
            (const __attribute__((address_space(1))) void*)(wtg + (size_t)bh * 4096 + off + lane * 8),
            (__attribute__((address_space(3))) void*)(wt + off), 16, 0, 0);
    }

    for (int t = 0; t < 2; ++t) {
        int lt = ch * 128 + t * 64;
#pragma unroll
        for (int j = 0; j < 2; ++j) {
            int r = w * 16 + j * 8 + (lane >> 3);
            int s = lane & 7;
            const short* src = qb + ((size_t)(b * L_ + lt + r)) * E_ + h * 64 + ((s ^ (r & 7)) * 8);
            __builtin_amdgcn_global_load_lds(
                (const __attribute__((address_space(1))) void*)src,
                (__attribute__((address_space(3))) void*)(qt + (w * 16 + j * 8) * 64), 16, 0, 0);
        }
        __syncthreads();

        f32x4 s4[4];
#pragma unroll
        for (int i = 0; i < 4; ++i) s4[i] = (f32x4){0.f, 0.f, 0.f, 0.f};
#pragma unroll
        for (int kk = 0; kk < 2; ++kk) {
            int row = w * 16 + lr;
            short8 a = *reinterpret_cast<const short8*>(
                qt + row * 64 + (((kk * 4 + kg) ^ (row & 7)) * 8));
#pragma unroll
            for (int ni = 0; ni < 4; ++ni) {
                int m = ni * 16 + lr;
                short8 bb = *reinterpret_cast<const short8*>(
                    sk + m * 64 + (((kk * 4 + kg) ^ (m & 7)) * 8));
                s4[ni] = __builtin_amdgcn_mfma_f32_16x16x32_bf16(a, bb, s4[ni], 0, 0, 0);
            }
        }
        float p[4][4];
#pragma unroll
        for (int r = 0; r < 4; ++r) {
            float v0 = s4[0][r] * SCALE, v1 = s4[1][r] * SCALE;
            float v2 = s4[2][r] * SCALE, v3 = s4[3][r] * SCALE;
            float mx = fmaxf(fmaxf(v0, v1), fmaxf(v2, v3));
            mx = fmaxf(mx, __shfl_xor(mx, 1));
            mx = fmaxf(mx, __shfl_xor(mx, 2));
            mx = fmaxf(mx, __shfl_xor(mx, 4));
            mx = fmaxf(mx, __shfl_xor(mx, 8));
            float e0 = __expf(v0 - mx), e1 = __expf(v1 - mx);
            float e2 = __expf(v2 - mx), e3 = __expf(v3 - mx);
            float sm = e0 + e1 + e2 + e3;
            sm += __shfl_xor(sm, 1);
            sm += __shfl_xor(sm, 2);
            sm += __shfl_xor(sm, 4);
            sm += __shfl_xor(sm, 8);
            float inv = 1.f / sm;
            p[0][r] = e0 * inv; p[1][r] = e1 * inv; p[2][r] = e2 * inv; p[3][r] = e3 * inv;
        }
        // scatter P1 (row-major [l][m], slot-swizzled)
#pragma unroll
        for (int ni = 0; ni < 4; ++ni)
#pragma unroll
            for (int r = 0; r < 4; ++r) {
                int m = ni * 16 + lr;
                int ll = w * 16 + kg * 4 + r;
                p1[ll * 64 + (((m >> 3) ^ (ll & 7)) * 8) + (m & 7)] = f2bf(p[ni][r]);
            }
        __syncthreads();
        // att-MFMA: att[l][d] = P1 . Wt^T (A = p1 rows l, B = wt rows d, K = m)
        f32x4 ao[4];
#pragma unroll
        for (int i = 0; i < 4; ++i) ao[i] = (f32x4){0.f, 0.f, 0.f, 0.f};
#pragma unroll
        for (int kk = 0; kk < 2; ++kk) {
            int row = w * 16 + lr;
            short8 a = *reinterpret_cast<const short8*>(
                p1 + row * 64 + (((kk * 4 + kg) ^ (row & 7)) * 8));
#pragma unroll
            for (int ni = 0; ni < 4; ++ni) {
                int d = ni * 16 + lr;
                short8 bb = *reinterpret_cast<const short8*>(
                    wt + d * 64 + (((kk * 4 + kg) ^ (d & 7)) * 8));
                ao[ni] = __builtin_amdgcn_mfma_f32_16x16x32_bf16(a, bb, ao[ni], 0, 0, 0);
            }
        }
#pragma unroll
        for (int ni = 0; ni < 4; ++ni)
#pragma unroll
            for (int r = 0; r < 4; ++r) {
                int l = lt + w * 16 + kg * 4 + r;
                int d = ni * 16 + lr;
                att[((size_t)(b * L_ + l)) * E_ + h * 64 + d] = f2bf(ao[ni][r]);
            }
    }
}

extern "C" void kernel_launch(void* const* d_in, const int* in_sizes, int n_in,
                              void* d_out, int out_size, void* d_ws, size_t ws_size,
                              hipStream_t stream) {
    const float* query = (const float*)d_in[0];
    const float* q_w = (const float*)d_in[1];
    const float* q_b = (const float*)d_in[2];
    const float* k_w = (const float*)d_in[3];
    const float* k_b = (const float*)d_in[4];
    const float* v_w = (const float*)d_in[5];
    const float* v_b = (const float*)d_in[6];
    const float* o_w = (const float*)d_in[7];
    const float* o_b = (const float*)d_in[8];
    float* out = (float*)d_out;

    char* p = (char*)d_ws;
    auto alloc = [&](size_t bytes) {
        char* r = p;
        p += (bytes + 255) & ~(size_t)255;
        return r;
    };
    short* xb    = (short*)alloc((size_t)MROWS * E_ * 2);
    short* qwb   = (short*)alloc((size_t)E_ * E_ * 2);
    short* kwb   = (short*)alloc((size_t)E_ * E_ * 2);
    short* vwb   = (short*)alloc((size_t)E_ * E_ * 2);
    short* owb   = (short*)alloc((size_t)E_ * E_ * 2);
    short* qbuf  = (short*)alloc((size_t)MROWS * E_ * 2);
    short* kbuf  = (short*)alloc((size_t)MROWS * E_ * 2);
    short* vbuf  = (short*)alloc((size_t)MROWS * E_ * 2);
    short* vtb   = (short*)alloc((size_t)32 * 64 * 2048 * 2);
    float* xpart = (float*)alloc((size_t)16 * B_ * E_ * 4);
    float* xsum  = (float*)alloc((size_t)B_ * E_ * 4);
    float* qsum  = (float*)alloc((size_t)B_ * E_ * 4);
    float* tb    = (float*)alloc((size_t)B_ * H_ * E_ * 4);
    float* scorp = (float*)alloc((size_t)4 * B_ * H_ * L_ * 4);
    float* scor  = (float*)alloc((size_t)B_ * H_ * L_ * 4);
    short* selkb = (short*)alloc((size_t)32 * 4096 * 2);
    short* wtg   = (short*)alloc((size_t)32 * 4096 * 2);
    float* wpart = (float*)alloc((size_t)16 * 32 * 4096 * 4);
    short* att   = (short*)alloc((size_t)MROWS * E_ * 2);

    // stage 1: casts / transpose / exact sums
    k_prep_x<<<4096, 256, 0, stream>>>(query, xb);
    k_castw<<<4096, 256, 0, stream>>>(q_w, k_w, v_w, o_w, qwb, kwb, vwb, owb);
    k_xsum<<<128, 256, 0, stream>>>(query, xpart);
    k_xred<<<8, 256, 0, stream>>>(xpart, xsum);

    // stage 2: fused q/k/v projections
    k_gemm3<<<768, 256, 0, stream>>>(xb, qwb, kwb, vwb, q_b, k_b, v_b, qbuf, kbuf, vbuf);

    // stage 3: exact f32 scores + top-k + v transpose
    k_qsum<<<512, 256, 0, stream>>>(xsum, q_w, q_b, qsum);
    k_t<<<128, 256, 0, stream>>>(qsum, k_w, tb);
    k_score<<<256, 256, 0, stream>>>(query, tb, scorp);
    k_scred<<<256, 256, 0, stream>>>(scorp, scor);
    k_topk<<<8, 256, 0, stream>>>(scor, kbuf, selkb);
    k_vt<<<1024, 256, 0, stream>>>(vbuf, vtb);

    // stage 4: MFMA attention core
    k_attW<<<512, 256, 0, stream>>>(kbuf, vtb, selkb, wpart);
    k_wreduce<<<512, 256, 0, stream>>>(wpart, wtg);
    k_attO<<<512, 256, 0, stream>>>(qbuf, selkb, wtg, att);

    // stage 5: o-projection fused with bias + residual + transpose back
    k_gemmo<<<512, 256, 0, stream>>>(att, owb, o_b, out, query);
}

// Round 5
// 193.826 us; speedup vs baseline: 2.3441x; 1.0039x over previous
//
#include <hip/hip_runtime.h>
#include <hip/hip_bf16.h>

#define L_ 2048
#define B_ 2
#define E_ 1024
#define H_ 16
#define HD_ 64
#define TOPK_ 64
#define MROWS (B_*L_)
#define SCALE 0.125f

typedef __attribute__((ext_vector_type(8))) short short8;
typedef __attribute__((ext_vector_type(4))) short short4v;
typedef __attribute__((ext_vector_type(4))) float f32x4;

static __device__ __forceinline__ short f2bf(float f) {
    __hip_bfloat16 h = __float2bfloat16(f);
    return *reinterpret_cast<short*>(&h);
}
static __device__ __forceinline__ float bf2f(short s) {
    unsigned u = ((unsigned)(unsigned short)s) << 16;
    return __uint_as_float(u);
}

// ---- merged: transpose [L,B,E] f32 -> [B,L,E] bf16  +  cast 4 weight mats ----
__global__ void k_prep(const float* __restrict__ q,
                       const float* __restrict__ w0, const float* __restrict__ w1,
                       const float* __restrict__ w2, const float* __restrict__ w3,
                       short* __restrict__ xb,
                       short* __restrict__ o0, short* __restrict__ o1,
                       short* __restrict__ o2, short* __restrict__ o3) {
    int blk = blockIdx.x;
    if (blk < 4096) {
        int i = blk * 256 + threadIdx.x;
        int idx = i * 4;
        int e = idx & (E_ - 1);
        int l = (idx >> 10) & (L_ - 1);
        int b = idx >> 21;
        float4 v = *reinterpret_cast<const float4*>(q + l * (B_ * E_) + b * E_ + e);
        short4v o;
        o[0] = f2bf(v.x); o[1] = f2bf(v.y); o[2] = f2bf(v.z); o[3] = f2bf(v.w);
        *reinterpret_cast<short4v*>(xb + idx) = o;
    } else {
        int cb = blk - 4096;
        int sel = cb >> 10, lb = cb & 1023;
        const float* w = sel == 0 ? w0 : sel == 1 ? w1 : sel == 2 ? w2 : w3;
        short* o = sel == 0 ? o0 : sel == 1 ? o1 : sel == 2 ? o2 : o3;
        int i = lb * 256 + threadIdx.x;
        float4 v = *reinterpret_cast<const float4*>(w + i * 4);
        short4v s;
        s[0] = f2bf(v.x); s[1] = f2bf(v.y); s[2] = f2bf(v.z); s[3] = f2bf(v.w);
        *reinterpret_cast<short4v*>(o + i * 4) = s;
    }
}

// ---- xpart[ch][col] = sum over 128 l of query[l*2048 + col] ----
__global__ void k_xsum(const float* __restrict__ q, float* __restrict__ xpart) {
    int cg = blockIdx.x & 7, ch = blockIdx.x >> 3;  // grid 128
    int col = cg * 256 + threadIdx.x;
    float s = 0.f;
    for (int l = ch * 128; l < (ch + 1) * 128; ++l) s += q[(size_t)l * (B_ * E_) + col];
    xpart[ch * (B_ * E_) + col] = s;
}
__global__ void k_xred(const float* __restrict__ xpart, float* __restrict__ xsum) {
    int col = blockIdx.x * 256 + threadIdx.x;  // grid 8
    float s = 0.f;
#pragma unroll
    for (int c = 0; c < 16; ++c) s += xpart[c * (B_ * E_) + col];
    xsum[col] = s;
}

// ---- GEMM core, double-buffered 2-phase: issue next-tile stage BEFORE compute,
// one vmcnt(0)+barrier per K-tile (T3 minimum recipe) ----
template<int MODE, int BM, int BN>
__device__ __forceinline__ void gemm_body(const short* __restrict__ A,
                                          const short* __restrict__ Bw,
                                          const float* __restrict__ bias,
                                          short* __restrict__ Cb,
                                          float* __restrict__ Cf,
                                          const float* __restrict__ ident,
                                          int bx, int by) {
    const int K = E_;
    constexpr int MI = BM / 32;
    constexpr int NI = BN / 32;
    __shared__ short As[2][BM * 64];
    __shared__ short Bs[2][BN * 64];
    int tid = threadIdx.x;
    int lane = tid & 63;
    int wid = tid >> 6;
    int wr = wid >> 1, wc = wid & 1;
    int lrow = lane & 15;
    int kg = lane >> 4;
    int lr8 = lane >> 3;
    int lc8 = (lane & 7) * 8;
    int mBase = by * BM, nBase = bx * BN;

    auto STAGE = [&](int buf, int k0) {
#pragma unroll
        for (int i = 0; i < BM / 32; ++i) {
            int r0 = (wid * (BM / 32) + i) * 8;
            const short* ga = A + (size_t)(mBase + r0 + lr8) * K + k0 + lc8;
            __builtin_amdgcn_global_load_lds(
                (const __attribute__((address_space(1))) void*)ga,
                (__attribute__((address_space(3))) void*)(&As[buf][r0 * 64]), 16, 0, 0);
        }
#pragma unroll
        for (int i = 0; i < BN / 32; ++i) {
            int r0 = (wid * (BN / 32) + i) * 8;
            const short* gb = Bw + (size_t)(nBase + r0 + lr8) * K + k0 + lc8;
            __builtin_amdgcn_global_load_lds(
                (const __attribute__((address_space(1))) void*)gb,
                (__attribute__((address_space(3))) void*)(&Bs[buf][r0 * 64]), 16, 0, 0);
        }
    };

    f32x4 acc[MI][NI];
#pragma unroll
    for (int i = 0; i < MI; ++i)
#pragma unroll
        for (int j = 0; j < NI; ++j) acc[i][j] = (f32x4){0.f, 0.f, 0.f, 0.f};

    STAGE(0, 0);
    asm volatile("s_waitcnt vmcnt(0)" ::: "memory");
    __syncthreads();

    int cur = 0;
    for (int k0 = 0; k0 < K; k0 += 64) {
        if (k0 + 64 < K) STAGE(cur ^ 1, k0 + 64);   // prefetch overlaps compute below

        short8 af[2][MI], bf[2][NI];
#pragma unroll
        for (int kk = 0; kk < 2; ++kk) {
#pragma unroll
            for (int mi = 0; mi < MI; ++mi)
                af[kk][mi] = *reinterpret_cast<const short8*>(
                    &As[cur][(wr * (MI * 16) + mi * 16 + lrow) * 64 + kk * 32 + kg * 8]);
#pragma unroll
            for (int ni = 0; ni < NI; ++ni)
                bf[kk][ni] = *reinterpret_cast<const short8*>(
                    &Bs[cur][(wc * (NI * 16) + ni * 16 + lrow) * 64 + kk * 32 + kg * 8]);
        }
#pragma unroll
        for (int kk = 0; kk < 2; ++kk)
#pragma unroll
            for (int mi = 0; mi < MI; ++mi)
#pragma unroll
                for (int ni = 0; ni < NI; ++ni)
                    acc[mi][ni] = __builtin_amdgcn_mfma_f32_16x16x32_bf16(
                        af[kk][mi], bf[kk][ni], acc[mi][ni], 0, 0, 0);

        asm volatile("s_waitcnt vmcnt(0)" ::: "memory");
        __syncthreads();
        cur ^= 1;
    }

    int rowq = (lane >> 4) * 4;
    int coll = lane & 15;
#pragma unroll
    for (int mi = 0; mi < MI; ++mi) {
#pragma unroll
        for (int ni = 0; ni < NI; ++ni) {
            int col = nBase + wc * (NI * 16) + ni * 16 + coll;
            float bv = bias[col];
#pragma unroll
            for (int r = 0; r < 4; ++r) {
                int row = mBase + wr * (MI * 16) + mi * 16 + rowq + r;
                float v = acc[mi][ni][r] + bv;
                if (MODE == 0) {
                    Cb[(size_t)row * E_ + col] = f2bf(v);
                } else {
                    int b = row >> 11, l = row & (L_ - 1);
                    size_t oi = (size_t)l * (B_ * E_) + b * E_ + col;
                    Cf[oi] = v + ident[oi];
                }
            }
        }
    }
}

__global__ __launch_bounds__(256) void k_gemm3(const short* __restrict__ A,
    const short* __restrict__ W0, const short* __restrict__ W1, const short* __restrict__ W2,
    const float* __restrict__ b0, const float* __restrict__ b1, const float* __restrict__ b2,
    short* __restrict__ C0, short* __restrict__ C1, short* __restrict__ C2) {
    int wg = blockIdx.x;
    int sw = (wg & 7) * 96 + (wg >> 3);
    int bx = sw & 7, by = (sw >> 3) & 31, z = sw >> 8;
    const short* Bw = z == 0 ? W0 : (z == 1 ? W1 : W2);
    const float* bias = z == 0 ? b0 : (z == 1 ? b1 : b2);
    short* C = z == 0 ? C0 : (z == 1 ? C1 : C2);
    gemm_body<0, 128, 128>(A, Bw, bias, C, nullptr, nullptr, bx, by);
}

__global__ __launch_bounds__(256) void k_gemmo(const short* __restrict__ A,
                                               const short* __restrict__ Bw,
                                               const float* __restrict__ bias,
                                               float* __restrict__ C,
                                               const float* __restrict__ ident) {
    int wg = blockIdx.x;
    int sw = (wg & 7) * 64 + (wg >> 3);
    int bx = sw & 15, by = sw >> 4;
    gemm_body<1, 128, 64>(A, Bw, bias, nullptr, C, ident, bx, by);
}

// ---- qsum[b][f] = xsum[b]. dot q_w[f] + L*q_b[f]  (f32 exact) ----
__global__ void k_qsum(const float* __restrict__ xsum, const float* __restrict__ qw,
                       const float* __restrict__ qb, float* __restrict__ qsum) {
    int wid = threadIdx.x >> 6, lane = threadIdx.x & 63;
    int gid = blockIdx.x * 4 + wid;
    int b = gid >> 10, f = gid & 1023;
    float s = 0.f;
    for (int e = lane; e < E_; e += 64) s += xsum[b * E_ + e] * qw[f * E_ + e];
#pragma unroll
    for (int off = 32; off; off >>= 1) s += __shfl_xor(s, off);
    if (lane == 0) qsum[gid] = s + (float)L_ * qb[f];
}

// ---- t[b,h,e] = sum_d qsum[b,h*64+d] * k_w[h*64+d, e] ----
__global__ void k_t(const float* __restrict__ qsum, const float* __restrict__ kw,
                    float* __restrict__ tb) {
    int i = blockIdx.x * 256 + threadIdx.x;
    int e = i & 1023, bh = i >> 10;
    int b = bh >> 4, h = bh & 15;
    float s = 0.f;
#pragma unroll
    for (int d = 0; d < HD_; ++d)
        s += qsum[b * E_ + h * HD_ + d] * kw[(size_t)(h * HD_ + d) * E_ + e];
    tb[i] = s;
}

// ---- partial scores over e-quarters ----
__global__ __launch_bounds__(256) void k_score(const float* __restrict__ query,
                                               const float* __restrict__ tb,
                                               float* __restrict__ scorp) {
    __shared__ float xs[64][68];
    __shared__ float ts[16][68];
    int id = blockIdx.x;
    int eq = id >> 6;
    int b = (id >> 5) & 1;
    int n0 = (id & 31) * 64;
    int tid = threadIdx.x;
    int hg = tid & 3, rg = tid >> 2;
    float acc[4] = {0.f, 0.f, 0.f, 0.f};
    for (int e0 = eq * 256; e0 < eq * 256 + 256; e0 += 64) {
        __syncthreads();
        for (int j = tid; j < 1024; j += 256) {
            int r = j >> 4, c4 = (j & 15) * 4;
            float4 v = *reinterpret_cast<const float4*>(
                &query[(size_t)(n0 + r) * (B_ * E_) + b * E_ + e0 + c4]);
            *reinterpret_cast<float4*>(&xs[r][c4]) = v;
        }
        {
            int hh = tid >> 4, c4 = (tid & 15) * 4;
            float4 v = *reinterpret_cast<const float4*>(&tb[(size_t)(b * 16 + hh) * E_ + e0 + c4]);
            *reinterpret_cast<float4*>(&ts[hh][c4]) = v;
        }
        __syncthreads();
        for (int c = 0; c < 64; ++c) {
            float x0 = xs[rg][c];
#pragma unroll
            for (int j = 0; j < 4; ++j) acc[j] += x0 * ts[hg + 4 * j][c];
        }
    }
#pragma unroll
    for (int j = 0; j < 4; ++j) {
        int h = hg + 4 * j;
        scorp[(size_t)eq * 65536 + (size_t)(b * 16 + h) * L_ + n0 + rg] = acc[j];
    }
}

// ---- top-64 per (b,h): fused e-quarter reduce + wave radix-select; gather
// selected k rows into pre-swizzled bf16 selkb for MFMA staging ----
__global__ __launch_bounds__(256) void k_topk(const float* __restrict__ scorp,
                                              const short* __restrict__ kb,
                                              short* __restrict__ selkb) {
    __shared__ int sel[4][64];
    int wid = threadIdx.x >> 6, lane = threadIdx.x & 63;
    int bh = blockIdx.x * 4 + wid;  // grid 8
    int b = bh >> 4, h = bh & 15;

    unsigned u[32];
#pragma unroll
    for (int j = 0; j < 32; ++j) {
        int base = bh * L_ + j * 64 + lane;
        float sc = ((scorp[base] + scorp[base + 65536]) + scorp[base + 131072]) + scorp[base + 196608];
        sc *= SCALE;
        unsigned bits = __float_as_uint(sc);
        u[j] = (bits & 0x80000000u) ? ~bits : (bits | 0x80000000u);
    }
    unsigned prefix = 0;
    int k = TOPK_;
    for (int bit = 31; bit >= 0; --bit) {
        unsigned cand = prefix | (1u << bit);
        int c = 0;
#pragma unroll
        for (int j = 0; j < 32; ++j) c += ((u[j] >> bit) == (cand >> bit)) ? 1 : 0;
#pragma unroll
        for (int off = 32; off; off >>= 1) c += __shfl_xor(c, off);
        if (c >= k) prefix = cand; else k -= c;
    }
    unsigned T = prefix;
    int nStrict = 0;
#pragma unroll
    for (int j = 0; j < 32; ++j) nStrict += (u[j] > T) ? 1 : 0;
#pragma unroll
    for (int off = 32; off; off >>= 1) nStrict += __shfl_xor(nStrict, off);
    int nTies = TOPK_ - nStrict;

    int strictBase = 0, tieBase = 0;
    unsigned long long below = (lane == 0) ? 0ull : ((~0ull) >> (64 - lane));
#pragma unroll
    for (int j = 0; j < 32; ++j) {
        unsigned long long mS = __ballot(u[j] > T);
        unsigned long long mT = __ballot(u[j] == T);
        if (u[j] > T) {
            int slot = strictBase + __popcll(mS & below);
            sel[wid][slot] = j * 64 + lane;
        } else if (u[j] == T) {
            int r = tieBase + __popcll(mT & below);
            if (r < nTies) sel[wid][nStrict + r] = j * 64 + lane;
        }
        strictBase += __popcll(mS);
        tieBase += __popcll(mT);
    }
    __syncthreads();
    for (int m = 0; m < TOPK_; ++m) {
        int idx = sel[wid][m];
        short v = kb[((size_t)b * L_ + idx) * E_ + h * HD_ + lane];
        selkb[(size_t)bh * 4096 + m * 64 + (((lane >> 3) ^ (m & 7)) * 8) + (lane & 7)] = v;
    }
}

// ---- vtb[bh*64+d][l] = v[b,l,h*64+d]  (bf16 transpose for W-MFMA B-operand) ----
__global__ __launch_bounds__(256) void k_vt(const short* __restrict__ vb,
                                            short* __restrict__ vtb) {
    __shared__ short ts[64][68];
    int blk = blockIdx.x;             // 1024 = 32 bh x 32 l-tiles
    int bh = blk >> 5, l0 = (blk & 31) * 64;
    int b = bh >> 4, h = bh & 15;
    int tid = threadIdx.x;
    int l = tid >> 2, d0 = (tid & 3) * 16;
    const short* src = vb + ((size_t)(b * L_ + l0 + l)) * E_ + h * 64 + d0;
    short8 v0 = *reinterpret_cast<const short8*>(src);
    short8 v1 = *reinterpret_cast<const short8*>(src + 8);
#pragma unroll
    for (int j = 0; j < 8; ++j) ts[d0 + j][l] = v0[j];
#pragma unroll
    for (int j = 0; j < 8; ++j) ts[d0 + 8 + j][l] = v1[j];
    __syncthreads();
    int d = tid >> 2, lp = (tid & 3) * 16;
    short* dst = vtb + ((size_t)(bh * 64 + d)) * 2048 + l0 + lp;
#pragma unroll
    for (int j = 0; j < 4; ++j)
        *reinterpret_cast<short4v*>(dst + j * 4) =
            *reinterpret_cast<const short4v*>(&ts[d][lp + j * 4]);
}

// ---- attW: S_k = k.selk^T (MFMA) -> softmax -> Wpart = P2^T v (MFMA) ----
__global__ __launch_bounds__(256) void k_attW(const short* __restrict__ kb,
                                              const short* __restrict__ vtb,
                                              const short* __restrict__ selkb,
                                              float* __restrict__ wpart) {
    __shared__ short sk[4096], kt[4096], vt[4096], pt[4096];
    int wg = blockIdx.x;
    int sw = (wg & 7) * 64 + (wg >> 3);   // XCD swizzle, 512 blocks
    int bh = sw & 31, ch = sw >> 5;       // ch 0..15, chunk = 128 l
    int b = bh >> 4, h = bh & 15;
    int tid = threadIdx.x, w = tid >> 6, lane = tid & 63;
    int lr = lane & 15, kg = lane >> 4;

#pragma unroll
    for (int j = 0; j < 2; ++j) {
        int off = (w * 2 + j) * 512;
        __builtin_amdgcn_global_load_lds(
            (const __attribute__((address_space(1))) void*)(selkb + (size_t)bh * 4096 + off + lane * 8),
            (__attribute__((address_space(3))) void*)(sk + off), 16, 0, 0);
    }

    f32x4 accw[4];
#pragma unroll
    for (int i = 0; i < 4; ++i) accw[i] = (f32x4){0.f, 0.f, 0.f, 0.f};

    for (int t = 0; t < 2; ++t) {
        int lt = ch * 128 + t * 64;
#pragma unroll
        for (int j = 0; j < 2; ++j) {
            int r = w * 16 + j * 8 + (lane >> 3);
            int s = lane & 7;
            const short* src = kb + ((size_t)(b * L_ + lt + r)) * E_ + h * 64 + ((s ^ (r & 7)) * 8);
            __builtin_amdgcn_global_load_lds(
                (const __attribute__((address_space(1))) void*)src,
                (__attribute__((address_space(3))) void*)(kt + (w * 16 + j * 8) * 64), 16, 0, 0);
        }
        __syncthreads();

        f32x4 s4[4];
#pragma unroll
        for (int i = 0; i < 4; ++i) s4[i] = (f32x4){0.f, 0.f, 0.f, 0.f};
#pragma unroll
        for (int kk = 0; kk < 2; ++kk) {
            int row = w * 16 + lr;
            short8 a = *reinterpret_cast<const short8*>(
                kt + row * 64 + (((kk * 4 + kg) ^ (row & 7)) * 8));
#pragma unroll
            for (int ni = 0; ni < 4; ++ni) {
                int m = ni * 16 + lr;
                short8 bb = *reinterpret_cast<const short8*>(
                    sk + m * 64 + (((kk * 4 + kg) ^ (m & 7)) * 8));
                s4[ni] = __builtin_amdgcn_mfma_f32_16x16x32_bf16(a, bb, s4[ni], 0, 0, 0);
            }
        }
        float p[4][4];
#pragma unroll
        for (int r = 0; r < 4; ++r) {
            float v0 = s4[0][r] * SCALE, v1 = s4[1][r] * SCALE;
            float v2 = s4[2][r] * SCALE, v3 = s4[3][r] * SCALE;
            float mx = fmaxf(fmaxf(v0, v1), fmaxf(v2, v3));
            mx = fmaxf(mx, __shfl_xor(mx, 1));
            mx = fmaxf(mx, __shfl_xor(mx, 2));
            mx = fmaxf(mx, __shfl_xor(mx, 4));
            mx = fmaxf(mx, __shfl_xor(mx, 8));
            float e0 = __expf(v0 - mx), e1 = __expf(v1 - mx);
            float e2 = __expf(v2 - mx), e3 = __expf(v3 - mx);
            float sm = e0 + e1 + e2 + e3;
            sm += __shfl_xor(sm, 1);
            sm += __shfl_xor(sm, 2);
            sm += __shfl_xor(sm, 4);
            sm += __shfl_xor(sm, 8);
            float inv = 1.f / sm;
            p[0][r] = e0 * inv; p[1][r] = e1 * inv; p[2][r] = e2 * inv; p[3][r] = e3 * inv;
        }
#pragma unroll
        for (int ni = 0; ni < 4; ++ni)
#pragma unroll
            for (int r = 0; r < 4; ++r) {
                int m = ni * 16 + lr;
                int ll = w * 16 + kg * 4 + r;
                pt[m * 64 + (((ll >> 3) ^ (m & 7)) * 8) + (ll & 7)] = f2bf(p[ni][r]);
            }
#pragma unroll
        for (int j = 0; j < 2; ++j) {
            int d = w * 16 + j * 8 + (lane >> 3);
            int s = lane & 7;
            const short* src = vtb + ((size_t)(bh * 64 + d)) * 2048 + lt + ((s ^ (d & 7)) * 8);
            __builtin_amdgcn_global_load_lds(
                (const __attribute__((address_space(1))) void*)src,
                (__attribute__((address_space(3))) void*)(vt + (w * 16 + j * 8) * 64), 16, 0, 0);
        }
        __syncthreads();
#pragma unroll
        for (int kk = 0; kk < 2; ++kk) {
            int mm = w * 16 + lr;
            short8 a = *reinterpret_cast<const short8*>(
                pt + mm * 64 + (((kk * 4 + kg) ^ (mm & 7)) * 8));
#pragma unroll
            for (int ni = 0; ni < 4; ++ni) {
                int d = ni * 16 + lr;
                short8 bb = *reinterpret_cast<const short8*>(
                    vt + d * 64 + (((kk * 4 + kg) ^ (d & 7)) * 8));
                accw[ni] = __builtin_amdgcn_mfma_f32_16x16x32_bf16(a, bb, accw[ni], 0, 0, 0);
            }
        }
    }
#pragma unroll
    for (int ni = 0; ni < 4; ++ni)
#pragma unroll
        for (int r = 0; r < 4; ++r) {
            int m = w * 16 + kg * 4 + r;
            int d = ni * 16 + lr;
            wpart[((size_t)(ch * 32 + bh)) * 4096 + m * 64 + d] = accw[ni][r];
        }
}

// ---- reduce wpart chunks -> Wt global bf16, transposed + pre-swizzled ----
__global__ void k_wreduce(const float* __restrict__ wpart, short* __restrict__ wtg) {
    int i = blockIdx.x * 256 + threadIdx.x;  // 131072, grid 512
    float s = 0.f;
#pragma unroll
    for (int c = 0; c < 16; ++c) s += wpart[(size_t)c * 131072 + i];
    int bh = i >> 12, m = (i >> 6) & 63, d = i & 63;
    wtg[(size_t)bh * 4096 + d * 64 + (((m >> 3) ^ (d & 7)) * 8) + (m & 7)] = f2bf(s);
}

// ---- attO: S_q = q.selk^T (MFMA) -> softmax -> att = P1.W (MFMA) -> bf16 ----
__global__ __launch_bounds__(256) void k_attO(const short* __restrict__ qb,
                                              const short* __restrict__ selkb,
                                              const short* __restrict__ wtg,
                                              short* __restrict__ att) {
    __shared__ short sk[4096], wt[4096], qt[4096], p1[4096];
    int wg = blockIdx.x;
    int sw = (wg & 7) * 64 + (wg >> 3);
    int bh = sw & 31, ch = sw >> 5;
    int b = bh >> 4, h = bh & 15;
    int tid = threadIdx.x, w = tid >> 6, lane = tid & 63;
    int lr = lane & 15, kg = lane >> 4;

#pragma unroll
    for (int j = 0; j < 2; ++j) {
        int off = (w * 2 + j) * 512;
        __builtin_amdgcn_global_load_lds(
            (const __attribute__((address_space(1))) void*)(selkb + (size_t)bh * 4096 + off + lane * 8),
            (__attribute__((address_space(3))) void*)(sk + off), 16, 0, 0);
        __builtin_amdgcn_global_load_lds(
            (const __attribute__((address_space(1))) void*)(wtg + (size_t)bh * 4096 + off + lane * 8),
            (__attribute__((address_space(3))) void*)(wt + off), 16, 0, 0);
    }

    for (int t = 0; t < 2; ++t) {
        int lt = ch * 128 + t * 64;
#pragma unroll
        for (int j = 0; j < 2; ++j) {
            int r = w * 16 + j * 8 + (lane >> 3);
            int s = lane & 7;
            const short* src = qb + ((size_t)(b * L_ + lt + r)) * E_ + h * 64 + ((s ^ (r & 7)) * 8);
            __builtin_amdgcn_global_load_lds(
                (const __attribute__((address_space(1))) void*)src,
                (__attribute__((address_space(3))) void*)(qt + (w * 16 + j * 8) * 64), 16, 0, 0);
        }
        __syncthreads();

        f32x4 s4[4];
#pragma unroll
        for (int i = 0; i < 4; ++i) s4[i] = (f32x4){0.f, 0.f, 0.f, 0.f};
#pragma unroll
        for (int kk = 0; kk < 2; ++kk) {
            int row = w * 16 + lr;
            short8 a = *reinterpret_cast<const short8*>(
                qt + row * 64 + (((kk * 4 + kg) ^ (row & 7)) * 8));
#pragma unroll
            for (int ni = 0; ni < 4; ++ni) {
                int m = ni * 16 + lr;
                short8 bb = *reinterpret_cast<const short8*>(
                    sk + m * 64 + (((kk * 4 + kg) ^ (m & 7)) * 8));
                s4[ni] = __builtin_amdgcn_mfma_f32_16x16x32_bf16(a, bb, s4[ni], 0, 0, 0);
            }
        }
        float p[4][4];
#pragma unroll
        for (int r = 0; r < 4; ++r) {
            float v0 = s4[0][r] * SCALE, v1 = s4[1][r] * SCALE;
            float v2 = s4[2][r] * SCALE, v3 = s4[3][r] * SCALE;
            float mx = fmaxf(fmaxf(v0, v1), fmaxf(v2, v3));
            mx = fmaxf(mx, __shfl_xor(mx, 1));
            mx = fmaxf(mx, __shfl_xor(mx, 2));
            mx = fmaxf(mx, __shfl_xor(mx, 4));
            mx = fmaxf(mx, __shfl_xor(mx, 8));
            float e0 = __expf(v0 - mx), e1 = __expf(v1 - mx);
            float e2 = __expf(v2 - mx), e3 = __expf(v3 - mx);
            float sm = e0 + e1 + e2 + e3;
            sm += __shfl_xor(sm, 1);
            sm += __shfl_xor(sm, 2);
            sm += __shfl_xor(sm, 4);
            sm += __shfl_xor(sm, 8);
            float inv = 1.f / sm;
            p[0][r] = e0 * inv; p[1][r] = e1 * inv; p[2][r] = e2 * inv; p[3][r] = e3 * inv;
        }
#pragma unroll
        for (int ni = 0; ni < 4; ++ni)
#pragma unroll
            for (int r = 0; r < 4; ++r) {
                int m = ni * 16 + lr;
                int ll = w * 16 + kg * 4 + r;
                p1[ll * 64 + (((m >> 3) ^ (ll & 7)) * 8) + (m & 7)] = f2bf(p[ni][r]);
            }
        __syncthreads();
        f32x4 ao[4];
#pragma unroll
        for (int i = 0; i < 4; ++i) ao[i] = (f32x4){0.f, 0.f, 0.f, 0.f};
#pragma unroll
        for (int kk = 0; kk < 2; ++kk) {
            int row = w * 16 + lr;
            short8 a = *reinterpret_cast<const short8*>(
                p1 + row * 64 + (((kk * 4 + kg) ^ (row & 7)) * 8));
#pragma unroll
            for (int ni = 0; ni < 4; ++ni) {
                int d = ni * 16 + lr;
                short8 bb = *reinterpret_cast<const short8*>(
                    wt + d * 64 + (((kk * 4 + kg) ^ (d & 7)) * 8));
                ao[ni] = __builtin_amdgcn_mfma_f32_16x16x32_bf16(a, bb, ao[ni], 0, 0, 0);
            }
        }
#pragma unroll
        for (int ni = 0; ni < 4; ++ni)
#pragma unroll
            for (int r = 0; r < 4; ++r) {
                int l = lt + w * 16 + kg * 4 + r;
                int d = ni * 16 + lr;
                att[((size_t)(b * L_ + l)) * E_ + h * 64 + d] = f2bf(ao[ni][r]);
            }
    }
}

extern "C" void kernel_launch(void* const* d_in, const int* in_sizes, int n_in,
                              void* d_out, int out_size, void* d_ws, size_t ws_size,
                              hipStream_t stream) {
    const float* query = (const float*)d_in[0];
    const float* q_w = (const float*)d_in[1];
    const float* q_b = (const float*)d_in[2];
    const float* k_w = (const float*)d_in[3];
    const float* k_b = (const float*)d_in[4];
    const float* v_w = (const float*)d_in[5];
    const float* v_b = (const float*)d_in[6];
    const float* o_w = (const float*)d_in[7];
    const float* o_b = (const float*)d_in[8];
    float* out = (float*)d_out;

    char* p = (char*)d_ws;
    auto alloc = [&](size_t bytes) {
        char* r = p;
        p += (bytes + 255) & ~(size_t)255;
        return r;
    };
    short* xb    = (short*)alloc((size_t)MROWS * E_ * 2);
    short* qwb   = (short*)alloc((size_t)E_ * E_ * 2);
    short* kwb   = (short*)alloc((size_t)E_ * E_ * 2);
    short* vwb   = (short*)alloc((size_t)E_ * E_ * 2);
    short* owb   = (short*)alloc((size_t)E_ * E_ * 2);
    short* qbuf  = (short*)alloc((size_t)MROWS * E_ * 2);
    short* kbuf  = (short*)alloc((size_t)MROWS * E_ * 2);
    short* vbuf  = (short*)alloc((size_t)MROWS * E_ * 2);
    short* vtb   = (short*)alloc((size_t)32 * 64 * 2048 * 2);
    float* xpart = (float*)alloc((size_t)16 * B_ * E_ * 4);
    float* xsum  = (float*)alloc((size_t)B_ * E_ * 4);
    float* qsum  = (float*)alloc((size_t)B_ * E_ * 4);
    float* tb    = (float*)alloc((size_t)B_ * H_ * E_ * 4);
    float* scorp = (float*)alloc((size_t)4 * B_ * H_ * L_ * 4);
    short* selkb = (short*)alloc((size_t)32 * 4096 * 2);
    short* wtg   = (short*)alloc((size_t)32 * 4096 * 2);
    float* wpart = (float*)alloc((size_t)16 * 32 * 4096 * 4);
    short* att   = (short*)alloc((size_t)MROWS * E_ * 2);

    // stage 1: merged transpose+casts, exact sums
    k_prep<<<8192, 256, 0, stream>>>(query, q_w, k_w, v_w, o_w, xb, qwb, kwb, vwb, owb);
    k_xsum<<<128, 256, 0, stream>>>(query, xpart);
    k_xred<<<8, 256, 0, stream>>>(xpart, xsum);

    // stage 2: fused q/k/v projections (double-buffered 2-phase)
    k_gemm3<<<768, 256, 0, stream>>>(xb, qwb, kwb, vwb, q_b, k_b, v_b, qbuf, kbuf, vbuf);

    // stage 3: exact f32 scores + fused top-k + v transpose
    k_qsum<<<512, 256, 0, stream>>>(xsum, q_w, q_b, qsum);
    k_t<<<128, 256, 0, stream>>>(qsum, k_w, tb);
    k_score<<<256, 256, 0, stream>>>(query, tb, scorp);
    k_topk<<<8, 256, 0, stream>>>(scorp, kbuf, selkb);
    k_vt<<<1024, 256, 0, stream>>>(vbuf, vtb);

    // stage 4: MFMA attention core
    k_attW<<<512, 256, 0, stream>>>(kbuf, vtb, selkb, wpart);
    k_wreduce<<<512, 256, 0, stream>>>(wpart, wtg);
    k_attO<<<512, 256, 0, stream>>>(qbuf, selkb, wtg, att);

    // stage 5: o-projection fused with bias + residual + transpose back
    k_gemmo<<<512, 256, 0, stream>>>(att, owb, o_b, out, query);
}

// Round 6
// 175.944 us; speedup vs baseline: 2.5823x; 1.1016x over previous
//
#include <hip/hip_runtime.h>
#include <hip/hip_bf16.h>

#define L_ 2048
#define B_ 2
#define E_ 1024
#define H_ 16
#define HD_ 64
#define TOPK_ 64
#define MROWS (B_*L_)
#define SCALE 0.125f

typedef __attribute__((ext_vector_type(8))) short short8;
typedef __attribute__((ext_vector_type(4))) short short4v;
typedef __attribute__((ext_vector_type(4))) float f32x4;

static __device__ __forceinline__ short f2bf(float f) {
    __hip_bfloat16 h = __float2bfloat16(f);
    return *reinterpret_cast<short*>(&h);
}
static __device__ __forceinline__ float bf2f(short s) {
    unsigned u = ((unsigned)(unsigned short)s) << 16;
    return __uint_as_float(u);
}

// ---- merged: transpose [L,B,E] f32 -> [B,L,E] bf16  +  cast 4 weight mats ----
__global__ void k_prep(const float* __restrict__ q,
                       const float* __restrict__ w0, const float* __restrict__ w1,
                       const float* __restrict__ w2, const float* __restrict__ w3,
                       short* __restrict__ xb,
                       short* __restrict__ o0, short* __restrict__ o1,
                       short* __restrict__ o2, short* __restrict__ o3) {
    int blk = blockIdx.x;
    if (blk < 4096) {
        int i = blk * 256 + threadIdx.x;
        int idx = i * 4;
        int e = idx & (E_ - 1);
        int l = (idx >> 10) & (L_ - 1);
        int b = idx >> 21;
        float4 v = *reinterpret_cast<const float4*>(q + l * (B_ * E_) + b * E_ + e);
        short4v o;
        o[0] = f2bf(v.x); o[1] = f2bf(v.y); o[2] = f2bf(v.z); o[3] = f2bf(v.w);
        *reinterpret_cast<short4v*>(xb + idx) = o;
    } else {
        int cb = blk - 4096;
        int sel = cb >> 10, lb = cb & 1023;
        const float* w = sel == 0 ? w0 : sel == 1 ? w1 : sel == 2 ? w2 : w3;
        short* o = sel == 0 ? o0 : sel == 1 ? o1 : sel == 2 ? o2 : o3;
        int i = lb * 256 + threadIdx.x;
        float4 v = *reinterpret_cast<const float4*>(w + i * 4);
        short4v s;
        s[0] = f2bf(v.x); s[1] = f2bf(v.y); s[2] = f2bf(v.z); s[3] = f2bf(v.w);
        *reinterpret_cast<short4v*>(o + i * 4) = s;
    }
}

// ---- xpart[ch][col] = sum over 128 l of query[l*2048 + col] ----
__global__ void k_xsum(const float* __restrict__ q, float* __restrict__ xpart) {
    int cg = blockIdx.x & 7, ch = blockIdx.x >> 3;  // grid 128
    int col = cg * 256 + threadIdx.x;
    float s = 0.f;
    for (int l = ch * 128; l < (ch + 1) * 128; ++l) s += q[(size_t)l * (B_ * E_) + col];
    xpart[ch * (B_ * E_) + col] = s;
}
__global__ void k_xred(const float* __restrict__ xpart, float* __restrict__ xsum) {
    int col = blockIdx.x * 256 + threadIdx.x;  // grid 8
    float s = 0.f;
#pragma unroll
    for (int c = 0; c < 16; ++c) s += xpart[c * (B_ * E_) + col];
    xsum[col] = s;
}

// ---- GEMM core, double-buffered 2-phase + T2 LDS XOR-swizzle ----
// Swizzle (rule #21, both-sides): global source chunk = (lane&7) ^ (stage_row&7),
// LDS dest linear, ds_read chunk = (kk*4+kg) ^ (frag_row&7).  frag_row bases are
// multiples of 8, so frag_row&7 == lrow&7; quarter-wave lanes then spread over
// 8 distinct 16B slots -> 2-way aliasing only (free).
template<int MODE, int BM, int BN>
__device__ __forceinline__ void gemm_body(const short* __restrict__ A,
                                          const short* __restrict__ Bw,
                                          const float* __restrict__ bias,
                                          short* __restrict__ Cb,
                                          float* __restrict__ Cf,
                                          const float* __restrict__ ident,
                                          int bx, int by) {
    const int K = E_;
    constexpr int MI = BM / 32;
    constexpr int NI = BN / 32;
    __shared__ short As[2][BM * 64];
    __shared__ short Bs[2][BN * 64];
    int tid = threadIdx.x;
    int lane = tid & 63;
    int wid = tid >> 6;
    int wr = wid >> 1, wc = wid & 1;
    int lrow = lane & 15;
    int kg = lane >> 4;
    int lr8 = lane >> 3;                       // stage row within 8-row chunk
    int swz = (((lane & 7) ^ (lr8 & 7)) * 8);  // pre-swizzled source chunk offset
    int rx = lrow & 7;                         // read-side XOR key
    int mBase = by * BM, nBase = bx * BN;

    auto STAGE = [&](int buf, int k0) {
#pragma unroll
        for (int i = 0; i < BM / 32; ++i) {
            int r0 = (wid * (BM / 32) + i) * 8;
            const short* ga = A + (size_t)(mBase + r0 + lr8) * K + k0 + swz;
            __builtin_amdgcn_global_load_lds(
                (const __attribute__((address_space(1))) void*)ga,
                (__attribute__((address_space(3))) void*)(&As[buf][r0 * 64]), 16, 0, 0);
        }
#pragma unroll
        for (int i = 0; i < BN / 32; ++i) {
            int r0 = (wid * (BN / 32) + i) * 8;
            const short* gb = Bw + (size_t)(nBase + r0 + lr8) * K + k0 + swz;
            __builtin_amdgcn_global_load_lds(
                (const __attribute__((address_space(1))) void*)gb,
                (__attribute__((address_space(3))) void*)(&Bs[buf][r0 * 64]), 16, 0, 0);
        }
    };

    f32x4 acc[MI][NI];
#pragma unroll
    for (int i = 0; i < MI; ++i)
#pragma unroll
        for (int j = 0; j < NI; ++j) acc[i][j] = (f32x4){0.f, 0.f, 0.f, 0.f};

    STAGE(0, 0);
    asm volatile("s_waitcnt vmcnt(0)" ::: "memory");
    __syncthreads();

    int cur = 0;
    for (int k0 = 0; k0 < K; k0 += 64) {
        if (k0 + 64 < K) STAGE(cur ^ 1, k0 + 64);   // prefetch overlaps compute below

        short8 af[2][MI], bf[2][NI];
#pragma unroll
        for (int kk = 0; kk < 2; ++kk) {
#pragma unroll
            for (int mi = 0; mi < MI; ++mi)
                af[kk][mi] = *reinterpret_cast<const short8*>(
                    &As[cur][(wr * (MI * 16) + mi * 16 + lrow) * 64 + (((kk * 4 + kg) ^ rx) * 8)]);
#pragma unroll
            for (int ni = 0; ni < NI; ++ni)
                bf[kk][ni] = *reinterpret_cast<const short8*>(
                    &Bs[cur][(wc * (NI * 16) + ni * 16 + lrow) * 64 + (((kk * 4 + kg) ^ rx) * 8)]);
        }
#pragma unroll
        for (int kk = 0; kk < 2; ++kk)
#pragma unroll
            for (int mi = 0; mi < MI; ++mi)
#pragma unroll
                for (int ni = 0; ni < NI; ++ni)
                    acc[mi][ni] = __builtin_amdgcn_mfma_f32_16x16x32_bf16(
                        af[kk][mi], bf[kk][ni], acc[mi][ni], 0, 0, 0);

        asm volatile("s_waitcnt vmcnt(0)" ::: "memory");
        __syncthreads();
        cur ^= 1;
    }

    int rowq = (lane >> 4) * 4;
    int coll = lane & 15;
#pragma unroll
    for (int mi = 0; mi < MI; ++mi) {
#pragma unroll
        for (int ni = 0; ni < NI; ++ni) {
            int col = nBase + wc * (NI * 16) + ni * 16 + coll;
            float bv = bias[col];
#pragma unroll
            for (int r = 0; r < 4; ++r) {
                int row = mBase + wr * (MI * 16) + mi * 16 + rowq + r;
                float v = acc[mi][ni][r] + bv;
                if (MODE == 0) {
                    Cb[(size_t)row * E_ + col] = f2bf(v);
                } else {
                    int b = row >> 11, l = row & (L_ - 1);
                    size_t oi = (size_t)l * (B_ * E_) + b * E_ + col;
                    Cf[oi] = v + ident[oi];
                }
            }
        }
    }
}

__global__ __launch_bounds__(256) void k_gemm3(const short* __restrict__ A,
    const short* __restrict__ W0, const short* __restrict__ W1, const short* __restrict__ W2,
    const float* __restrict__ b0, const float* __restrict__ b1, const float* __restrict__ b2,
    short* __restrict__ C0, short* __restrict__ C1, short* __restrict__ C2) {
    int wg = blockIdx.x;
    int sw = (wg & 7) * 96 + (wg >> 3);
    int bx = sw & 7, by = (sw >> 3) & 31, z = sw >> 8;
    const short* Bw = z == 0 ? W0 : (z == 1 ? W1 : W2);
    const float* bias = z == 0 ? b0 : (z == 1 ? b1 : b2);
    short* C = z == 0 ? C0 : (z == 1 ? C1 : C2);
    gemm_body<0, 128, 128>(A, Bw, bias, C, nullptr, nullptr, bx, by);
}

__global__ __launch_bounds__(256) void k_gemmo(const short* __restrict__ A,
                                               const short* __restrict__ Bw,
                                               const float* __restrict__ bias,
                                               float* __restrict__ C,
                                               const float* __restrict__ ident) {
    int wg = blockIdx.x;
    int sw = (wg & 7) * 64 + (wg >> 3);
    int bx = sw & 15, by = sw >> 4;
    gemm_body<1, 128, 64>(A, Bw, bias, nullptr, C, ident, bx, by);
}

// ---- qsum[b][f] = xsum[b]. dot q_w[f] + L*q_b[f]  (f32 exact) ----
__global__ void k_qsum(const float* __restrict__ xsum, const float* __restrict__ qw,
                       const float* __restrict__ qb, float* __restrict__ qsum) {
    int wid = threadIdx.x >> 6, lane = threadIdx.x & 63;
    int gid = blockIdx.x * 4 + wid;
    int b = gid >> 10, f = gid & 1023;
    float s = 0.f;
    for (int e = lane; e < E_; e += 64) s += xsum[b * E_ + e] * qw[f * E_ + e];
#pragma unroll
    for (int off = 32; off; off >>= 1) s += __shfl_xor(s, off);
    if (lane == 0) qsum[gid] = s + (float)L_ * qb[f];
}

// ---- t[b,h,e] = sum_d qsum[b,h*64+d] * k_w[h*64+d, e] ----
__global__ void k_t(const float* __restrict__ qsum, const float* __restrict__ kw,
                    float* __restrict__ tb) {
    int i = blockIdx.x * 256 + threadIdx.x;
    int e = i & 1023, bh = i >> 10;
    int b = bh >> 4, h = bh & 15;
    float s = 0.f;
#pragma unroll
    for (int d = 0; d < HD_; ++d)
        s += qsum[b * E_ + h * HD_ + d] * kw[(size_t)(h * HD_ + d) * E_ + e];
    tb[i] = s;
}

// ---- partial scores over e-quarters ----
__global__ __launch_bounds__(256) void k_score(const float* __restrict__ query,
                                               const float* __restrict__ tb,
                                               float* __restrict__ scorp) {
    __shared__ float xs[64][68];
    __shared__ float ts[16][68];
    int id = blockIdx.x;
    int eq = id >> 6;
    int b = (id >> 5) & 1;
    int n0 = (id & 31) * 64;
    int tid = threadIdx.x;
    int hg = tid & 3, rg = tid >> 2;
    float acc[4] = {0.f, 0.f, 0.f, 0.f};
    for (int e0 = eq * 256; e0 < eq * 256 + 256; e0 += 64) {
        __syncthreads();
        for (int j = tid; j < 1024; j += 256) {
            int r = j >> 4, c4 = (j & 15) * 4;
            float4 v = *reinterpret_cast<const float4*>(
                &query[(size_t)(n0 + r) * (B_ * E_) + b * E_ + e0 + c4]);
            *reinterpret_cast<float4*>(&xs[r][c4]) = v;
        }
        {
            int hh = tid >> 4, c4 = (tid & 15) * 4;
            float4 v = *reinterpret_cast<const float4*>(&tb[(size_t)(b * 16 + hh) * E_ + e0 + c4]);
            *reinterpret_cast<float4*>(&ts[hh][c4]) = v;
        }
        __syncthreads();
        for (int c = 0; c < 64; ++c) {
            float x0 = xs[rg][c];
#pragma unroll
            for (int j = 0; j < 4; ++j) acc[j] += x0 * ts[hg + 4 * j][c];
        }
    }
#pragma unroll
    for (int j = 0; j < 4; ++j) {
        int h = hg + 4 * j;
        scorp[(size_t)eq * 65536 + (size_t)(b * 16 + h) * L_ + n0 + rg] = acc[j];
    }
}

// ---- top-64 per (b,h): fused e-quarter reduce + wave radix-select; gather
// selected k rows into pre-swizzled bf16 selkb for MFMA staging ----
__global__ __launch_bounds__(256) void k_topk(const float* __restrict__ scorp,
                                              const short* __restrict__ kb,
                                              short* __restrict__ selkb) {
    __shared__ int sel[4][64];
    int wid = threadIdx.x >> 6, lane = threadIdx.x & 63;
    int bh = blockIdx.x * 4 + wid;  // grid 8
    int b = bh >> 4, h = bh & 15;

    unsigned u[32];
#pragma unroll
    for (int j = 0; j < 32; ++j) {
        int base = bh * L_ + j * 64 + lane;
        float sc = ((scorp[base] + scorp[base + 65536]) + scorp[base + 131072]) + scorp[base + 196608];
        sc *= SCALE;
        unsigned bits = __float_as_uint(sc);
        u[j] = (bits & 0x80000000u) ? ~bits : (bits | 0x80000000u);
    }
    unsigned prefix = 0;
    int k = TOPK_;
    for (int bit = 31; bit >= 0; --bit) {
        unsigned cand = prefix | (1u << bit);
        int c = 0;
#pragma unroll
        for (int j = 0; j < 32; ++j) c += ((u[j] >> bit) == (cand >> bit)) ? 1 : 0;
#pragma unroll
        for (int off = 32; off; off >>= 1) c += __shfl_xor(c, off);
        if (c >= k) prefix = cand; else k -= c;
    }
    unsigned T = prefix;
    int nStrict = 0;
#pragma unroll
    for (int j = 0; j < 32; ++j) nStrict += (u[j] > T) ? 1 : 0;
#pragma unroll
    for (int off = 32; off; off >>= 1) nStrict += __shfl_xor(nStrict, off);
    int nTies = TOPK_ - nStrict;

    int strictBase = 0, tieBase = 0;
    unsigned long long below = (lane == 0) ? 0ull : ((~0ull) >> (64 - lane));
#pragma unroll
    for (int j = 0; j < 32; ++j) {
        unsigned long long mS = __ballot(u[j] > T);
        unsigned long long mT = __ballot(u[j] == T);
        if (u[j] > T) {
            int slot = strictBase + __popcll(mS & below);
            sel[wid][slot] = j * 64 + lane;
        } else if (u[j] == T) {
            int r = tieBase + __popcll(mT & below);
            if (r < nTies) sel[wid][nStrict + r] = j * 64 + lane;
        }
        strictBase += __popcll(mS);
        tieBase += __popcll(mT);
    }
    __syncthreads();
    for (int m = 0; m < TOPK_; ++m) {
        int idx = sel[wid][m];
        short v = kb[((size_t)b * L_ + idx) * E_ + h * HD_ + lane];
        selkb[(size_t)bh * 4096 + m * 64 + (((lane >> 3) ^ (m & 7)) * 8) + (lane & 7)] = v;
    }
}

// ---- vtb[bh*64+d][l] = v[b,l,h*64+d]  (bf16 transpose for W-MFMA B-operand) ----
__global__ __launch_bounds__(256) void k_vt(const short* __restrict__ vb,
                                            short* __restrict__ vtb) {
    __shared__ short ts[64][68];
    int blk = blockIdx.x;             // 1024 = 32 bh x 32 l-tiles
    int bh = blk >> 5, l0 = (blk & 31) * 64;
    int b = bh >> 4, h = bh & 15;
    int tid = threadIdx.x;
    int l = tid >> 2, d0 = (tid & 3) * 16;
    const short* src = vb + ((size_t)(b * L_ + l0 + l)) * E_ + h * 64 + d0;
    short8 v0 = *reinterpret_cast<const short8*>(src);
    short8 v1 = *reinterpret_cast<const short8*>(src + 8);
#pragma unroll
    for (int j = 0; j < 8; ++j) ts[d0 + j][l] = v0[j];
#pragma unroll
    for (int j = 0; j < 8; ++j) ts[d0 + 8 + j][l] = v1[j];
    __syncthreads();
    int d = tid >> 2, lp = (tid & 3) * 16;
    short* dst = vtb + ((size_t)(bh * 64 + d)) * 2048 + l0 + lp;
#pragma unroll
    for (int j = 0; j < 4; ++j)
        *reinterpret_cast<short4v*>(dst + j * 4) =
            *reinterpret_cast<const short4v*>(&ts[d][lp + j * 4]);
}

// ---- attW: S_k = k.selk^T (MFMA) -> softmax -> Wpart = P2^T v (MFMA) ----
__global__ __launch_bounds__(256) void k_attW(const short* __restrict__ kb,
                                              const short* __restrict__ vtb,
                                              const short* __restrict__ selkb,
                                              float* __restrict__ wpart) {
    __shared__ short sk[4096], kt[4096], vt[4096], pt[4096];
    int wg = blockIdx.x;
    int sw = (wg & 7) * 64 + (wg >> 3);   // XCD swizzle, 512 blocks
    int bh = sw & 31, ch = sw >> 5;       // ch 0..15, chunk = 128 l
    int b = bh >> 4, h = bh & 15;
    int tid = threadIdx.x, w = tid >> 6, lane = tid & 63;
    int lr = lane & 15, kg = lane >> 4;

#pragma unroll
    for (int j = 0; j < 2; ++j) {
        int off = (w * 2 + j) * 512;
        __builtin_amdgcn_global_load_lds(
            (const __attribute__((address_space(1))) void*)(selkb + (size_t)bh * 4096 + off + lane * 8),
            (__attribute__((address_space(3))) void*)(sk + off), 16, 0, 0);
    }

    f32x4 accw[4];
#pragma unroll
    for (int i = 0; i < 4; ++i) accw[i] = (f32x4){0.f, 0.f, 0.f, 0.f};

    for (int t = 0; t < 2; ++t) {
        int lt = ch * 128 + t * 64;
#pragma unroll
        for (int j = 0; j < 2; ++j) {
            int r = w * 16 + j * 8 + (lane >> 3);
            int s = lane & 7;
            const short* src = kb + ((size_t)(b * L_ + lt + r)) * E_ + h * 64 + ((s ^ (r & 7)) * 8);
            __builtin_amdgcn_global_load_lds(
                (const __attribute__((address_space(1))) void*)src,
                (__attribute__((address_space(3))) void*)(kt + (w * 16 + j * 8) * 64), 16, 0, 0);
        }
        __syncthreads();

        f32x4 s4[4];
#pragma unroll
        for (int i = 0; i < 4; ++i) s4[i] = (f32x4){0.f, 0.f, 0.f, 0.f};
#pragma unroll
        for (int kk = 0; kk < 2; ++kk) {
            int row = w * 16 + lr;
            short8 a = *reinterpret_cast<const short8*>(
                kt + row * 64 + (((kk * 4 + kg) ^ (row & 7)) * 8));
#pragma unroll
            for (int ni = 0; ni < 4; ++ni) {
                int m = ni * 16 + lr;
                short8 bb = *reinterpret_cast<const short8*>(
                    sk + m * 64 + (((kk * 4 + kg) ^ (m & 7)) * 8));
                s4[ni] = __builtin_amdgcn_mfma_f32_16x16x32_bf16(a, bb, s4[ni], 0, 0, 0);
            }
        }
        float p[4][4];
#pragma unroll
        for (int r = 0; r < 4; ++r) {
            float v0 = s4[0][r] * SCALE, v1 = s4[1][r] * SCALE;
            float v2 = s4[2][r] * SCALE, v3 = s4[3][r] * SCALE;
            float mx = fmaxf(fmaxf(v0, v1), fmaxf(v2, v3));
            mx = fmaxf(mx, __shfl_xor(mx, 1));
            mx = fmaxf(mx, __shfl_xor(mx, 2));
            mx = fmaxf(mx, __shfl_xor(mx, 4));
            mx = fmaxf(mx, __shfl_xor(mx, 8));
            float e0 = __expf(v0 - mx), e1 = __expf(v1 - mx);
            float e2 = __expf(v2 - mx), e3 = __expf(v3 - mx);
            float sm = e0 + e1 + e2 + e3;
            sm += __shfl_xor(sm, 1);
            sm += __shfl_xor(sm, 2);
            sm += __shfl_xor(sm, 4);
            sm += __shfl_xor(sm, 8);
            float inv = 1.f / sm;
            p[0][r] = e0 * inv; p[1][r] = e1 * inv; p[2][r] = e2 * inv; p[3][r] = e3 * inv;
        }
#pragma unroll
        for (int ni = 0; ni < 4; ++ni)
#pragma unroll
            for (int r = 0; r < 4; ++r) {
                int m = ni * 16 + lr;
                int ll = w * 16 + kg * 4 + r;
                pt[m * 64 + (((ll >> 3) ^ (m & 7)) * 8) + (ll & 7)] = f2bf(p[ni][r]);
            }
#pragma unroll
        for (int j = 0; j < 2; ++j) {
            int d = w * 16 + j * 8 + (lane >> 3);
            int s = lane & 7;
            const short* src = vtb + ((size_t)(bh * 64 + d)) * 2048 + lt + ((s ^ (d & 7)) * 8);
            __builtin_amdgcn_global_load_lds(
                (const __attribute__((address_space(1))) void*)src,
                (__attribute__((address_space(3))) void*)(vt + (w * 16 + j * 8) * 64), 16, 0, 0);
        }
        __syncthreads();
#pragma unroll
        for (int kk = 0; kk < 2; ++kk) {
            int mm = w * 16 + lr;
            short8 a = *reinterpret_cast<const short8*>(
                pt + mm * 64 + (((kk * 4 + kg) ^ (mm & 7)) * 8));
#pragma unroll
            for (int ni = 0; ni < 4; ++ni) {
                int d = ni * 16 + lr;
                short8 bb = *reinterpret_cast<const short8*>(
                    vt + d * 64 + (((kk * 4 + kg) ^ (d & 7)) * 8));
                accw[ni] = __builtin_amdgcn_mfma_f32_16x16x32_bf16(a, bb, accw[ni], 0, 0, 0);
            }
        }
    }
#pragma unroll
    for (int ni = 0; ni < 4; ++ni)
#pragma unroll
        for (int r = 0; r < 4; ++r) {
            int m = w * 16 + kg * 4 + r;
            int d = ni * 16 + lr;
            wpart[((size_t)(ch * 32 + bh)) * 4096 + m * 64 + d] = accw[ni][r];
        }
}

// ---- reduce wpart chunks -> Wt global bf16, transposed + pre-swizzled ----
__global__ void k_wreduce(const float* __restrict__ wpart, short* __restrict__ wtg) {
    int i = blockIdx.x * 256 + threadIdx.x;  // 131072, grid 512
    float s = 0.f;
#pragma unroll
    for (int c = 0; c < 16; ++c) s += wpart[(size_t)c * 131072 + i];
    int bh = i >> 12, m = (i >> 6) & 63, d = i & 63;
    wtg[(size_t)bh * 4096 + d * 64 + (((m >> 3) ^ (d & 7)) * 8) + (m & 7)] = f2bf(s);
}

// ---- attO: S_q = q.selk^T (MFMA) -> softmax -> att = P1.W (MFMA) -> bf16 ----
__global__ __launch_bounds__(256) void k_attO(const short* __restrict__ qb,
                                              const short* __restrict__ selkb,
                                              const short* __restrict__ wtg,
                                              short* __restrict__ att) {
    __shared__ short sk[4096], wt[4096], qt[4096], p1[4096];
    int wg = blockIdx.x;
    int sw = (wg & 7) * 64 + (wg >> 3);
    int bh = sw & 31, ch = sw >> 5;
    int b = bh >> 4, h = bh & 15;
    int tid = threadIdx.x, w = tid >> 6, lane = tid & 63;
    int lr = lane & 15, kg = lane >> 4;

#pragma unroll
    for (int j = 0; j < 2; ++j) {
        int off = (w * 2 + j) * 512;
        __builtin_amdgcn_global_load_lds(
            (const __attribute__((address_space(1))) void*)(selkb + (size_t)bh * 4096 + off + lane * 8),
            (__attribute__((address_space(3))) void*)(sk + off), 16, 0, 0);
        __builtin_amdgcn_global_load_lds(
            (const __attribute__((address_space(1))) void*)(wtg + (size_t)bh * 4096 + off + lane * 8),
            (__attribute__((address_space(3))) void*)(wt + off), 16, 0, 0);
    }

    for (int t = 0; t < 2; ++t) {
        int lt = ch * 128 + t * 64;
#pragma unroll
        for (int j = 0; j < 2; ++j) {
            int r = w * 16 + j * 8 + (lane >> 3);
            int s = lane & 7;
            const short* src = qb + ((size_t)(b * L_ + lt + r)) * E_ + h * 64 + ((s ^ (r & 7)) * 8);
            __builtin_amdgcn_global_load_lds(
                (const __attribute__((address_space(1))) void*)src,
                (__attribute__((address_space(3))) void*)(qt + (w * 16 + j * 8) * 64), 16, 0, 0);
        }
        __syncthreads();

        f32x4 s4[4];
#pragma unroll
        for (int i = 0; i < 4; ++i) s4[i] = (f32x4){0.f, 0.f, 0.f, 0.f};
#pragma unroll
        for (int kk = 0; kk < 2; ++kk) {
            int row = w * 16 + lr;
            short8 a = *reinterpret_cast<const short8*>(
                qt + row * 64 + (((kk * 4 + kg) ^ (row & 7)) * 8));
#pragma unroll
            for (int ni = 0; ni < 4; ++ni) {
                int m = ni * 16 + lr;
                short8 bb = *reinterpret_cast<const short8*>(
                    sk + m * 64 + (((kk * 4 + kg) ^ (m & 7)) * 8));
                s4[ni] = __builtin_amdgcn_mfma_f32_16x16x32_bf16(a, bb, s4[ni], 0, 0, 0);
            }
        }
        float p[4][4];
#pragma unroll
        for (int r = 0; r < 4; ++r) {
            float v0 = s4[0][r] * SCALE, v1 = s4[1][r] * SCALE;
            float v2 = s4[2][r] * SCALE, v3 = s4[3][r] * SCALE;
            float mx = fmaxf(fmaxf(v0, v1), fmaxf(v2, v3));
            mx = fmaxf(mx, __shfl_xor(mx, 1));
            mx = fmaxf(mx, __shfl_xor(mx, 2));
            mx = fmaxf(mx, __shfl_xor(mx, 4));
            mx = fmaxf(mx, __shfl_xor(mx, 8));
            float e0 = __expf(v0 - mx), e1 = __expf(v1 - mx);
            float e2 = __expf(v2 - mx), e3 = __expf(v3 - mx);
            float sm = e0 + e1 + e2 + e3;
            sm += __shfl_xor(sm, 1);
            sm += __shfl_xor(sm, 2);
            sm += __shfl_xor(sm, 4);
            sm += __shfl_xor(sm, 8);
            float inv = 1.f / sm;
            p[0][r] = e0 * inv; p[1][r] = e1 * inv; p[2][r] = e2 * inv; p[3][r] = e3 * inv;
        }
#pragma unroll
        for (int ni = 0; ni < 4; ++ni)
#pragma unroll
            for (int r = 0; r < 4; ++r) {
                int m = ni * 16 + lr;
                int ll = w * 16 + kg * 4 + r;
                p1[ll * 64 + (((m >> 3) ^ (ll & 7)) * 8) + (m & 7)] = f2bf(p[ni][r]);
            }
        __syncthreads();
        f32x4 ao[4];
#pragma unroll
        for (int i = 0; i < 4; ++i) ao[i] = (f32x4){0.f, 0.f, 0.f, 0.f};
#pragma unroll
        for (int kk = 0; kk < 2; ++kk) {
            int row = w * 16 + lr;
            short8 a = *reinterpret_cast<const short8*>(
                p1 + row * 64 + (((kk * 4 + kg) ^ (row & 7)) * 8));
#pragma unroll
            for (int ni = 0; ni < 4; ++ni) {
                int d = ni * 16 + lr;
                short8 bb = *reinterpret_cast<const short8*>(
                    wt + d * 64 + (((kk * 4 + kg) ^ (d & 7)) * 8));
                ao[ni] = __builtin_amdgcn_mfma_f32_16x16x32_bf16(a, bb, ao[ni], 0, 0, 0);
            }
        }
#pragma unroll
        for (int ni = 0; ni < 4; ++ni)
#pragma unroll
            for (int r = 0; r < 4; ++r) {
                int l = lt + w * 16 + kg * 4 + r;
                int d = ni * 16 + lr;
                att[((size_t)(b * L_ + l)) * E_ + h * 64 + d] = f2bf(ao[ni][r]);
            }
    }
}

extern "C" void kernel_launch(void* const* d_in, const int* in_sizes, int n_in,
                              void* d_out, int out_size, void* d_ws, size_t ws_size,
                              hipStream_t stream) {
    const float* query = (const float*)d_in[0];
    const float* q_w = (const float*)d_in[1];
    const float* q_b = (const float*)d_in[2];
    const float* k_w = (const float*)d_in[3];
    const float* k_b = (const float*)d_in[4];
    const float* v_w = (const float*)d_in[5];
    const float* v_b = (const float*)d_in[6];
    const float* o_w = (const float*)d_in[7];
    const float* o_b = (const float*)d_in[8];
    float* out = (float*)d_out;

    char* p = (char*)d_ws;
    auto alloc = [&](size_t bytes) {
        char* r = p;
        p += (bytes + 255) & ~(size_t)255;
        return r;
    };
    short* xb    = (short*)alloc((size_t)MROWS * E_ * 2);
    short* qwb   = (short*)alloc((size_t)E_ * E_ * 2);
    short* kwb   = (short*)alloc((size_t)E_ * E_ * 2);
    short* vwb   = (short*)alloc((size_t)E_ * E_ * 2);
    short* owb   = (short*)alloc((size_t)E_ * E_ * 2);
    short* qbuf  = (short*)alloc((size_t)MROWS * E_ * 2);
    short* kbuf  = (short*)alloc((size_t)MROWS * E_ * 2);
    short* vbuf  = (short*)alloc((size_t)MROWS * E_ * 2);
    short* vtb   = (short*)alloc((size_t)32 * 64 * 2048 * 2);
    float* xpart = (float*)alloc((size_t)16 * B_ * E_ * 4);
    float* xsum  = (float*)alloc((size_t)B_ * E_ * 4);
    float* qsum  = (float*)alloc((size_t)B_ * E_ * 4);
    float* tb    = (float*)alloc((size_t)B_ * H_ * E_ * 4);
    float* scorp = (float*)alloc((size_t)4 * B_ * H_ * L_ * 4);
    short* selkb = (short*)alloc((size_t)32 * 4096 * 2);
    short* wtg   = (short*)alloc((size_t)32 * 4096 * 2);
    float* wpart = (float*)alloc((size_t)16 * 32 * 4096 * 4);
    short* att   = (short*)alloc((size_t)MROWS * E_ * 2);

    // stage 1: merged transpose+casts, exact sums
    k_prep<<<8192, 256, 0, stream>>>(query, q_w, k_w, v_w, o_w, xb, qwb, kwb, vwb, owb);
    k_xsum<<<128, 256, 0, stream>>>(query, xpart);
    k_xred<<<8, 256, 0, stream>>>(xpart, xsum);

    // stage 2: fused q/k/v projections (dbuf 2-phase + T2 swizzle)
    k_gemm3<<<768, 256, 0, stream>>>(xb, qwb, kwb, vwb, q_b, k_b, v_b, qbuf, kbuf, vbuf);

    // stage 3: exact f32 scores + fused top-k + v transpose
    k_qsum<<<512, 256, 0, stream>>>(xsum, q_w, q_b, qsum);
    k_t<<<128, 256, 0, stream>>>(qsum, k_w, tb);
    k_score<<<256, 256, 0, stream>>>(query, tb, scorp);
    k_topk<<<8, 256, 0, stream>>>(scorp, kbuf, selkb);
    k_vt<<<1024, 256, 0, stream>>>(vbuf, vtb);

    // stage 4: MFMA attention core
    k_attW<<<512, 256, 0, stream>>>(kbuf, vtb, selkb, wpart);
    k_wreduce<<<512, 256, 0, stream>>>(wpart, wtg);
    k_attO<<<512, 256, 0, stream>>>(qbuf, selkb, wtg, att);

    // stage 5: o-projection fused with bias + residual + transpose back
    k_gemmo<<<512, 256, 0, stream>>>(att, owb, o_b, out, query);
}

// Round 7
// 174.242 us; speedup vs baseline: 2.6076x; 1.0098x over previous
//
#include <hip/hip_runtime.h>
#include <hip/hip_bf16.h>

#define L_ 2048
#define B_ 2
#define E_ 1024
#define H_ 16
#define HD_ 64
#define TOPK_ 64
#define MROWS (B_*L_)
#define SCALE 0.125f

typedef __attribute__((ext_vector_type(8))) short short8;
typedef __attribute__((ext_vector_type(4))) short short4v;
typedef __attribute__((ext_vector_type(4))) float f32x4;

static __device__ __forceinline__ short f2bf(float f) {
    __hip_bfloat16 h = __float2bfloat16(f);
    return *reinterpret_cast<short*>(&h);
}
static __device__ __forceinline__ float bf2f(short s) {
    unsigned u = ((unsigned)(unsigned short)s) << 16;
    return __uint_as_float(u);
}

// ---- merged: transpose [L,B,E] f32 -> [B,L,E] bf16  +  cast 4 weight mats ----
__global__ void k_prep(const float* __restrict__ q,
                       const float* __restrict__ w0, const float* __restrict__ w1,
                       const float* __restrict__ w2, const float* __restrict__ w3,
                       short* __restrict__ xb,
                       short* __restrict__ o0, short* __restrict__ o1,
                       short* __restrict__ o2, short* __restrict__ o3) {
    int blk = blockIdx.x;
    if (blk < 4096) {
        int i = blk * 256 + threadIdx.x;
        int idx = i * 4;
        int e = idx & (E_ - 1);
        int l = (idx >> 10) & (L_ - 1);
        int b = idx >> 21;
        float4 v = *reinterpret_cast<const float4*>(q + l * (B_ * E_) + b * E_ + e);
        short4v o;
        o[0] = f2bf(v.x); o[1] = f2bf(v.y); o[2] = f2bf(v.z); o[3] = f2bf(v.w);
        *reinterpret_cast<short4v*>(xb + idx) = o;
    } else {
        int cb = blk - 4096;
        int sel = cb >> 10, lb = cb & 1023;
        const float* w = sel == 0 ? w0 : sel == 1 ? w1 : sel == 2 ? w2 : w3;
        short* o = sel == 0 ? o0 : sel == 1 ? o1 : sel == 2 ? o2 : o3;
        int i = lb * 256 + threadIdx.x;
        float4 v = *reinterpret_cast<const float4*>(w + i * 4);
        short4v s;
        s[0] = f2bf(v.x); s[1] = f2bf(v.y); s[2] = f2bf(v.z); s[3] = f2bf(v.w);
        *reinterpret_cast<short4v*>(o + i * 4) = s;
    }
}

// ---- xpart[ch][col] = sum over 128 l of query[l*2048 + col] ----
__global__ void k_xsum(const float* __restrict__ q, float* __restrict__ xpart) {
    int cg = blockIdx.x & 7, ch = blockIdx.x >> 3;  // grid 128
    int col = cg * 256 + threadIdx.x;
    float s = 0.f;
    for (int l = ch * 128; l < (ch + 1) * 128; ++l) s += q[(size_t)l * (B_ * E_) + col];
    xpart[ch * (B_ * E_) + col] = s;
}
__global__ void k_xred(const float* __restrict__ xpart, float* __restrict__ xsum) {
    int col = blockIdx.x * 256 + threadIdx.x;  // grid 8
    float s = 0.f;
#pragma unroll
    for (int c = 0; c < 16; ++c) s += xpart[c * (B_ * E_) + col];
    xsum[col] = s;
}

// ---- GEMM core, double-buffered 2-phase + T2 LDS XOR-swizzle ----
template<int MODE, int BM, int BN>
__device__ __forceinline__ void gemm_body(const short* __restrict__ A,
                                          const short* __restrict__ Bw,
                                          const float* __restrict__ bias,
                                          short* __restrict__ Cb,
                                          float* __restrict__ Cf,
                                          const float* __restrict__ ident,
                                          int bx, int by) {
    const int K = E_;
    constexpr int MI = BM / 32;
    constexpr int NI = BN / 32;
    __shared__ short As[2][BM * 64];
    __shared__ short Bs[2][BN * 64];
    int tid = threadIdx.x;
    int lane = tid & 63;
    int wid = tid >> 6;
    int wr = wid >> 1, wc = wid & 1;
    int lrow = lane & 15;
    int kg = lane >> 4;
    int lr8 = lane >> 3;
    int swz = (((lane & 7) ^ (lr8 & 7)) * 8);
    int rx = lrow & 7;
    int mBase = by * BM, nBase = bx * BN;

    auto STAGE = [&](int buf, int k0) {
#pragma unroll
        for (int i = 0; i < BM / 32; ++i) {
            int r0 = (wid * (BM / 32) + i) * 8;
            const short* ga = A + (size_t)(mBase + r0 + lr8) * K + k0 + swz;
            __builtin_amdgcn_global_load_lds(
                (const __attribute__((address_space(1))) void*)ga,
                (__attribute__((address_space(3))) void*)(&As[buf][r0 * 64]), 16, 0, 0);
        }
#pragma unroll
        for (int i = 0; i < BN / 32; ++i) {
            int r0 = (wid * (BN / 32) + i) * 8;
            const short* gb = Bw + (size_t)(nBase + r0 + lr8) * K + k0 + swz;
            __builtin_amdgcn_global_load_lds(
                (const __attribute__((address_space(1))) void*)gb,
                (__attribute__((address_space(3))) void*)(&Bs[buf][r0 * 64]), 16, 0, 0);
        }
    };

    f32x4 acc[MI][NI];
#pragma unroll
    for (int i = 0; i < MI; ++i)
#pragma unroll
        for (int j = 0; j < NI; ++j) acc[i][j] = (f32x4){0.f, 0.f, 0.f, 0.f};

    STAGE(0, 0);
    asm volatile("s_waitcnt vmcnt(0)" ::: "memory");
    __syncthreads();

    int cur = 0;
    for (int k0 = 0; k0 < K; k0 += 64) {
        if (k0 + 64 < K) STAGE(cur ^ 1, k0 + 64);

        short8 af[2][MI], bf[2][NI];
#pragma unroll
        for (int kk = 0; kk < 2; ++kk) {
#pragma unroll
            for (int mi = 0; mi < MI; ++mi)
                af[kk][mi] = *reinterpret_cast<const short8*>(
                    &As[cur][(wr * (MI * 16) + mi * 16 + lrow) * 64 + (((kk * 4 + kg) ^ rx) * 8)]);
#pragma unroll
            for (int ni = 0; ni < NI; ++ni)
                bf[kk][ni] = *reinterpret_cast<const short8*>(
                    &Bs[cur][(wc * (NI * 16) + ni * 16 + lrow) * 64 + (((kk * 4 + kg) ^ rx) * 8)]);
        }
#pragma unroll
        for (int kk = 0; kk < 2; ++kk)
#pragma unroll
            for (int mi = 0; mi < MI; ++mi)
#pragma unroll
                for (int ni = 0; ni < NI; ++ni)
                    acc[mi][ni] = __builtin_amdgcn_mfma_f32_16x16x32_bf16(
                        af[kk][mi], bf[kk][ni], acc[mi][ni], 0, 0, 0);

        asm volatile("s_waitcnt vmcnt(0)" ::: "memory");
        __syncthreads();
        cur ^= 1;
    }

    int rowq = (lane >> 4) * 4;
    int coll = lane & 15;
#pragma unroll
    for (int mi = 0; mi < MI; ++mi) {
#pragma unroll
        for (int ni = 0; ni < NI; ++ni) {
            int col = nBase + wc * (NI * 16) + ni * 16 + coll;
            float bv = bias[col];
#pragma unroll
            for (int r = 0; r < 4; ++r) {
                int row = mBase + wr * (MI * 16) + mi * 16 + rowq + r;
                float v = acc[mi][ni][r] + bv;
                if (MODE == 0) {
                    Cb[(size_t)row * E_ + col] = f2bf(v);
                } else {
                    int b = row >> 11, l = row & (L_ - 1);
                    size_t oi = (size_t)l * (B_ * E_) + b * E_ + col;
                    Cf[oi] = v + ident[oi];
                }
            }
        }
    }
}

__global__ __launch_bounds__(256) void k_gemm3(const short* __restrict__ A,
    const short* __restrict__ W0, const short* __restrict__ W1, const short* __restrict__ W2,
    const float* __restrict__ b0, const float* __restrict__ b1, const float* __restrict__ b2,
    short* __restrict__ C0, short* __restrict__ C1, short* __restrict__ C2) {
    int wg = blockIdx.x;
    int sw = (wg & 7) * 96 + (wg >> 3);
    int bx = sw & 7, by = (sw >> 3) & 31, z = sw >> 8;
    const short* Bw = z == 0 ? W0 : (z == 1 ? W1 : W2);
    const float* bias = z == 0 ? b0 : (z == 1 ? b1 : b2);
    short* C = z == 0 ? C0 : (z == 1 ? C1 : C2);
    gemm_body<0, 128, 128>(A, Bw, bias, C, nullptr, nullptr, bx, by);
}

__global__ __launch_bounds__(256) void k_gemmo(const short* __restrict__ A,
                                               const short* __restrict__ Bw,
                                               const float* __restrict__ bias,
                                               float* __restrict__ C,
                                               const float* __restrict__ ident) {
    int wg = blockIdx.x;
    int sw = (wg & 7) * 64 + (wg >> 3);
    int bx = sw & 15, by = sw >> 4;
    gemm_body<1, 128, 64>(A, Bw, bias, nullptr, C, ident, bx, by);
}

// ---- qsum[b][f] = xsum[b]. dot q_w[f] + L*q_b[f]  (f32 exact) ----
__global__ void k_qsum(const float* __restrict__ xsum, const float* __restrict__ qw,
                       const float* __restrict__ qb, float* __restrict__ qsum) {
    int wid = threadIdx.x >> 6, lane = threadIdx.x & 63;
    int gid = blockIdx.x * 4 + wid;
    int b = gid >> 10, f = gid & 1023;
    float s = 0.f;
    for (int e = lane; e < E_; e += 64) s += xsum[b * E_ + e] * qw[f * E_ + e];
#pragma unroll
    for (int off = 32; off; off >>= 1) s += __shfl_xor(s, off);
    if (lane == 0) qsum[gid] = s + (float)L_ * qb[f];
}

// ---- t[b,h,e] = sum_d qsum[b,h*64+d] * k_w[h*64+d, e] ----
__global__ void k_t(const float* __restrict__ qsum, const float* __restrict__ kw,
                    float* __restrict__ tb) {
    int i = blockIdx.x * 256 + threadIdx.x;
    int e = i & 1023, bh = i >> 10;
    int b = bh >> 4, h = bh & 15;
    float s = 0.f;
#pragma unroll
    for (int d = 0; d < HD_; ++d)
        s += qsum[b * E_ + h * HD_ + d] * kw[(size_t)(h * HD_ + d) * E_ + e];
    tb[i] = s;
}

// ---- partial scores over e-quarters ----
__global__ __launch_bounds__(256) void k_score(const float* __restrict__ query,
                                               const float* __restrict__ tb,
                                               float* __restrict__ scorp) {
    __shared__ float xs[64][68];
    __shared__ float ts[16][68];
    int id = blockIdx.x;
    int eq = id >> 6;
    int b = (id >> 5) & 1;
    int n0 = (id & 31) * 64;
    int tid = threadIdx.x;
    int hg = tid & 3, rg = tid >> 2;
    float acc[4] = {0.f, 0.f, 0.f, 0.f};
    for (int e0 = eq * 256; e0 < eq * 256 + 256; e0 += 64) {
        __syncthreads();
        for (int j = tid; j < 1024; j += 256) {
            int r = j >> 4, c4 = (j & 15) * 4;
            float4 v = *reinterpret_cast<const float4*>(
                &query[(size_t)(n0 + r) * (B_ * E_) + b * E_ + e0 + c4]);
            *reinterpret_cast<float4*>(&xs[r][c4]) = v;
        }
        {
            int hh = tid >> 4, c4 = (tid & 15) * 4;
            float4 v = *reinterpret_cast<const float4*>(&tb[(size_t)(b * 16 + hh) * E_ + e0 + c4]);
            *reinterpret_cast<float4*>(&ts[hh][c4]) = v;
        }
        __syncthreads();
        for (int c = 0; c < 64; ++c) {
            float x0 = xs[rg][c];
#pragma unroll
            for (int j = 0; j < 4; ++j) acc[j] += x0 * ts[hg + 4 * j][c];
        }
    }
#pragma unroll
    for (int j = 0; j < 4; ++j) {
        int h = hg + 4 * j;
        scorp[(size_t)eq * 65536 + (size_t)(b * 16 + h) * L_ + n0 + rg] = acc[j];
    }
}

// ---- top-64 per (b,h): fused e-quarter reduce + wave radix-select; gather
// rewritten: 8 rows/wave-iteration via short8 (8 lanes x 16B = one 64-bf16 row),
// sel indices hoisted to registers, 8 independent unrolled iterations (MLP) ----
__global__ __launch_bounds__(256) void k_topk(const float* __restrict__ scorp,
                                              const short* __restrict__ kb,
                                              short* __restrict__ selkb) {
    __shared__ int sel[4][64];
    int wid = threadIdx.x >> 6, lane = threadIdx.x & 63;
    int bh = blockIdx.x * 4 + wid;  // grid 8
    int b = bh >> 4, h = bh & 15;

    unsigned u[32];
#pragma unroll
    for (int j = 0; j < 32; ++j) {
        int base = bh * L_ + j * 64 + lane;
        float sc = ((scorp[base] + scorp[base + 65536]) + scorp[base + 131072]) + scorp[base + 196608];
        sc *= SCALE;
        unsigned bits = __float_as_uint(sc);
        u[j] = (bits & 0x80000000u) ? ~bits : (bits | 0x80000000u);
    }
    unsigned prefix = 0;
    int k = TOPK_;
    for (int bit = 31; bit >= 0; --bit) {
        unsigned cand = prefix | (1u << bit);
        int c = 0;
#pragma unroll
        for (int j = 0; j < 32; ++j) c += ((u[j] >> bit) == (cand >> bit)) ? 1 : 0;
#pragma unroll
        for (int off = 32; off; off >>= 1) c += __shfl_xor(c, off);
        if (c >= k) prefix = cand; else k -= c;
    }
    unsigned T = prefix;
    int nStrict = 0;
#pragma unroll
    for (int j = 0; j < 32; ++j) nStrict += (u[j] > T) ? 1 : 0;
#pragma unroll
    for (int off = 32; off; off >>= 1) nStrict += __shfl_xor(nStrict, off);
    int nTies = TOPK_ - nStrict;

    int strictBase = 0, tieBase = 0;
    unsigned long long below = (lane == 0) ? 0ull : ((~0ull) >> (64 - lane));
#pragma unroll
    for (int j = 0; j < 32; ++j) {
        unsigned long long mS = __ballot(u[j] > T);
        unsigned long long mT = __ballot(u[j] == T);
        if (u[j] > T) {
            int slot = strictBase + __popcll(mS & below);
            sel[wid][slot] = j * 64 + lane;
        } else if (u[j] == T) {
            int r = tieBase + __popcll(mT & below);
            if (r < nTies) sel[wid][nStrict + r] = j * 64 + lane;
        }
        strictBase += __popcll(mS);
        tieBase += __popcll(mT);
    }
    __syncthreads();

    // parallel gather: m = it*8 + (lane>>3); lane&7 picks the 16B chunk of the row
    int idx8[8];
#pragma unroll
    for (int it = 0; it < 8; ++it) idx8[it] = sel[wid][it * 8 + (lane >> 3)];
#pragma unroll
    for (int it = 0; it < 8; ++it) {
        int m = it * 8 + (lane >> 3);
        const short* src = kb + ((size_t)b * L_ + idx8[it]) * E_ + h * HD_ + (lane & 7) * 8;
        short8 v = *reinterpret_cast<const short8*>(src);
        *reinterpret_cast<short8*>(
            selkb + (size_t)bh * 4096 + m * 64 + (((lane & 7) ^ (m & 7)) * 8)) = v;
    }
}

// ---- vtb[bh*64+d][l] = v[b,l,h*64+d]  (bf16 transpose for W-MFMA B-operand) ----
__global__ __launch_bounds__(256) void k_vt(const short* __restrict__ vb,
                                            short* __restrict__ vtb) {
    __shared__ short ts[64][68];
    int blk = blockIdx.x;             // 1024 = 32 bh x 32 l-tiles
    int bh = blk >> 5, l0 = (blk & 31) * 64;
    int b = bh >> 4, h = bh & 15;
    int tid = threadIdx.x;
    int l = tid >> 2, d0 = (tid & 3) * 16;
    const short* src = vb + ((size_t)(b * L_ + l0 + l)) * E_ + h * 64 + d0;
    short8 v0 = *reinterpret_cast<const short8*>(src);
    short8 v1 = *reinterpret_cast<const short8*>(src + 8);
#pragma unroll
    for (int j = 0; j < 8; ++j) ts[d0 + j][l] = v0[j];
#pragma unroll
    for (int j = 0; j < 8; ++j) ts[d0 + 8 + j][l] = v1[j];
    __syncthreads();
    int d = tid >> 2, lp = (tid & 3) * 16;
    short* dst = vtb + ((size_t)(bh * 64 + d)) * 2048 + l0 + lp;
#pragma unroll
    for (int j = 0; j < 4; ++j)
        *reinterpret_cast<short4v*>(dst + j * 4) =
            *reinterpret_cast<const short4v*>(&ts[d][lp + j * 4]);
}

// ---- attW: S_k = k.selk^T (MFMA) -> softmax -> Wpart = P2^T v (MFMA) ----
__global__ __launch_bounds__(256) void k_attW(const short* __restrict__ kb,
                                              const short* __restrict__ vtb,
                                              const short* __restrict__ selkb,
                                              float* __restrict__ wpart) {
    __shared__ short sk[4096], kt[4096], vt[4096], pt[4096];
    int wg = blockIdx.x;
    int sw = (wg & 7) * 64 + (wg >> 3);   // XCD swizzle, 512 blocks
    int bh = sw & 31, ch = sw >> 5;       // ch 0..15, chunk = 128 l
    int b = bh >> 4, h = bh & 15;
    int tid = threadIdx.x, w = tid >> 6, lane = tid & 63;
    int lr = lane & 15, kg = lane >> 4;

#pragma unroll
    for (int j = 0; j < 2; ++j) {
        int off = (w * 2 + j) * 512;
        __builtin_amdgcn_global_load_lds(
            (const __attribute__((address_space(1))) void*)(selkb + (size_t)bh * 4096 + off + lane * 8),
            (__attribute__((address_space(3))) void*)(sk + off), 16, 0, 0);
    }

    f32x4 accw[4];
#pragma unroll
    for (int i = 0; i < 4; ++i) accw[i] = (f32x4){0.f, 0.f, 0.f, 0.f};

    for (int t = 0; t < 2; ++t) {
        int lt = ch * 128 + t * 64;
#pragma unroll
        for (int j = 0; j < 2; ++j) {
            int r = w * 16 + j * 8 + (lane >> 3);
            int s = lane & 7;
            const short* src = kb + ((size_t)(b * L_ + lt + r)) * E_ + h * 64 + ((s ^ (r & 7)) * 8);
            __builtin_amdgcn_global_load_lds(
                (const __attribute__((address_space(1))) void*)src,
                (__attribute__((address_space(3))) void*)(kt + (w * 16 + j * 8) * 64), 16, 0, 0);
        }
        __syncthreads();

        f32x4 s4[4];
#pragma unroll
        for (int i = 0; i < 4; ++i) s4[i] = (f32x4){0.f, 0.f, 0.f, 0.f};
#pragma unroll
        for (int kk = 0; kk < 2; ++kk) {
            int row = w * 16 + lr;
            short8 a = *reinterpret_cast<const short8*>(
                kt + row * 64 + (((kk * 4 + kg) ^ (row & 7)) * 8));
#pragma unroll
            for (int ni = 0; ni < 4; ++ni) {
                int m = ni * 16 + lr;
                short8 bb = *reinterpret_cast<const short8*>(
                    sk + m * 64 + (((kk * 4 + kg) ^ (m & 7)) * 8));
                s4[ni] = __builtin_amdgcn_mfma_f32_16x16x32_bf16(a, bb, s4[ni], 0, 0, 0);
            }
        }
        float p[4][4];
#pragma unroll
        for (int r = 0; r < 4; ++r) {
            float v0 = s4[0][r] * SCALE, v1 = s4[1][r] * SCALE;
            float v2 = s4[2][r] * SCALE, v3 = s4[3][r] * SCALE;
            float mx = fmaxf(fmaxf(v0, v1), fmaxf(v2, v3));
            mx = fmaxf(mx, __shfl_xor(mx, 1));
            mx = fmaxf(mx, __shfl_xor(mx, 2));
            mx = fmaxf(mx, __shfl_xor(mx, 4));
            mx = fmaxf(mx, __shfl_xor(mx, 8));
            float e0 = __expf(v0 - mx), e1 = __expf(v1 - mx);
            float e2 = __expf(v2 - mx), e3 = __expf(v3 - mx);
            float sm = e0 + e1 + e2 + e3;
            sm += __shfl_xor(sm, 1);
            sm += __shfl_xor(sm, 2);
            sm += __shfl_xor(sm, 4);
            sm += __shfl_xor(sm, 8);
            float inv = 1.f / sm;
            p[0][r] = e0 * inv; p[1][r] = e1 * inv; p[2][r] = e2 * inv; p[3][r] = e3 * inv;
        }
#pragma unroll
        for (int ni = 0; ni < 4; ++ni)
#pragma unroll
            for (int r = 0; r < 4; ++r) {
                int m = ni * 16 + lr;
                int ll = w * 16 + kg * 4 + r;
                pt[m * 64 + (((ll >> 3) ^ (m & 7)) * 8) + (ll & 7)] = f2bf(p[ni][r]);
            }
#pragma unroll
        for (int j = 0; j < 2; ++j) {
            int d = w * 16 + j * 8 + (lane >> 3);
            int s = lane & 7;
            const short* src = vtb + ((size_t)(bh * 64 + d)) * 2048 + lt + ((s ^ (d & 7)) * 8);
            __builtin_amdgcn_global_load_lds(
                (const __attribute__((address_space(1))) void*)src,
                (__attribute__((address_space(3))) void*)(vt + (w * 16 + j * 8) * 64), 16, 0, 0);
        }
        __syncthreads();
#pragma unroll
        for (int kk = 0; kk < 2; ++kk) {
            int mm = w * 16 + lr;
            short8 a = *reinterpret_cast<const short8*>(
                pt + mm * 64 + (((kk * 4 + kg) ^ (mm & 7)) * 8));
#pragma unroll
            for (int ni = 0; ni < 4; ++ni) {
                int d = ni * 16 + lr;
                short8 bb = *reinterpret_cast<const short8*>(
                    vt + d * 64 + (((kk * 4 + kg) ^ (d & 7)) * 8));
                accw[ni] = __builtin_amdgcn_mfma_f32_16x16x32_bf16(a, bb, accw[ni], 0, 0, 0);
            }
        }
    }
#pragma unroll
    for (int ni = 0; ni < 4; ++ni)
#pragma unroll
        for (int r = 0; r < 4; ++r) {
            int m = w * 16 + kg * 4 + r;
            int d = ni * 16 + lr;
            wpart[((size_t)(ch * 32 + bh)) * 4096 + m * 64 + d] = accw[ni][r];
        }
}

// ---- reduce wpart chunks -> Wt global bf16, transposed + pre-swizzled ----
__global__ void k_wreduce(const float* __restrict__ wpart, short* __restrict__ wtg) {
    int i = blockIdx.x * 256 + threadIdx.x;  // 131072, grid 512
    float s = 0.f;
#pragma unroll
    for (int c = 0; c < 16; ++c) s += wpart[(size_t)c * 131072 + i];
    int bh = i >> 12, m = (i >> 6) & 63, d = i & 63;
    wtg[(size_t)bh * 4096 + d * 64 + (((m >> 3) ^ (d & 7)) * 8) + (m & 7)] = f2bf(s);
}

// ---- attO: S_q = q.selk^T (MFMA) -> softmax -> att = P1.W (MFMA) -> bf16 ----
__global__ __launch_bounds__(256) void k_attO(const short* __restrict__ qb,
                                              const short* __restrict__ selkb,
                                              const short* __restrict__ wtg,
                                              short* __restrict__ att) {
    __shared__ short sk[4096], wt[4096], qt[4096], p1[4096];
    int wg = blockIdx.x;
    int sw = (wg & 7) * 64 + (wg >> 3);
    int bh = sw & 31, ch = sw >> 5;
    int b = bh >> 4, h = bh & 15;
    int tid = threadIdx.x, w = tid >> 6, lane = tid & 63;
    int lr = lane & 15, kg = lane >> 4;

#pragma unroll
    for (int j = 0; j < 2; ++j) {
        int off = (w * 2 + j) * 512;
        __builtin_amdgcn_global_load_lds(
            (const __attribute__((address_space(1))) void*)(selkb + (size_t)bh * 4096 + off + lane * 8),
            (__attribute__((address_space(3))) void*)(sk + off), 16, 0, 0);
        __builtin_amdgcn_global_load_lds(
            (const __attribute__((address_space(1))) void*)(wtg + (size_t)bh * 4096 + off + lane * 8),
            (__attribute__((address_space(3))) void*)(wt + off), 16, 0, 0);
    }

    for (int t = 0; t < 2; ++t) {
        int lt = ch * 128 + t * 64;
#pragma unroll
        for (int j = 0; j < 2; ++j) {
            int r = w * 16 + j * 8 + (lane >> 3);
            int s = lane & 7;
            const short* src = qb + ((size_t)(b * L_ + lt + r)) * E_ + h * 64 + ((s ^ (r & 7)) * 8);
            __builtin_amdgcn_global_load_lds(
                (const __attribute__((address_space(1))) void*)src,
                (__attribute__((address_space(3))) void*)(qt + (w * 16 + j * 8) * 64), 16, 0, 0);
        }
        __syncthreads();

        f32x4 s4[4];
#pragma unroll
        for (int i = 0; i < 4; ++i) s4[i] = (f32x4){0.f, 0.f, 0.f, 0.f};
#pragma unroll
        for (int kk = 0; kk < 2; ++kk) {
            int row = w * 16 + lr;
            short8 a = *reinterpret_cast<const short8*>(
                qt + row * 64 + (((kk * 4 + kg) ^ (row & 7)) * 8));
#pragma unroll
            for (int ni = 0; ni < 4; ++ni) {
                int m = ni * 16 + lr;
                short8 bb = *reinterpret_cast<const short8*>(
                    sk + m * 64 + (((kk * 4 + kg) ^ (m & 7)) * 8));
                s4[ni] = __builtin_amdgcn_mfma_f32_16x16x32_bf16(a, bb, s4[ni], 0, 0, 0);
            }
        }
        float p[4][4];
#pragma unroll
        for (int r = 0; r < 4; ++r) {
            float v0 = s4[0][r] * SCALE, v1 = s4[1][r] * SCALE;
            float v2 = s4[2][r] * SCALE, v3 = s4[3][r] * SCALE;
            float mx = fmaxf(fmaxf(v0, v1), fmaxf(v2, v3));
            mx = fmaxf(mx, __shfl_xor(mx, 1));
            mx = fmaxf(mx, __shfl_xor(mx, 2));
            mx = fmaxf(mx, __shfl_xor(mx, 4));
            mx = fmaxf(mx, __shfl_xor(mx, 8));
            float e0 = __expf(v0 - mx), e1 = __expf(v1 - mx);
            float e2 = __expf(v2 - mx), e3 = __expf(v3 - mx);
            float sm = e0 + e1 + e2 + e3;
            sm += __shfl_xor(sm, 1);
            sm += __shfl_xor(sm, 2);
            sm += __shfl_xor(sm, 4);
            sm += __shfl_xor(sm, 8);
            float inv = 1.f / sm;
            p[0][r] = e0 * inv; p[1][r] = e1 * inv; p[2][r] = e2 * inv; p[3][r] = e3 * inv;
        }
#pragma unroll
        for (int ni = 0; ni < 4; ++ni)
#pragma unroll
            for (int r = 0; r < 4; ++r) {
                int m = ni * 16 + lr;
                int ll = w * 16 + kg * 4 + r;
                p1[ll * 64 + (((m >> 3) ^ (ll & 7)) * 8) + (m & 7)] = f2bf(p[ni][r]);
            }
        __syncthreads();
        f32x4 ao[4];
#pragma unroll
        for (int i = 0; i < 4; ++i) ao[i] = (f32x4){0.f, 0.f, 0.f, 0.f};
#pragma unroll
        for (int kk = 0; kk < 2; ++kk) {
            int row = w * 16 + lr;
            short8 a = *reinterpret_cast<const short8*>(
                p1 + row * 64 + (((kk * 4 + kg) ^ (row & 7)) * 8));
#pragma unroll
            for (int ni = 0; ni < 4; ++ni) {
                int d = ni * 16 + lr;
                short8 bb = *reinterpret_cast<const short8*>(
                    wt + d * 64 + (((kk * 4 + kg) ^ (d & 7)) * 8));
                ao[ni] = __builtin_amdgcn_mfma_f32_16x16x32_bf16(a, bb, ao[ni], 0, 0, 0);
            }
        }
#pragma unroll
        for (int ni = 0; ni < 4; ++ni)
#pragma unroll
            for (int r = 0; r < 4; ++r) {
                int l = lt + w * 16 + kg * 4 + r;
                int d = ni * 16 + lr;
                att[((size_t)(b * L_ + l)) * E_ + h * 64 + d] = f2bf(ao[ni][r]);
            }
    }
}

extern "C" void kernel_launch(void* const* d_in, const int* in_sizes, int n_in,
                              void* d_out, int out_size, void* d_ws, size_t ws_size,
                              hipStream_t stream) {
    const float* query = (const float*)d_in[0];
    const float* q_w = (const float*)d_in[1];
    const float* q_b = (const float*)d_in[2];
    const float* k_w = (const float*)d_in[3];
    const float* k_b = (const float*)d_in[4];
    const float* v_w = (const float*)d_in[5];
    const float* v_b = (const float*)d_in[6];
    const float* o_w = (const float*)d_in[7];
    const float* o_b = (const float*)d_in[8];
    float* out = (float*)d_out;

    char* p = (char*)d_ws;
    auto alloc = [&](size_t bytes) {
        char* r = p;
        p += (bytes + 255) & ~(size_t)255;
        return r;
    };
    short* xb    = (short*)alloc((size_t)MROWS * E_ * 2);
    short* qwb   = (short*)alloc((size_t)E_ * E_ * 2);
    short* kwb   = (short*)alloc((size_t)E_ * E_ * 2);
    short* vwb   = (short*)alloc((size_t)E_ * E_ * 2);
    short* owb   = (short*)alloc((size_t)E_ * E_ * 2);
    short* qbuf  = (short*)alloc((size_t)MROWS * E_ * 2);
    short* kbuf  = (short*)alloc((size_t)MROWS * E_ * 2);
    short* vbuf  = (short*)alloc((size_t)MROWS * E_ * 2);
    short* vtb   = (short*)alloc((size_t)32 * 64 * 2048 * 2);
    float* xpart = (float*)alloc((size_t)16 * B_ * E_ * 4);
    float* xsum  = (float*)alloc((size_t)B_ * E_ * 4);
    float* qsum  = (float*)alloc((size_t)B_ * E_ * 4);
    float* tb    = (float*)alloc((size_t)B_ * H_ * E_ * 4);
    float* scorp = (float*)alloc((size_t)4 * B_ * H_ * L_ * 4);
    short* selkb = (short*)alloc((size_t)32 * 4096 * 2);
    short* wtg   = (short*)alloc((size_t)32 * 4096 * 2);
    float* wpart = (float*)alloc((size_t)16 * 32 * 4096 * 4);
    short* att   = (short*)alloc((size_t)MROWS * E_ * 2);

    // stage 1: merged transpose+casts, exact sums
    k_prep<<<8192, 256, 0, stream>>>(query, q_w, k_w, v_w, o_w, xb, qwb, kwb, vwb, owb);
    k_xsum<<<128, 256, 0, stream>>>(query, xpart);
    k_xred<<<8, 256, 0, stream>>>(xpart, xsum);

    // stage 2: fused q/k/v projections (dbuf 2-phase + T2 swizzle)
    k_gemm3<<<768, 256, 0, stream>>>(xb, qwb, kwb, vwb, q_b, k_b, v_b, qbuf, kbuf, vbuf);

    // stage 3: exact f32 scores + fused top-k + v transpose
    k_qsum<<<512, 256, 0, stream>>>(xsum, q_w, q_b, qsum);
    k_t<<<128, 256, 0, stream>>>(qsum, k_w, tb);
    k_score<<<256, 256, 0, stream>>>(query, tb, scorp);
    k_topk<<<8, 256, 0, stream>>>(scorp, kbuf, selkb);
    k_vt<<<1024, 256, 0, stream>>>(vbuf, vtb);

    // stage 4: MFMA attention core
    k_attW<<<512, 256, 0, stream>>>(kbuf, vtb, selkb, wpart);
    k_wreduce<<<512, 256, 0, stream>>>(wpart, wtg);
    k_attO<<<512, 256, 0, stream>>>(qbuf, selkb, wtg, att);

    // stage 5: o-projection fused with bias + residual + transpose back
    k_gemmo<<<512, 256, 0, stream>>>(att, owb, o_b, out, query);
}

// Round 8
// 173.628 us; speedup vs baseline: 2.6168x; 1.0035x over previous
//
#include <hip/hip_runtime.h>
#include <hip/hip_bf16.h>

#define L_ 2048
#define B_ 2
#define E_ 1024
#define H_ 16
#define HD_ 64
#define TOPK_ 64
#define MROWS (B_*L_)
#define SCALE 0.125f

typedef __attribute__((ext_vector_type(8))) short short8;
typedef __attribute__((ext_vector_type(4))) short short4v;
typedef __attribute__((ext_vector_type(4))) float f32x4;

static __device__ __forceinline__ short f2bf(float f) {
    __hip_bfloat16 h = __float2bfloat16(f);
    return *reinterpret_cast<short*>(&h);
}
static __device__ __forceinline__ float bf2f(short s) {
    unsigned u = ((unsigned)(unsigned short)s) << 16;
    return __uint_as_float(u);
}

// ---- merged: transpose x->bf16 + cast 4 weights + xsum partials (grid 8320) ----
__global__ void k_prep(const float* __restrict__ q,
                       const float* __restrict__ w0, const float* __restrict__ w1,
                       const float* __restrict__ w2, const float* __restrict__ w3,
                       short* __restrict__ xb,
                       short* __restrict__ o0, short* __restrict__ o1,
                       short* __restrict__ o2, short* __restrict__ o3,
                       float* __restrict__ xpart) {
    int blk = blockIdx.x;
    if (blk < 4096) {
        int i = blk * 256 + threadIdx.x;
        int idx = i * 4;
        int e = idx & (E_ - 1);
        int l = (idx >> 10) & (L_ - 1);
        int b = idx >> 21;
        float4 v = *reinterpret_cast<const float4*>(q + l * (B_ * E_) + b * E_ + e);
        short4v o;
        o[0] = f2bf(v.x); o[1] = f2bf(v.y); o[2] = f2bf(v.z); o[3] = f2bf(v.w);
        *reinterpret_cast<short4v*>(xb + idx) = o;
    } else if (blk < 8192) {
        int cb = blk - 4096;
        int sel = cb >> 10, lb = cb & 1023;
        const float* w = sel == 0 ? w0 : sel == 1 ? w1 : sel == 2 ? w2 : w3;
        short* o = sel == 0 ? o0 : sel == 1 ? o1 : sel == 2 ? o2 : o3;
        int i = lb * 256 + threadIdx.x;
        float4 v = *reinterpret_cast<const float4*>(w + i * 4);
        short4v s;
        s[0] = f2bf(v.x); s[1] = f2bf(v.y); s[2] = f2bf(v.z); s[3] = f2bf(v.w);
        *reinterpret_cast<short4v*>(o + i * 4) = s;
    } else {
        int cb = blk - 8192;           // 0..127
        int cg = cb & 7, ch = cb >> 3;
        int col = cg * 256 + threadIdx.x;
        float s = 0.f;
        for (int l = ch * 128; l < (ch + 1) * 128; ++l) s += q[(size_t)l * (B_ * E_) + col];
        xpart[ch * (B_ * E_) + col] = s;
    }
}

// ---- GEMM core: single-buffer (m97-style), T2 LDS XOR-swizzle, 32KB -> 5 blk/CU ----
// Swizzle (rule #21, both-sides): global source chunk = (lane&7) ^ (stage_row&7),
// LDS dest linear, ds_read chunk = (kk*4+kg) ^ (frag_row&7).
template<int MODE, int BM, int BN>
__device__ __forceinline__ void gemm_body(const short* __restrict__ A,
                                          const short* __restrict__ Bw,
                                          const float* __restrict__ bias,
                                          short* __restrict__ Cb,
                                          float* __restrict__ Cf,
                                          const float* __restrict__ ident,
                                          int bx, int by) {
    const int K = E_;
    constexpr int MI = BM / 32;
    constexpr int NI = BN / 32;
    __shared__ short As[BM * 64];
    __shared__ short Bs[BN * 64];
    int tid = threadIdx.x;
    int lane = tid & 63;
    int wid = tid >> 6;
    int wr = wid >> 1, wc = wid & 1;
    int lrow = lane & 15;
    int kg = lane >> 4;
    int lr8 = lane >> 3;
    int swz = (((lane & 7) ^ (lr8 & 7)) * 8);
    int rx = lrow & 7;
    int mBase = by * BM, nBase = bx * BN;

    f32x4 acc[MI][NI];
#pragma unroll
    for (int i = 0; i < MI; ++i)
#pragma unroll
        for (int j = 0; j < NI; ++j) acc[i][j] = (f32x4){0.f, 0.f, 0.f, 0.f};

    for (int k0 = 0; k0 < K; k0 += 64) {
        __syncthreads();                // protect LDS from prior iteration's readers
#pragma unroll
        for (int i = 0; i < BM / 32; ++i) {
            int r0 = (wid * (BM / 32) + i) * 8;
            const short* ga = A + (size_t)(mBase + r0 + lr8) * K + k0 + swz;
            __builtin_amdgcn_global_load_lds(
                (const __attribute__((address_space(1))) void*)ga,
                (__attribute__((address_space(3))) void*)(As + r0 * 64), 16, 0, 0);
        }
#pragma unroll
        for (int i = 0; i < BN / 32; ++i) {
            int r0 = (wid * (BN / 32) + i) * 8;
            const short* gb = Bw + (size_t)(nBase + r0 + lr8) * K + k0 + swz;
            __builtin_amdgcn_global_load_lds(
                (const __attribute__((address_space(1))) void*)gb,
                (__attribute__((address_space(3))) void*)(Bs + r0 * 64), 16, 0, 0);
        }
        asm volatile("s_waitcnt vmcnt(0)" ::: "memory");
        __syncthreads();

        short8 af[2][MI], bf[2][NI];
#pragma unroll
        for (int kk = 0; kk < 2; ++kk) {
#pragma unroll
            for (int mi = 0; mi < MI; ++mi)
                af[kk][mi] = *reinterpret_cast<const short8*>(
                    As + (wr * (MI * 16) + mi * 16 + lrow) * 64 + (((kk * 4 + kg) ^ rx) * 8));
#pragma unroll
            for (int ni = 0; ni < NI; ++ni)
                bf[kk][ni] = *reinterpret_cast<const short8*>(
                    Bs + (wc * (NI * 16) + ni * 16 + lrow) * 64 + (((kk * 4 + kg) ^ rx) * 8));
        }
#pragma unroll
        for (int kk = 0; kk < 2; ++kk)
#pragma unroll
            for (int mi = 0; mi < MI; ++mi)
#pragma unroll
                for (int ni = 0; ni < NI; ++ni)
                    acc[mi][ni] = __builtin_amdgcn_mfma_f32_16x16x32_bf16(
                        af[kk][mi], bf[kk][ni], acc[mi][ni], 0, 0, 0);
    }

    int rowq = (lane >> 4) * 4;
    int coll = lane & 15;
#pragma unroll
    for (int mi = 0; mi < MI; ++mi) {
#pragma unroll
        for (int ni = 0; ni < NI; ++ni) {
            int col = nBase + wc * (NI * 16) + ni * 16 + coll;
            float bv = bias[col];
#pragma unroll
            for (int r = 0; r < 4; ++r) {
                int row = mBase + wr * (MI * 16) + mi * 16 + rowq + r;
                float v = acc[mi][ni][r] + bv;
                if (MODE == 0) {
                    Cb[(size_t)row * E_ + col] = f2bf(v);
                } else {
                    int b = row >> 11, l = row & (L_ - 1);
                    size_t oi = (size_t)l * (B_ * E_) + b * E_ + col;
                    Cf[oi] = v + ident[oi];
                }
            }
        }
    }
}

__global__ __launch_bounds__(256) void k_gemm3(const short* __restrict__ A,
    const short* __restrict__ W0, const short* __restrict__ W1, const short* __restrict__ W2,
    const float* __restrict__ b0, const float* __restrict__ b1, const float* __restrict__ b2,
    short* __restrict__ C0, short* __restrict__ C1, short* __restrict__ C2) {
    int wg = blockIdx.x;
    int sw = (wg & 7) * 96 + (wg >> 3);
    int bx = sw & 7, by = (sw >> 3) & 31, z = sw >> 8;
    const short* Bw = z == 0 ? W0 : (z == 1 ? W1 : W2);
    const float* bias = z == 0 ? b0 : (z == 1 ? b1 : b2);
    short* C = z == 0 ? C0 : (z == 1 ? C1 : C2);
    gemm_body<0, 128, 128>(A, Bw, bias, C, nullptr, nullptr, bx, by);
}

__global__ __launch_bounds__(256) void k_gemmo(const short* __restrict__ A,
                                               const short* __restrict__ Bw,
                                               const float* __restrict__ bias,
                                               float* __restrict__ C,
                                               const float* __restrict__ ident) {
    int wg = blockIdx.x;
    int sw = (wg & 7) * 64 + (wg >> 3);
    int bx = sw & 15, by = sw >> 4;
    gemm_body<1, 128, 64>(A, Bw, bias, nullptr, C, ident, bx, by);
}

// ---- qsum[b][f] = xsum[b]. dot q_w[f] + L*q_b[f]; xsum reduced from xpart in LDS ----
__global__ __launch_bounds__(256) void k_qsum(const float* __restrict__ xpart,
                                              const float* __restrict__ qw,
                                              const float* __restrict__ qb,
                                              float* __restrict__ qsum) {
    __shared__ float xs[1024];
    int tid = threadIdx.x;
    int wid = tid >> 6, lane = tid & 63;
    int gid = blockIdx.x * 4 + wid;
    int b = gid >> 10, f = gid & 1023;   // b uniform per block (gid 4-aligned)
    for (int j = tid; j < 1024; j += 256) {
        float s = 0.f;
#pragma unroll
        for (int c = 0; c < 16; ++c) s += xpart[c * (B_ * E_) + b * E_ + j];
        xs[j] = s;
    }
    __syncthreads();
    float s = 0.f;
    for (int e = lane; e < E_; e += 64) s += xs[e] * qw[f * E_ + e];
#pragma unroll
    for (int off = 32; off; off >>= 1) s += __shfl_xor(s, off);
    if (lane == 0) qsum[gid] = s + (float)L_ * qb[f];
}

// ---- t[b,h,e] = sum_d qsum[b,h*64+d] * k_w[h*64+d, e] ----
__global__ void k_t(const float* __restrict__ qsum, const float* __restrict__ kw,
                    float* __restrict__ tb) {
    int i = blockIdx.x * 256 + threadIdx.x;
    int e = i & 1023, bh = i >> 10;
    int b = bh >> 4, h = bh & 15;
    float s = 0.f;
#pragma unroll
    for (int d = 0; d < HD_; ++d)
        s += qsum[b * E_ + h * HD_ + d] * kw[(size_t)(h * HD_ + d) * E_ + e];
    tb[i] = s;
}

// ---- partial scores over e-quarters ----
__global__ __launch_bounds__(256) void k_score(const float* __restrict__ query,
                                               const float* __restrict__ tb,
                                               float* __restrict__ scorp) {
    __shared__ float xs[64][68];
    __shared__ float ts[16][68];
    int id = blockIdx.x;
    int eq = id >> 6;
    int b = (id >> 5) & 1;
    int n0 = (id & 31) * 64;
    int tid = threadIdx.x;
    int hg = tid & 3, rg = tid >> 2;
    float acc[4] = {0.f, 0.f, 0.f, 0.f};
    for (int e0 = eq * 256; e0 < eq * 256 + 256; e0 += 64) {
        __syncthreads();
        for (int j = tid; j < 1024; j += 256) {
            int r = j >> 4, c4 = (j & 15) * 4;
            float4 v = *reinterpret_cast<const float4*>(
                &query[(size_t)(n0 + r) * (B_ * E_) + b * E_ + e0 + c4]);
            *reinterpret_cast<float4*>(&xs[r][c4]) = v;
        }
        {
            int hh = tid >> 4, c4 = (tid & 15) * 4;
            float4 v = *reinterpret_cast<const float4*>(&tb[(size_t)(b * 16 + hh) * E_ + e0 + c4]);
            *reinterpret_cast<float4*>(&ts[hh][c4]) = v;
        }
        __syncthreads();
        for (int c = 0; c < 64; ++c) {
            float x0 = xs[rg][c];
#pragma unroll
            for (int j = 0; j < 4; ++j) acc[j] += x0 * ts[hg + 4 * j][c];
        }
    }
#pragma unroll
    for (int j = 0; j < 4; ++j) {
        int h = hg + 4 * j;
        scorp[(size_t)eq * 65536 + (size_t)(b * 16 + h) * L_ + n0 + rg] = acc[j];
    }
}

// ---- top-64 per (b,h): fused e-quarter reduce + wave radix-select + wide gather ----
__global__ __launch_bounds__(256) void k_topk(const float* __restrict__ scorp,
                                              const short* __restrict__ kb,
                                              short* __restrict__ selkb) {
    __shared__ int sel[4][64];
    int wid = threadIdx.x >> 6, lane = threadIdx.x & 63;
    int bh = blockIdx.x * 4 + wid;  // grid 8
    int b = bh >> 4, h = bh & 15;

    unsigned u[32];
#pragma unroll
    for (int j = 0; j < 32; ++j) {
        int base = bh * L_ + j * 64 + lane;
        float sc = ((scorp[base] + scorp[base + 65536]) + scorp[base + 131072]) + scorp[base + 196608];
        sc *= SCALE;
        unsigned bits = __float_as_uint(sc);
        u[j] = (bits & 0x80000000u) ? ~bits : (bits | 0x80000000u);
    }
    unsigned prefix = 0;
    int k = TOPK_;
    for (int bit = 31; bit >= 0; --bit) {
        unsigned cand = prefix | (1u << bit);
        int c = 0;
#pragma unroll
        for (int j = 0; j < 32; ++j) c += ((u[j] >> bit) == (cand >> bit)) ? 1 : 0;
#pragma unroll
        for (int off = 32; off; off >>= 1) c += __shfl_xor(c, off);
        if (c >= k) prefix = cand; else k -= c;
    }
    unsigned T = prefix;
    int nStrict = 0;
#pragma unroll
    for (int j = 0; j < 32; ++j) nStrict += (u[j] > T) ? 1 : 0;
#pragma unroll
    for (int off = 32; off; off >>= 1) nStrict += __shfl_xor(nStrict, off);
    int nTies = TOPK_ - nStrict;

    int strictBase = 0, tieBase = 0;
    unsigned long long below = (lane == 0) ? 0ull : ((~0ull) >> (64 - lane));
#pragma unroll
    for (int j = 0; j < 32; ++j) {
        unsigned long long mS = __ballot(u[j] > T);
        unsigned long long mT = __ballot(u[j] == T);
        if (u[j] > T) {
            int slot = strictBase + __popcll(mS & below);
            sel[wid][slot] = j * 64 + lane;
        } else if (u[j] == T) {
            int r = tieBase + __popcll(mT & below);
            if (r < nTies) sel[wid][nStrict + r] = j * 64 + lane;
        }
        strictBase += __popcll(mS);
        tieBase += __popcll(mT);
    }
    __syncthreads();

    int idx8[8];
#pragma unroll
    for (int it = 0; it < 8; ++it) idx8[it] = sel[wid][it * 8 + (lane >> 3)];
#pragma unroll
    for (int it = 0; it < 8; ++it) {
        int m = it * 8 + (lane >> 3);
        const short* src = kb + ((size_t)b * L_ + idx8[it]) * E_ + h * HD_ + (lane & 7) * 8;
        short8 v = *reinterpret_cast<const short8*>(src);
        *reinterpret_cast<short8*>(
            selkb + (size_t)bh * 4096 + m * 64 + (((lane & 7) ^ (m & 7)) * 8)) = v;
    }
}

// ---- vtb[bh*64+d][l] = v[b,l,h*64+d] ----
__global__ __launch_bounds__(256) void k_vt(const short* __restrict__ vb,
                                            short* __restrict__ vtb) {
    __shared__ short ts[64][68];
    int blk = blockIdx.x;
    int bh = blk >> 5, l0 = (blk & 31) * 64;
    int b = bh >> 4, h = bh & 15;
    int tid = threadIdx.x;
    int l = tid >> 2, d0 = (tid & 3) * 16;
    const short* src = vb + ((size_t)(b * L_ + l0 + l)) * E_ + h * 64 + d0;
    short8 v0 = *reinterpret_cast<const short8*>(src);
    short8 v1 = *reinterpret_cast<const short8*>(src + 8);
#pragma unroll
    for (int j = 0; j < 8; ++j) ts[d0 + j][l] = v0[j];
#pragma unroll
    for (int j = 0; j < 8; ++j) ts[d0 + 8 + j][l] = v1[j];
    __syncthreads();
    int d = tid >> 2, lp = (tid & 3) * 16;
    short* dst = vtb + ((size_t)(bh * 64 + d)) * 2048 + l0 + lp;
#pragma unroll
    for (int j = 0; j < 4; ++j)
        *reinterpret_cast<short4v*>(dst + j * 4) =
            *reinterpret_cast<const short4v*>(&ts[d][lp + j * 4]);
}

// ---- attW: S_k = k.selk^T (MFMA) -> softmax -> Wpart = P2^T v (MFMA) ----
__global__ __launch_bounds__(256) void k_attW(const short* __restrict__ kb,
                                              const short* __restrict__ vtb,
                                              const short* __restrict__ selkb,
                                              float* __restrict__ wpart) {
    __shared__ short sk[4096], kt[4096], vt[4096], pt[4096];
    int wg = blockIdx.x;
    int sw = (wg & 7) * 64 + (wg >> 3);
    int bh = sw & 31, ch = sw >> 5;
    int b = bh >> 4, h = bh & 15;
    int tid = threadIdx.x, w = tid >> 6, lane = tid & 63;
    int lr = lane & 15, kg = lane >> 4;

#pragma unroll
    for (int j = 0; j < 2; ++j) {
        int off = (w * 2 + j) * 512;
        __builtin_amdgcn_global_load_lds(
            (const __attribute__((address_space(1))) void*)(selkb + (size_t)bh * 4096 + off + lane * 8),
            (__attribute__((address_space(3))) void*)(sk + off), 16, 0, 0);
    }

    f32x4 accw[4];
#pragma unroll
    for (int i = 0; i < 4; ++i) accw[i] = (f32x4){0.f, 0.f, 0.f, 0.f};

    for (int t = 0; t < 2; ++t) {
        int lt = ch * 128 + t * 64;
#pragma unroll
        for (int j = 0; j < 2; ++j) {
            int r = w * 16 + j * 8 + (lane >> 3);
            int s = lane & 7;
            const short* src = kb + ((size_t)(b * L_ + lt + r)) * E_ + h * 64 + ((s ^ (r & 7)) * 8);
            __builtin_amdgcn_global_load_lds(
                (const __attribute__((address_space(1))) void*)src,
                (__attribute__((address_space(3))) void*)(kt + (w * 16 + j * 8) * 64), 16, 0, 0);
        }
        __syncthreads();

        f32x4 s4[4];
#pragma unroll
        for (int i = 0; i < 4; ++i) s4[i] = (f32x4){0.f, 0.f, 0.f, 0.f};
#pragma unroll
        for (int kk = 0; kk < 2; ++kk) {
            int row = w * 16 + lr;
            short8 a = *reinterpret_cast<const short8*>(
                kt + row * 64 + (((kk * 4 + kg) ^ (row & 7)) * 8));
#pragma unroll
            for (int ni = 0; ni < 4; ++ni) {
                int m = ni * 16 + lr;
                short8 bb = *reinterpret_cast<const short8*>(
                    sk + m * 64 + (((kk * 4 + kg) ^ (m & 7)) * 8));
                s4[ni] = __builtin_amdgcn_mfma_f32_16x16x32_bf16(a, bb, s4[ni], 0, 0, 0);
            }
        }
        float p[4][4];
#pragma unroll
        for (int r = 0; r < 4; ++r) {
            float v0 = s4[0][r] * SCALE, v1 = s4[1][r] * SCALE;
            float v2 = s4[2][r] * SCALE, v3 = s4[3][r] * SCALE;
            float mx = fmaxf(fmaxf(v0, v1), fmaxf(v2, v3));
            mx = fmaxf(mx, __shfl_xor(mx, 1));
            mx = fmaxf(mx, __shfl_xor(mx, 2));
            mx = fmaxf(mx, __shfl_xor(mx, 4));
            mx = fmaxf(mx, __shfl_xor(mx, 8));
            float e0 = __expf(v0 - mx), e1 = __expf(v1 - mx);
            float e2 = __expf(v2 - mx), e3 = __expf(v3 - mx);
            float sm = e0 + e1 + e2 + e3;
            sm += __shfl_xor(sm, 1);
            sm += __shfl_xor(sm, 2);
            sm += __shfl_xor(sm, 4);
            sm += __shfl_xor(sm, 8);
            float inv = 1.f / sm;
            p[0][r] = e0 * inv; p[1][r] = e1 * inv; p[2][r] = e2 * inv; p[3][r] = e3 * inv;
        }
#pragma unroll
        for (int ni = 0; ni < 4; ++ni)
#pragma unroll
            for (int r = 0; r < 4; ++r) {
                int m = ni * 16 + lr;
                int ll = w * 16 + kg * 4 + r;
                pt[m * 64 + (((ll >> 3) ^ (m & 7)) * 8) + (ll & 7)] = f2bf(p[ni][r]);
            }
#pragma unroll
        for (int j = 0; j < 2; ++j) {
            int d = w * 16 + j * 8 + (lane >> 3);
            int s = lane & 7;
            const short* src = vtb + ((size_t)(bh * 64 + d)) * 2048 + lt + ((s ^ (d & 7)) * 8);
            __builtin_amdgcn_global_load_lds(
                (const __attribute__((address_space(1))) void*)src,
                (__attribute__((address_space(3))) void*)(vt + (w * 16 + j * 8) * 64), 16, 0, 0);
        }
        __syncthreads();
#pragma unroll
        for (int kk = 0; kk < 2; ++kk) {
            int mm = w * 16 + lr;
            short8 a = *reinterpret_cast<const short8*>(
                pt + mm * 64 + (((kk * 4 + kg) ^ (mm & 7)) * 8));
#pragma unroll
            for (int ni = 0; ni < 4; ++ni) {
                int d = ni * 16 + lr;
                short8 bb = *reinterpret_cast<const short8*>(
                    vt + d * 64 + (((kk * 4 + kg) ^ (d & 7)) * 8));
                accw[ni] = __builtin_amdgcn_mfma_f32_16x16x32_bf16(a, bb, accw[ni], 0, 0, 0);
            }
        }
    }
#pragma unroll
    for (int ni = 0; ni < 4; ++ni)
#pragma unroll
        for (int r = 0; r < 4; ++r) {
            int m = w * 16 + kg * 4 + r;
            int d = ni * 16 + lr;
            wpart[((size_t)(ch * 32 + bh)) * 4096 + m * 64 + d] = accw[ni][r];
        }
}

// ---- reduce wpart chunks -> Wt global bf16, transposed + pre-swizzled ----
__global__ void k_wreduce(const float* __restrict__ wpart, short* __restrict__ wtg) {
    int i = blockIdx.x * 256 + threadIdx.x;  // 131072, grid 512
    float s = 0.f;
#pragma unroll
    for (int c = 0; c < 16; ++c) s += wpart[(size_t)c * 131072 + i];
    int bh = i >> 12, m = (i >> 6) & 63, d = i & 63;
    wtg[(size_t)bh * 4096 + d * 64 + (((m >> 3) ^ (d & 7)) * 8) + (m & 7)] = f2bf(s);
}

// ---- attO: S_q = q.selk^T (MFMA) -> softmax -> att = P1.W (MFMA) -> bf16 ----
__global__ __launch_bounds__(256) void k_attO(const short* __restrict__ qb,
                                              const short* __restrict__ selkb,
                                              const short* __restrict__ wtg,
                                              short* __restrict__ att) {
    __shared__ short sk[4096], wt[4096], qt[4096], p1[4096];
    int wg = blockIdx.x;
    int sw = (wg & 7) * 64 + (wg >> 3);
    int bh = sw & 31, ch = sw >> 5;
    int b = bh >> 4, h = bh & 15;
    int tid = threadIdx.x, w = tid >> 6, lane = tid & 63;
    int lr = lane & 15, kg = lane >> 4;

#pragma unroll
    for (int j = 0; j < 2; ++j) {
        int off = (w * 2 + j) * 512;
        __builtin_amdgcn_global_load_lds(
            (const __attribute__((address_space(1))) void*)(selkb + (size_t)bh * 4096 + off + lane * 8),
            (__attribute__((address_space(3))) void*)(sk + off), 16, 0, 0);
        __builtin_amdgcn_global_load_lds(
            (const __attribute__((address_space(1))) void*)(wtg + (size_t)bh * 4096 + off + lane * 8),
            (__attribute__((address_space(3))) void*)(wt + off), 16, 0, 0);
    }

    for (int t = 0; t < 2; ++t) {
        int lt = ch * 128 + t * 64;
#pragma unroll
        for (int j = 0; j < 2; ++j) {
            int r = w * 16 + j * 8 + (lane >> 3);
            int s = lane & 7;
            const short* src = qb + ((size_t)(b * L_ + lt + r)) * E_ + h * 64 + ((s ^ (r & 7)) * 8);
            __builtin_amdgcn_global_load_lds(
                (const __attribute__((address_space(1))) void*)src,
                (__attribute__((address_space(3))) void*)(qt + (w * 16 + j * 8) * 64), 16, 0, 0);
        }
        __syncthreads();

        f32x4 s4[4];
#pragma unroll
        for (int i = 0; i < 4; ++i) s4[i] = (f32x4){0.f, 0.f, 0.f, 0.f};
#pragma unroll
        for (int kk = 0; kk < 2; ++kk) {
            int row = w * 16 + lr;
            short8 a = *reinterpret_cast<const short8*>(
                qt + row * 64 + (((kk * 4 + kg) ^ (row & 7)) * 8));
#pragma unroll
            for (int ni = 0; ni < 4; ++ni) {
                int m = ni * 16 + lr;
                short8 bb = *reinterpret_cast<const short8*>(
                    sk + m * 64 + (((kk * 4 + kg) ^ (m & 7)) * 8));
                s4[ni] = __builtin_amdgcn_mfma_f32_16x16x32_bf16(a, bb, s4[ni], 0, 0, 0);
            }
        }
        float p[4][4];
#pragma unroll
        for (int r = 0; r < 4; ++r) {
            float v0 = s4[0][r] * SCALE, v1 = s4[1][r] * SCALE;
            float v2 = s4[2][r] * SCALE, v3 = s4[3][r] * SCALE;
            float mx = fmaxf(fmaxf(v0, v1), fmaxf(v2, v3));
            mx = fmaxf(mx, __shfl_xor(mx, 1));
            mx = fmaxf(mx, __shfl_xor(mx, 2));
            mx = fmaxf(mx, __shfl_xor(mx, 4));
            mx = fmaxf(mx, __shfl_xor(mx, 8));
            float e0 = __expf(v0 - mx), e1 = __expf(v1 - mx);
            float e2 = __expf(v2 - mx), e3 = __expf(v3 - mx);
            float sm = e0 + e1 + e2 + e3;
            sm += __shfl_xor(sm, 1);
            sm += __shfl_xor(sm, 2);
            sm += __shfl_xor(sm, 4);
            sm += __shfl_xor(sm, 8);
            float inv = 1.f / sm;
            p[0][r] = e0 * inv; p[1][r] = e1 * inv; p[2][r] = e2 * inv; p[3][r] = e3 * inv;
        }
#pragma unroll
        for (int ni = 0; ni < 4; ++ni)
#pragma unroll
            for (int r = 0; r < 4; ++r) {
                int m = ni * 16 + lr;
                int ll = w * 16 + kg * 4 + r;
                p1[ll * 64 + (((m >> 3) ^ (ll & 7)) * 8) + (m & 7)] = f2bf(p[ni][r]);
            }
        __syncthreads();
        f32x4 ao[4];
#pragma unroll
        for (int i = 0; i < 4; ++i) ao[i] = (f32x4){0.f, 0.f, 0.f, 0.f};
#pragma unroll
        for (int kk = 0; kk < 2; ++kk) {
            int row = w * 16 + lr;
            short8 a = *reinterpret_cast<const short8*>(
                p1 + row * 64 + (((kk * 4 + kg) ^ (row & 7)) * 8));
#pragma unroll
            for (int ni = 0; ni < 4; ++ni) {
                int d = ni * 16 + lr;
                short8 bb = *reinterpret_cast<const short8*>(
                    wt + d * 64 + (((kk * 4 + kg) ^ (d & 7)) * 8));
                ao[ni] = __builtin_amdgcn_mfma_f32_16x16x32_bf16(a, bb, ao[ni], 0, 0, 0);
            }
        }
#pragma unroll
        for (int ni = 0; ni < 4; ++ni)
#pragma unroll
            for (int r = 0; r < 4; ++r) {
                int l = lt + w * 16 + kg * 4 + r;
                int d = ni * 16 + lr;
                att[((size_t)(b * L_ + l)) * E_ + h * 64 + d] = f2bf(ao[ni][r]);
            }
    }
}

extern "C" void kernel_launch(void* const* d_in, const int* in_sizes, int n_in,
                              void* d_out, int out_size, void* d_ws, size_t ws_size,
                              hipStream_t stream) {
    const float* query = (const float*)d_in[0];
    const float* q_w = (const float*)d_in[1];
    const float* q_b = (const float*)d_in[2];
    const float* k_w = (const float*)d_in[3];
    const float* k_b = (const float*)d_in[4];
    const float* v_w = (const float*)d_in[5];
    const float* v_b = (const float*)d_in[6];
    const float* o_w = (const float*)d_in[7];
    const float* o_b = (const float*)d_in[8];
    float* out = (float*)d_out;

    char* p = (char*)d_ws;
    auto alloc = [&](size_t bytes) {
        char* r = p;
        p += (bytes + 255) & ~(size_t)255;
        return r;
    };
    short* xb    = (short*)alloc((size_t)MROWS * E_ * 2);
    short* qwb   = (short*)alloc((size_t)E_ * E_ * 2);
    short* kwb   = (short*)alloc((size_t)E_ * E_ * 2);
    short* vwb   = (short*)alloc((size_t)E_ * E_ * 2);
    short* owb   = (short*)alloc((size_t)E_ * E_ * 2);
    short* qbuf  = (short*)alloc((size_t)MROWS * E_ * 2);
    short* kbuf  = (short*)alloc((size_t)MROWS * E_ * 2);
    short* vbuf  = (short*)alloc((size_t)MROWS * E_ * 2);
    short* vtb   = (short*)alloc((size_t)32 * 64 * 2048 * 2);
    float* xpart = (float*)alloc((size_t)16 * B_ * E_ * 4);
    float* qsum  = (float*)alloc((size_t)B_ * E_ * 4);
    float* tb    = (float*)alloc((size_t)B_ * H_ * E_ * 4);
    float* scorp = (float*)alloc((size_t)4 * B_ * H_ * L_ * 4);
    short* selkb = (short*)alloc((size_t)32 * 4096 * 2);
    short* wtg   = (short*)alloc((size_t)32 * 4096 * 2);
    float* wpart = (float*)alloc((size_t)16 * 32 * 4096 * 4);
    short* att   = (short*)alloc((size_t)MROWS * E_ * 2);

    // stage 1: merged transpose+casts+xsum partials
    k_prep<<<8320, 256, 0, stream>>>(query, q_w, k_w, v_w, o_w, xb, qwb, kwb, vwb, owb, xpart);

    // stage 2: fused q/k/v projections (single-buffer + T2 swizzle, 5 blocks/CU)
    k_gemm3<<<768, 256, 0, stream>>>(xb, qwb, kwb, vwb, q_b, k_b, v_b, qbuf, kbuf, vbuf);

    // stage 3: exact f32 scores + fused top-k + v transpose
    k_qsum<<<512, 256, 0, stream>>>(xpart, q_w, q_b, qsum);
    k_t<<<128, 256, 0, stream>>>(qsum, k_w, tb);
    k_score<<<256, 256, 0, stream>>>(query, tb, scorp);
    k_topk<<<8, 256, 0, stream>>>(scorp, kbuf, selkb);
    k_vt<<<1024, 256, 0, stream>>>(vbuf, vtb);

    // stage 4: MFMA attention core
    k_attW<<<512, 256, 0, stream>>>(kbuf, vtb, selkb, wpart);
    k_wreduce<<<512, 256, 0, stream>>>(wpart, wtg);
    k_attO<<<512, 256, 0, stream>>>(qbuf, selkb, wtg, att);

    // stage 5: o-projection fused with bias + residual + transpose back
    k_gemmo<<<512, 256, 0, stream>>>(att, owb, o_b, out, query);
}

// Round 9
// 165.471 us; speedup vs baseline: 2.7458x; 1.0493x over previous
//
#include <hip/hip_runtime.h>
#include <hip/hip_bf16.h>

#define L_ 2048
#define B_ 2
#define E_ 1024
#define H_ 16
#define HD_ 64
#define TOPK_ 64
#define MROWS (B_*L_)
#define SCALE 0.125f

typedef __attribute__((ext_vector_type(8))) short short8;
typedef __attribute__((ext_vector_type(4))) short short4v;
typedef __attribute__((ext_vector_type(4))) float f32x4;

static __device__ __forceinline__ short f2bf(float f) {
    __hip_bfloat16 h = __float2bfloat16(f);
    return *reinterpret_cast<short*>(&h);
}
static __device__ __forceinline__ float bf2f(short s) {
    unsigned u = ((unsigned)(unsigned short)s) << 16;
    return __uint_as_float(u);
}

// ---- merged: transpose x->bf16 + cast 4 weights + xsum partials (grid 8320) ----
__global__ void k_prep(const float* __restrict__ q,
                       const float* __restrict__ w0, const float* __restrict__ w1,
                       const float* __restrict__ w2, const float* __restrict__ w3,
                       short* __restrict__ xb,
                       short* __restrict__ o0, short* __restrict__ o1,
                       short* __restrict__ o2, short* __restrict__ o3,
                       float* __restrict__ xpart) {
    int blk = blockIdx.x;
    if (blk < 4096) {
        int i = blk * 256 + threadIdx.x;
        int idx = i * 4;
        int e = idx & (E_ - 1);
        int l = (idx >> 10) & (L_ - 1);
        int b = idx >> 21;
        float4 v = *reinterpret_cast<const float4*>(q + l * (B_ * E_) + b * E_ + e);
        short4v o;
        o[0] = f2bf(v.x); o[1] = f2bf(v.y); o[2] = f2bf(v.z); o[3] = f2bf(v.w);
        *reinterpret_cast<short4v*>(xb + idx) = o;
    } else if (blk < 8192) {
        int cb = blk - 4096;
        int sel = cb >> 10, lb = cb & 1023;
        const float* w = sel == 0 ? w0 : sel == 1 ? w1 : sel == 2 ? w2 : w3;
        short* o = sel == 0 ? o0 : sel == 1 ? o1 : sel == 2 ? o2 : o3;
        int i = lb * 256 + threadIdx.x;
        float4 v = *reinterpret_cast<const float4*>(w + i * 4);
        short4v s;
        s[0] = f2bf(v.x); s[1] = f2bf(v.y); s[2] = f2bf(v.z); s[3] = f2bf(v.w);
        *reinterpret_cast<short4v*>(o + i * 4) = s;
    } else {
        int cb = blk - 8192;           // 0..127
        int cg = cb & 7, ch = cb >> 3;
        int col = cg * 256 + threadIdx.x;
        float s = 0.f;
        for (int l = ch * 128; l < (ch + 1) * 128; ++l) s += q[(size_t)l * (B_ * E_) + col];
        xpart[ch * (B_ * E_) + col] = s;
    }
}

// ---- GEMM core: dbuf 2-phase (round-7 proven) + T2 swizzle, 512 threads / 8 waves
// Wave grid 2x4: wave (wr,wc) owns (BM/2)x(BN/4) output. 16 waves/CU hides drain. ----
template<int MODE, int BM, int BN>
__device__ __forceinline__ void gemm_body(const short* __restrict__ A,
                                          const short* __restrict__ Bw,
                                          const float* __restrict__ bias,
                                          short* __restrict__ Cb,
                                          float* __restrict__ Cf,
                                          const float* __restrict__ ident,
                                          int bx, int by) {
    const int K = E_;
    constexpr int MI = BM / 32;     // fragments per wave in M (BM/2/16)
    constexpr int NI = BN / 64;     // fragments per wave in N (BN/4/16)
    __shared__ short As[2][BM * 64];
    __shared__ short Bs[2][BN * 64];
    int tid = threadIdx.x;
    int lane = tid & 63;
    int wid = tid >> 6;             // 0..7
    int wr = wid >> 2, wc = wid & 3;
    int lrow = lane & 15;
    int kg = lane >> 4;
    int lr8 = lane >> 3;
    int swz = (((lane & 7) ^ (lr8 & 7)) * 8);
    int rx = lrow & 7;
    int mBase = by * BM, nBase = bx * BN;

    auto STAGE = [&](int buf, int k0) {
#pragma unroll
        for (int i = 0; i < BM / 64; ++i) {
            int r0 = (wid * (BM / 64) + i) * 8;
            const short* ga = A + (size_t)(mBase + r0 + lr8) * K + k0 + swz;
            __builtin_amdgcn_global_load_lds(
                (const __attribute__((address_space(1))) void*)ga,
                (__attribute__((address_space(3))) void*)(&As[buf][r0 * 64]), 16, 0, 0);
        }
#pragma unroll
        for (int i = 0; i < BN / 64; ++i) {
            int r0 = (wid * (BN / 64) + i) * 8;
            const short* gb = Bw + (size_t)(nBase + r0 + lr8) * K + k0 + swz;
            __builtin_amdgcn_global_load_lds(
                (const __attribute__((address_space(1))) void*)gb,
                (__attribute__((address_space(3))) void*)(&Bs[buf][r0 * 64]), 16, 0, 0);
        }
    };

    f32x4 acc[MI][NI];
#pragma unroll
    for (int i = 0; i < MI; ++i)
#pragma unroll
        for (int j = 0; j < NI; ++j) acc[i][j] = (f32x4){0.f, 0.f, 0.f, 0.f};

    STAGE(0, 0);
    asm volatile("s_waitcnt vmcnt(0)" ::: "memory");
    __syncthreads();

    int cur = 0;
    for (int k0 = 0; k0 < K; k0 += 64) {
        if (k0 + 64 < K) STAGE(cur ^ 1, k0 + 64);   // prefetch overlaps compute below

        short8 af[2][MI], bf[2][NI];
#pragma unroll
        for (int kk = 0; kk < 2; ++kk) {
#pragma unroll
            for (int mi = 0; mi < MI; ++mi)
                af[kk][mi] = *reinterpret_cast<const short8*>(
                    &As[cur][(wr * (MI * 16) + mi * 16 + lrow) * 64 + (((kk * 4 + kg) ^ rx) * 8)]);
#pragma unroll
            for (int ni = 0; ni < NI; ++ni)
                bf[kk][ni] = *reinterpret_cast<const short8*>(
                    &Bs[cur][(wc * (NI * 16) + ni * 16 + lrow) * 64 + (((kk * 4 + kg) ^ rx) * 8)]);
        }
#pragma unroll
        for (int kk = 0; kk < 2; ++kk)
#pragma unroll
            for (int mi = 0; mi < MI; ++mi)
#pragma unroll
                for (int ni = 0; ni < NI; ++ni)
                    acc[mi][ni] = __builtin_amdgcn_mfma_f32_16x16x32_bf16(
                        af[kk][mi], bf[kk][ni], acc[mi][ni], 0, 0, 0);

        asm volatile("s_waitcnt vmcnt(0)" ::: "memory");
        __syncthreads();
        cur ^= 1;
    }

    int rowq = (lane >> 4) * 4;
    int coll = lane & 15;
#pragma unroll
    for (int mi = 0; mi < MI; ++mi) {
#pragma unroll
        for (int ni = 0; ni < NI; ++ni) {
            int col = nBase + wc * (NI * 16) + ni * 16 + coll;
            float bv = bias[col];
#pragma unroll
            for (int r = 0; r < 4; ++r) {
                int row = mBase + wr * (MI * 16) + mi * 16 + rowq + r;
                float v = acc[mi][ni][r] + bv;
                if (MODE == 0) {
                    Cb[(size_t)row * E_ + col] = f2bf(v);
                } else {
                    int b = row >> 11, l = row & (L_ - 1);
                    size_t oi = (size_t)l * (B_ * E_) + b * E_ + col;
                    Cf[oi] = v + ident[oi];
                }
            }
        }
    }
}

__global__ __launch_bounds__(512) void k_gemm3(const short* __restrict__ A,
    const short* __restrict__ W0, const short* __restrict__ W1, const short* __restrict__ W2,
    const float* __restrict__ b0, const float* __restrict__ b1, const float* __restrict__ b2,
    short* __restrict__ C0, short* __restrict__ C1, short* __restrict__ C2) {
    int wg = blockIdx.x;
    int sw = (wg & 7) * 96 + (wg >> 3);
    int bx = sw & 7, by = (sw >> 3) & 31, z = sw >> 8;
    const short* Bw = z == 0 ? W0 : (z == 1 ? W1 : W2);
    const float* bias = z == 0 ? b0 : (z == 1 ? b1 : b2);
    short* C = z == 0 ? C0 : (z == 1 ? C1 : C2);
    gemm_body<0, 128, 128>(A, Bw, bias, C, nullptr, nullptr, bx, by);
}

__global__ __launch_bounds__(512) void k_gemmo(const short* __restrict__ A,
                                               const short* __restrict__ Bw,
                                               const float* __restrict__ bias,
                                               float* __restrict__ C,
                                               const float* __restrict__ ident) {
    int wg = blockIdx.x;
    int sw = (wg & 7) * 64 + (wg >> 3);
    int bx = sw & 15, by = sw >> 4;
    gemm_body<1, 128, 64>(A, Bw, bias, nullptr, C, ident, bx, by);
}

// ---- fused qsum + t: per (b,h) block computes t[b,h,:] from xpart (f32 exact) ----
__global__ __launch_bounds__(256) void k_qt(const float* __restrict__ xpart,
                                            const float* __restrict__ qw,
                                            const float* __restrict__ qb,
                                            const float* __restrict__ kw,
                                            float* __restrict__ tb) {
    __shared__ float xs[1024];
    __shared__ float pr[256];
    __shared__ float qs[64];
    int bh = blockIdx.x;              // grid 32
    int b = bh >> 4, h = bh & 15;
    int tid = threadIdx.x;
    for (int j = tid; j < 1024; j += 256) {
        float s = 0.f;
#pragma unroll
        for (int c = 0; c < 16; ++c) s += xpart[c * (B_ * E_) + b * E_ + j];
        xs[j] = s;
    }
    __syncthreads();
    int fl = tid >> 2, eq = tid & 3;
    int f = h * 64 + fl;
    float s = 0.f;
    for (int e = eq * 256; e < eq * 256 + 256; ++e) s += xs[e] * qw[(size_t)f * E_ + e];
    pr[tid] = s;
    __syncthreads();
    if (eq == 0)
        qs[fl] = ((pr[tid] + pr[tid + 1]) + pr[tid + 2]) + pr[tid + 3] + (float)L_ * qb[f];
    __syncthreads();
    float acc[4] = {0.f, 0.f, 0.f, 0.f};
    for (int d = 0; d < 64; ++d) {
        float qv = qs[d];
        float4 kv = *reinterpret_cast<const float4*>(kw + (size_t)(h * 64 + d) * E_ + tid * 4);
        acc[0] += qv * kv.x; acc[1] += qv * kv.y; acc[2] += qv * kv.z; acc[3] += qv * kv.w;
    }
    float4 o; o.x = acc[0]; o.y = acc[1]; o.z = acc[2]; o.w = acc[3];
    *reinterpret_cast<float4*>(tb + (size_t)bh * E_ + tid * 4) = o;
}

// ---- partial scores over e-quarters ----
__global__ __launch_bounds__(256) void k_score(const float* __restrict__ query,
                                               const float* __restrict__ tb,
                                               float* __restrict__ scorp) {
    __shared__ float xs[64][68];
    __shared__ float ts[16][68];
    int id = blockIdx.x;
    int eq = id >> 6;
    int b = (id >> 5) & 1;
    int n0 = (id & 31) * 64;
    int tid = threadIdx.x;
    int hg = tid & 3, rg = tid >> 2;
    float acc[4] = {0.f, 0.f, 0.f, 0.f};
    for (int e0 = eq * 256; e0 < eq * 256 + 256; e0 += 64) {
        __syncthreads();
        for (int j = tid; j < 1024; j += 256) {
            int r = j >> 4, c4 = (j & 15) * 4;
            float4 v = *reinterpret_cast<const float4*>(
                &query[(size_t)(n0 + r) * (B_ * E_) + b * E_ + e0 + c4]);
            *reinterpret_cast<float4*>(&xs[r][c4]) = v;
        }
        {
            int hh = tid >> 4, c4 = (tid & 15) * 4;
            float4 v = *reinterpret_cast<const float4*>(&tb[(size_t)(b * 16 + hh) * E_ + e0 + c4]);
            *reinterpret_cast<float4*>(&ts[hh][c4]) = v;
        }
        __syncthreads();
        for (int c = 0; c < 64; ++c) {
            float x0 = xs[rg][c];
#pragma unroll
            for (int j = 0; j < 4; ++j) acc[j] += x0 * ts[hg + 4 * j][c];
        }
    }
#pragma unroll
    for (int j = 0; j < 4; ++j) {
        int h = hg + 4 * j;
        scorp[(size_t)eq * 65536 + (size_t)(b * 16 + h) * L_ + n0 + rg] = acc[j];
    }
}

// ---- fused: top-64 select+gather (blocks 0..7)  +  v transpose (blocks 8..1031) ----
__global__ __launch_bounds__(256) void k_sel(const float* __restrict__ scorp,
                                             const short* __restrict__ kb,
                                             const short* __restrict__ vb,
                                             short* __restrict__ selkb,
                                             short* __restrict__ vtb) {
    __shared__ int sel[4][64];
    __shared__ short ts[64][68];
    int blk = blockIdx.x;
    int tid = threadIdx.x;
    if (blk < 8) {
        int wid = tid >> 6, lane = tid & 63;
        int bh = blk * 4 + wid;
        int b = bh >> 4, h = bh & 15;

        unsigned u[32];
#pragma unroll
        for (int j = 0; j < 32; ++j) {
            int base = bh * L_ + j * 64 + lane;
            float sc = ((scorp[base] + scorp[base + 65536]) + scorp[base + 131072]) + scorp[base + 196608];
            sc *= SCALE;
            unsigned bits = __float_as_uint(sc);
            u[j] = (bits & 0x80000000u) ? ~bits : (bits | 0x80000000u);
        }
        unsigned prefix = 0;
        int k = TOPK_;
        for (int bit = 31; bit >= 0; --bit) {
            unsigned cand = prefix | (1u << bit);
            int c = 0;
#pragma unroll
            for (int j = 0; j < 32; ++j) c += ((u[j] >> bit) == (cand >> bit)) ? 1 : 0;
#pragma unroll
            for (int off = 32; off; off >>= 1) c += __shfl_xor(c, off);
            if (c >= k) prefix = cand; else k -= c;
        }
        unsigned T = prefix;
        int nStrict = 0;
#pragma unroll
        for (int j = 0; j < 32; ++j) nStrict += (u[j] > T) ? 1 : 0;
#pragma unroll
        for (int off = 32; off; off >>= 1) nStrict += __shfl_xor(nStrict, off);
        int nTies = TOPK_ - nStrict;

        int strictBase = 0, tieBase = 0;
        unsigned long long below = (lane == 0) ? 0ull : ((~0ull) >> (64 - lane));
#pragma unroll
        for (int j = 0; j < 32; ++j) {
            unsigned long long mS = __ballot(u[j] > T);
            unsigned long long mT = __ballot(u[j] == T);
            if (u[j] > T) {
                int slot = strictBase + __popcll(mS & below);
                sel[wid][slot] = j * 64 + lane;
            } else if (u[j] == T) {
                int r = tieBase + __popcll(mT & below);
                if (r < nTies) sel[wid][nStrict + r] = j * 64 + lane;
            }
            strictBase += __popcll(mS);
            tieBase += __popcll(mT);
        }
        __syncthreads();

        int idx8[8];
#pragma unroll
        for (int it = 0; it < 8; ++it) idx8[it] = sel[wid][it * 8 + (lane >> 3)];
#pragma unroll
        for (int it = 0; it < 8; ++it) {
            int m = it * 8 + (lane >> 3);
            const short* src = kb + ((size_t)b * L_ + idx8[it]) * E_ + h * HD_ + (lane & 7) * 8;
            short8 v = *reinterpret_cast<const short8*>(src);
            *reinterpret_cast<short8*>(
                selkb + (size_t)bh * 4096 + m * 64 + (((lane & 7) ^ (m & 7)) * 8)) = v;
        }
    } else {
        int vblk = blk - 8;
        int bh = vblk >> 5, l0 = (vblk & 31) * 64;
        int b = bh >> 4, h = bh & 15;
        int l = tid >> 2, d0 = (tid & 3) * 16;
        const short* src = vb + ((size_t)(b * L_ + l0 + l)) * E_ + h * 64 + d0;
        short8 v0 = *reinterpret_cast<const short8*>(src);
        short8 v1 = *reinterpret_cast<const short8*>(src + 8);
#pragma unroll
        for (int j = 0; j < 8; ++j) ts[d0 + j][l] = v0[j];
#pragma unroll
        for (int j = 0; j < 8; ++j) ts[d0 + 8 + j][l] = v1[j];
        __syncthreads();
        int d = tid >> 2, lp = (tid & 3) * 16;
        short* dst = vtb + ((size_t)(bh * 64 + d)) * 2048 + l0 + lp;
#pragma unroll
        for (int j = 0; j < 4; ++j)
            *reinterpret_cast<short4v*>(dst + j * 4) =
                *reinterpret_cast<const short4v*>(&ts[d][lp + j * 4]);
    }
}

// ---- attW: S_k = k.selk^T (MFMA) -> softmax -> Wpart = P2^T v (MFMA) ----
__global__ __launch_bounds__(256) void k_attW(const short* __restrict__ kb,
                                              const short* __restrict__ vtb,
                                              const short* __restrict__ selkb,
                                              float* __restrict__ wpart) {
    __shared__ short sk[4096], kt[4096], vt[4096], pt[4096];
    int wg = blockIdx.x;
    int sw = (wg & 7) * 64 + (wg >> 3);
    int bh = sw & 31, ch = sw >> 5;
    int b = bh >> 4, h = bh & 15;
    int tid = threadIdx.x, w = tid >> 6, lane = tid & 63;
    int lr = lane & 15, kg = lane >> 4;

#pragma unroll
    for (int j = 0; j < 2; ++j) {
        int off = (w * 2 + j) * 512;
        __builtin_amdgcn_global_load_lds(
            (const __attribute__((address_space(1))) void*)(selkb + (size_t)bh * 4096 + off + lane * 8),
            (__attribute__((address_space(3))) void*)(sk + off), 16, 0, 0);
    }

    f32x4 accw[4];
#pragma unroll
    for (int i = 0; i < 4; ++i) accw[i] = (f32x4){0.f, 0.f, 0.f, 0.f};

    for (int t = 0; t < 2; ++t) {
        int lt = ch * 128 + t * 64;
#pragma unroll
        for (int j = 0; j < 2; ++j) {
            int r = w * 16 + j * 8 + (lane >> 3);
            int s = lane & 7;
            const short* src = kb + ((size_t)(b * L_ + lt + r)) * E_ + h * 64 + ((s ^ (r & 7)) * 8);
            __builtin_amdgcn_global_load_lds(
                (const __attribute__((address_space(1))) void*)src,
                (__attribute__((address_space(3))) void*)(kt + (w * 16 + j * 8) * 64), 16, 0, 0);
        }
        __syncthreads();

        f32x4 s4[4];
#pragma unroll
        for (int i = 0; i < 4; ++i) s4[i] = (f32x4){0.f, 0.f, 0.f, 0.f};
#pragma unroll
        for (int kk = 0; kk < 2; ++kk) {
            int row = w * 16 + lr;
            short8 a = *reinterpret_cast<const short8*>(
                kt + row * 64 + (((kk * 4 + kg) ^ (row & 7)) * 8));
#pragma unroll
            for (int ni = 0; ni < 4; ++ni) {
                int m = ni * 16 + lr;
                short8 bb = *reinterpret_cast<const short8*>(
                    sk + m * 64 + (((kk * 4 + kg) ^ (m & 7)) * 8));
                s4[ni] = __builtin_amdgcn_mfma_f32_16x16x32_bf16(a, bb, s4[ni], 0, 0, 0);
            }
        }
        float p[4][4];
#pragma unroll
        for (int r = 0; r < 4; ++r) {
            float v0 = s4[0][r] * SCALE, v1 = s4[1][r] * SCALE;
            float v2 = s4[2][r] * SCALE, v3 = s4[3][r] * SCALE;
            float mx = fmaxf(fmaxf(v0, v1), fmaxf(v2, v3));
            mx = fmaxf(mx, __shfl_xor(mx, 1));
            mx = fmaxf(mx, __shfl_xor(mx, 2));
            mx = fmaxf(mx, __shfl_xor(mx, 4));
            mx = fmaxf(mx, __shfl_xor(mx, 8));
            float e0 = __expf(v0 - mx), e1 = __expf(v1 - mx);
            float e2 = __expf(v2 - mx), e3 = __expf(v3 - mx);
            float sm = e0 + e1 + e2 + e3;
            sm += __shfl_xor(sm, 1);
            sm += __shfl_xor(sm, 2);
            sm += __shfl_xor(sm, 4);
            sm += __shfl_xor(sm, 8);
            float inv = 1.f / sm;
            p[0][r] = e0 * inv; p[1][r] = e1 * inv; p[2][r] = e2 * inv; p[3][r] = e3 * inv;
        }
#pragma unroll
        for (int ni = 0; ni < 4; ++ni)
#pragma unroll
            for (int r = 0; r < 4; ++r) {
                int m = ni * 16 + lr;
                int ll = w * 16 + kg * 4 + r;
                pt[m * 64 + (((ll >> 3) ^ (m & 7)) * 8) + (ll & 7)] = f2bf(p[ni][r]);
            }
#pragma unroll
        for (int j = 0; j < 2; ++j) {
            int d = w * 16 + j * 8 + (lane >> 3);
            int s = lane & 7;
            const short* src = vtb + ((size_t)(bh * 64 + d)) * 2048 + lt + ((s ^ (d & 7)) * 8);
            __builtin_amdgcn_global_load_lds(
                (const __attribute__((address_space(1))) void*)src,
                (__attribute__((address_space(3))) void*)(vt + (w * 16 + j * 8) * 64), 16, 0, 0);
        }
        __syncthreads();
#pragma unroll
        for (int kk = 0; kk < 2; ++kk) {
            int mm = w * 16 + lr;
            short8 a = *reinterpret_cast<const short8*>(
                pt + mm * 64 + (((kk * 4 + kg) ^ (mm & 7)) * 8));
#pragma unroll
            for (int ni = 0; ni < 4; ++ni) {
                int d = ni * 16 + lr;
                short8 bb = *reinterpret_cast<const short8*>(
                    vt + d * 64 + (((kk * 4 + kg) ^ (d & 7)) * 8));
                accw[ni] = __builtin_amdgcn_mfma_f32_16x16x32_bf16(a, bb, accw[ni], 0, 0, 0);
            }
        }
    }
#pragma unroll
    for (int ni = 0; ni < 4; ++ni)
#pragma unroll
        for (int r = 0; r < 4; ++r) {
            int m = w * 16 + kg * 4 + r;
            int d = ni * 16 + lr;
            wpart[((size_t)(ch * 32 + bh)) * 4096 + m * 64 + d] = accw[ni][r];
        }
}

// ---- reduce wpart chunks -> Wt global bf16, transposed + pre-swizzled ----
__global__ void k_wreduce(const float* __restrict__ wpart, short* __restrict__ wtg) {
    int i = blockIdx.x * 256 + threadIdx.x;  // 131072, grid 512
    float s = 0.f;
#pragma unroll
    for (int c = 0; c < 16; ++c) s += wpart[(size_t)c * 131072 + i];
    int bh = i >> 12, m = (i >> 6) & 63, d = i & 63;
    wtg[(size_t)bh * 4096 + d * 64 + (((m >> 3) ^ (d & 7)) * 8) + (m & 7)] = f2bf(s);
}

// ---- attO: S_q = q.selk^T (MFMA) -> softmax -> att = P1.W (MFMA) -> bf16 ----
__global__ __launch_bounds__(256) void k_attO(const short* __restrict__ qb,
                                              const short* __restrict__ selkb,
                                              const short* __restrict__ wtg,
                                              short* __restrict__ att) {
    __shared__ short sk[4096], wt[4096], qt[4096], p1[4096];
    int wg = blockIdx.x;
    int sw = (wg & 7) * 64 + (wg >> 3);
    int bh = sw & 31, ch = sw >> 5;
    int b = bh >> 4, h = bh & 15;
    int tid = threadIdx.x, w = tid >> 6, lane = tid & 63;
    int lr = lane & 15, kg = lane >> 4;

#pragma unroll
    for (int j = 0; j < 2; ++j) {
        int off = (w * 2 + j) * 512;
        __builtin_amdgcn_global_load_lds(
            (const __attribute__((address_space(1))) void*)(selkb + (size_t)bh * 4096 + off + lane * 8),
            (__attribute__((address_space(3))) void*)(sk + off), 16, 0, 0);
        __builtin_amdgcn_global_load_lds(
            (const __attribute__((address_space(1))) void*)(wtg + (size_t)bh * 4096 + off + lane * 8),
            (__attribute__((address_space(3))) void*)(wt + off), 16, 0, 0);
    }

    for (int t = 0; t < 2; ++t) {
        int lt = ch * 128 + t * 64;
#pragma unroll
        for (int j = 0; j < 2; ++j) {
            int r = w * 16 + j * 8 + (lane >> 3);
            int s = lane & 7;
            const short* src = qb + ((size_t)(b * L_ + lt + r)) * E_ + h * 64 + ((s ^ (r & 7)) * 8);
            __builtin_amdgcn_global_load_lds(
                (const __attribute__((address_space(1))) void*)src,
                (__attribute__((address_space(3))) void*)(qt + (w * 16 + j * 8) * 64), 16, 0, 0);
        }
        __syncthreads();

        f32x4 s4[4];
#pragma unroll
        for (int i = 0; i < 4; ++i) s4[i] = (f32x4){0.f, 0.f, 0.f, 0.f};
#pragma unroll
        for (int kk = 0; kk < 2; ++kk) {
            int row = w * 16 + lr;
            short8 a = *reinterpret_cast<const short8*>(
                qt + row * 64 + (((kk * 4 + kg) ^ (row & 7)) * 8));
#pragma unroll
            for (int ni = 0; ni < 4; ++ni) {
                int m = ni * 16 + lr;
                short8 bb = *reinterpret_cast<const short8*>(
                    sk + m * 64 + (((kk * 4 + kg) ^ (m & 7)) * 8));
                s4[ni] = __builtin_amdgcn_mfma_f32_16x16x32_bf16(a, bb, s4[ni], 0, 0, 0);
            }
        }
        float p[4][4];
#pragma unroll
        for (int r = 0; r < 4; ++r) {
            float v0 = s4[0][r] * SCALE, v1 = s4[1][r] * SCALE;
            float v2 = s4[2][r] * SCALE, v3 = s4[3][r] * SCALE;
            float mx = fmaxf(fmaxf(v0, v1), fmaxf(v2, v3));
            mx = fmaxf(mx, __shfl_xor(mx, 1));
            mx = fmaxf(mx, __shfl_xor(mx, 2));
            mx = fmaxf(mx, __shfl_xor(mx, 4));
            mx = fmaxf(mx, __shfl_xor(mx, 8));
            float e0 = __expf(v0 - mx), e1 = __expf(v1 - mx);
            float e2 = __expf(v2 - mx), e3 = __expf(v3 - mx);
            float sm = e0 + e1 + e2 + e3;
            sm += __shfl_xor(sm, 1);
            sm += __shfl_xor(sm, 2);
            sm += __shfl_xor(sm, 4);
            sm += __shfl_xor(sm, 8);
            float inv = 1.f / sm;
            p[0][r] = e0 * inv; p[1][r] = e1 * inv; p[2][r] = e2 * inv; p[3][r] = e3 * inv;
        }
#pragma unroll
        for (int ni = 0; ni < 4; ++ni)
#pragma unroll
            for (int r = 0; r < 4; ++r) {
                int m = ni * 16 + lr;
                int ll = w * 16 + kg * 4 + r;
                p1[ll * 64 + (((m >> 3) ^ (ll & 7)) * 8) + (m & 7)] = f2bf(p[ni][r]);
            }
        __syncthreads();
        f32x4 ao[4];
#pragma unroll
        for (int i = 0; i < 4; ++i) ao[i] = (f32x4){0.f, 0.f, 0.f, 0.f};
#pragma unroll
        for (int kk = 0; kk < 2; ++kk) {
            int row = w * 16 + lr;
            short8 a = *reinterpret_cast<const short8*>(
                p1 + row * 64 + (((kk * 4 + kg) ^ (row & 7)) * 8));
#pragma unroll
            for (int ni = 0; ni < 4; ++ni) {
                int d = ni * 16 + lr;
                short8 bb = *reinterpret_cast<const short8*>(
                    wt + d * 64 + (((kk * 4 + kg) ^ (d & 7)) * 8));
                ao[ni] = __builtin_amdgcn_mfma_f32_16x16x32_bf16(a, bb, ao[ni], 0, 0, 0);
            }
        }
#pragma unroll
        for (int ni = 0; ni < 4; ++ni)
#pragma unroll
            for (int r = 0; r < 4; ++r) {
                int l = lt + w * 16 + kg * 4 + r;
                int d = ni * 16 + lr;
                att[((size_t)(b * L_ + l)) * E_ + h * 64 + d] = f2bf(ao[ni][r]);
            }
    }
}

extern "C" void kernel_launch(void* const* d_in, const int* in_sizes, int n_in,
                              void* d_out, int out_size, void* d_ws, size_t ws_size,
                              hipStream_t stream) {
    const float* query = (const float*)d_in[0];
    const float* q_w = (const float*)d_in[1];
    const float* q_b = (const float*)d_in[2];
    const float* k_w = (const float*)d_in[3];
    const float* k_b = (const float*)d_in[4];
    const float* v_w = (const float*)d_in[5];
    const float* v_b = (const float*)d_in[6];
    const float* o_w = (const float*)d_in[7];
    const float* o_b = (const float*)d_in[8];
    float* out = (float*)d_out;

    char* p = (char*)d_ws;
    auto alloc = [&](size_t bytes) {
        char* r = p;
        p += (bytes + 255) & ~(size_t)255;
        return r;
    };
    short* xb    = (short*)alloc((size_t)MROWS * E_ * 2);
    short* qwb   = (short*)alloc((size_t)E_ * E_ * 2);
    short* kwb   = (short*)alloc((size_t)E_ * E_ * 2);
    short* vwb   = (short*)alloc((size_t)E_ * E_ * 2);
    short* owb   = (short*)alloc((size_t)E_ * E_ * 2);
    short* qbuf  = (short*)alloc((size_t)MROWS * E_ * 2);
    short* kbuf  = (short*)alloc((size_t)MROWS * E_ * 2);
    short* vbuf  = (short*)alloc((size_t)MROWS * E_ * 2);
    short* vtb   = (short*)alloc((size_t)32 * 64 * 2048 * 2);
    float* xpart = (float*)alloc((size_t)16 * B_ * E_ * 4);
    float* tb    = (float*)alloc((size_t)B_ * H_ * E_ * 4);
    float* scorp = (float*)alloc((size_t)4 * B_ * H_ * L_ * 4);
    short* selkb = (short*)alloc((size_t)32 * 4096 * 2);
    short* wtg   = (short*)alloc((size_t)32 * 4096 * 2);
    float* wpart = (float*)alloc((size_t)16 * 32 * 4096 * 4);
    short* att   = (short*)alloc((size_t)MROWS * E_ * 2);

    // stage 1: merged transpose+casts+xsum partials; score path (independent of GEMMs)
    k_prep<<<8320, 256, 0, stream>>>(query, q_w, k_w, v_w, o_w, xb, qwb, kwb, vwb, owb, xpart);
    k_qt<<<32, 256, 0, stream>>>(xpart, q_w, q_b, k_w, tb);
    k_score<<<256, 256, 0, stream>>>(query, tb, scorp);

    // stage 2: fused q/k/v projections (dbuf 2-phase, 8 waves/block)
    k_gemm3<<<768, 512, 0, stream>>>(xb, qwb, kwb, vwb, q_b, k_b, v_b, qbuf, kbuf, vbuf);

    // stage 3: fused top-k gather + v transpose
    k_sel<<<1032, 256, 0, stream>>>(scorp, kbuf, vbuf, selkb, vtb);

    // stage 4: MFMA attention core
    k_attW<<<512, 256, 0, stream>>>(kbuf, vtb, selkb, wpart);
    k_wreduce<<<512, 256, 0, stream>>>(wpart, wtg);
    k_attO<<<512, 256, 0, stream>>>(qbuf, selkb, wtg, att);

    // stage 5: o-projection fused with bias + residual + transpose back
    k_gemmo<<<512, 512, 0, stream>>>(att, owb, o_b, out, query);
}

// Round 10
// 139.730 us; speedup vs baseline: 3.2516x; 1.1842x over previous
//
#include <hip/hip_runtime.h>
#include <hip/hip_bf16.h>

#define L_ 2048
#define B_ 2
#define E_ 1024
#define H_ 16
#define HD_ 64
#define TOPK_ 64
#define MROWS (B_*L_)
#define SCALE 0.125f

typedef __attribute__((ext_vector_type(8))) short short8;
typedef __attribute__((ext_vector_type(4))) short short4v;
typedef __attribute__((ext_vector_type(4))) float f32x4;

static __device__ __forceinline__ short f2bf(float f) {
    __hip_bfloat16 h = __float2bfloat16(f);
    return *reinterpret_cast<short*>(&h);
}
static __device__ __forceinline__ float bf2f(short s) {
    unsigned u = ((unsigned)(unsigned short)s) << 16;
    return __uint_as_float(u);
}

// ---- merged: xsum partials FIRST (512 blks, 4-acc unrolled) + transpose + casts ----
__global__ void k_prep(const float* __restrict__ q,
                       const float* __restrict__ w0, const float* __restrict__ w1,
                       const float* __restrict__ w2, const float* __restrict__ w3,
                       short* __restrict__ xb,
                       short* __restrict__ o0, short* __restrict__ o1,
                       short* __restrict__ o2, short* __restrict__ o3,
                       float* __restrict__ xpart) {
    int blk = blockIdx.x;
    if (blk < 512) {
        // xsum: chunk ch (32 rows) x col-group cg; 4 independent accumulators
        int cg = blk & 7, ch = blk >> 3;   // ch 0..63
        int col = cg * 256 + threadIdx.x;
        const float* qp = q + (size_t)(ch * 32) * (B_ * E_) + col;
        float s0 = 0.f, s1 = 0.f, s2 = 0.f, s3 = 0.f;
#pragma unroll
        for (int l = 0; l < 32; l += 4) {
            s0 += qp[(size_t)(l + 0) * (B_ * E_)];
            s1 += qp[(size_t)(l + 1) * (B_ * E_)];
            s2 += qp[(size_t)(l + 2) * (B_ * E_)];
            s3 += qp[(size_t)(l + 3) * (B_ * E_)];
        }
        xpart[ch * (B_ * E_) + col] = (s0 + s1) + (s2 + s3);
    } else if (blk < 4608) {
        int i = (blk - 512) * 256 + threadIdx.x;
        int idx = i * 4;
        int e = idx & (E_ - 1);
        int l = (idx >> 10) & (L_ - 1);
        int b = idx >> 21;
        float4 v = *reinterpret_cast<const float4*>(q + l * (B_ * E_) + b * E_ + e);
        short4v o;
        o[0] = f2bf(v.x); o[1] = f2bf(v.y); o[2] = f2bf(v.z); o[3] = f2bf(v.w);
        *reinterpret_cast<short4v*>(xb + idx) = o;
    } else {
        int cb = blk - 4608;
        int sel = cb >> 10, lb = cb & 1023;
        const float* w = sel == 0 ? w0 : sel == 1 ? w1 : sel == 2 ? w2 : w3;
        short* o = sel == 0 ? o0 : sel == 1 ? o1 : sel == 2 ? o2 : o3;
        int i = lb * 256 + threadIdx.x;
        float4 v = *reinterpret_cast<const float4*>(w + i * 4);
        short4v s;
        s[0] = f2bf(v.x); s[1] = f2bf(v.y); s[2] = f2bf(v.z); s[3] = f2bf(v.w);
        *reinterpret_cast<short4v*>(o + i * 4) = s;
    }
}

// ---- GEMM core: dbuf 2-phase + T2 swizzle, 512 threads / 8 waves (round-9 proven) ----
template<int MODE, int BM, int BN>
__device__ __forceinline__ void gemm_body(const short* __restrict__ A,
                                          const short* __restrict__ Bw,
                                          const float* __restrict__ bias,
                                          short* __restrict__ Cb,
                                          float* __restrict__ Cf,
                                          const float* __restrict__ ident,
                                          int bx, int by) {
    const int K = E_;
    constexpr int MI = BM / 32;
    constexpr int NI = BN / 64;
    __shared__ short As[2][BM * 64];
    __shared__ short Bs[2][BN * 64];
    int tid = threadIdx.x;
    int lane = tid & 63;
    int wid = tid >> 6;
    int wr = wid >> 2, wc = wid & 3;
    int lrow = lane & 15;
    int kg = lane >> 4;
    int lr8 = lane >> 3;
    int swz = (((lane & 7) ^ (lr8 & 7)) * 8);
    int rx = lrow & 7;
    int mBase = by * BM, nBase = bx * BN;

    auto STAGE = [&](int buf, int k0) {
#pragma unroll
        for (int i = 0; i < BM / 64; ++i) {
            int r0 = (wid * (BM / 64) + i) * 8;
            const short* ga = A + (size_t)(mBase + r0 + lr8) * K + k0 + swz;
            __builtin_amdgcn_global_load_lds(
                (const __attribute__((address_space(1))) void*)ga,
                (__attribute__((address_space(3))) void*)(&As[buf][r0 * 64]), 16, 0, 0);
        }
#pragma unroll
        for (int i = 0; i < BN / 64; ++i) {
            int r0 = (wid * (BN / 64) + i) * 8;
            const short* gb = Bw + (size_t)(nBase + r0 + lr8) * K + k0 + swz;
            __builtin_amdgcn_global_load_lds(
                (const __attribute__((address_space(1))) void*)gb,
                (__attribute__((address_space(3))) void*)(&Bs[buf][r0 * 64]), 16, 0, 0);
        }
    };

    f32x4 acc[MI][NI];
#pragma unroll
    for (int i = 0; i < MI; ++i)
#pragma unroll
        for (int j = 0; j < NI; ++j) acc[i][j] = (f32x4){0.f, 0.f, 0.f, 0.f};

    STAGE(0, 0);
    asm volatile("s_waitcnt vmcnt(0)" ::: "memory");
    __syncthreads();

    int cur = 0;
    for (int k0 = 0; k0 < K; k0 += 64) {
        if (k0 + 64 < K) STAGE(cur ^ 1, k0 + 64);

        short8 af[2][MI], bf[2][NI];
#pragma unroll
        for (int kk = 0; kk < 2; ++kk) {
#pragma unroll
            for (int mi = 0; mi < MI; ++mi)
                af[kk][mi] = *reinterpret_cast<const short8*>(
                    &As[cur][(wr * (MI * 16) + mi * 16 + lrow) * 64 + (((kk * 4 + kg) ^ rx) * 8)]);
#pragma unroll
            for (int ni = 0; ni < NI; ++ni)
                bf[kk][ni] = *reinterpret_cast<const short8*>(
                    &Bs[cur][(wc * (NI * 16) + ni * 16 + lrow) * 64 + (((kk * 4 + kg) ^ rx) * 8)]);
        }
#pragma unroll
        for (int kk = 0; kk < 2; ++kk)
#pragma unroll
            for (int mi = 0; mi < MI; ++mi)
#pragma unroll
                for (int ni = 0; ni < NI; ++ni)
                    acc[mi][ni] = __builtin_amdgcn_mfma_f32_16x16x32_bf16(
                        af[kk][mi], bf[kk][ni], acc[mi][ni], 0, 0, 0);

        asm volatile("s_waitcnt vmcnt(0)" ::: "memory");
        __syncthreads();
        cur ^= 1;
    }

    int rowq = (lane >> 4) * 4;
    int coll = lane & 15;
#pragma unroll
    for (int mi = 0; mi < MI; ++mi) {
#pragma unroll
        for (int ni = 0; ni < NI; ++ni) {
            int col = nBase + wc * (NI * 16) + ni * 16 + coll;
            float bv = bias[col];
#pragma unroll
            for (int r = 0; r < 4; ++r) {
                int row = mBase + wr * (MI * 16) + mi * 16 + rowq + r;
                float v = acc[mi][ni][r] + bv;
                if (MODE == 0) {
                    Cb[(size_t)row * E_ + col] = f2bf(v);
                } else {
                    int b = row >> 11, l = row & (L_ - 1);
                    size_t oi = (size_t)l * (B_ * E_) + b * E_ + col;
                    Cf[oi] = v + ident[oi];
                }
            }
        }
    }
}

__global__ __launch_bounds__(512) void k_gemm3(const short* __restrict__ A,
    const short* __restrict__ W0, const short* __restrict__ W1, const short* __restrict__ W2,
    const float* __restrict__ b0, const float* __restrict__ b1, const float* __restrict__ b2,
    short* __restrict__ C0, short* __restrict__ C1, short* __restrict__ C2) {
    int wg = blockIdx.x;
    int sw = (wg & 7) * 96 + (wg >> 3);
    int bx = sw & 7, by = (sw >> 3) & 31, z = sw >> 8;
    const short* Bw = z == 0 ? W0 : (z == 1 ? W1 : W2);
    const float* bias = z == 0 ? b0 : (z == 1 ? b1 : b2);
    short* C = z == 0 ? C0 : (z == 1 ? C1 : C2);
    gemm_body<0, 128, 128>(A, Bw, bias, C, nullptr, nullptr, bx, by);
}

__global__ __launch_bounds__(512) void k_gemmo(const short* __restrict__ A,
                                               const short* __restrict__ Bw,
                                               const float* __restrict__ bias,
                                               float* __restrict__ C,
                                               const float* __restrict__ ident) {
    int wg = blockIdx.x;
    int sw = (wg & 7) * 64 + (wg >> 3);
    int bx = sw & 15, by = sw >> 4;
    gemm_body<1, 128, 64>(A, Bw, bias, nullptr, C, ident, bx, by);
}

// ---- fused qsum + t: per (b,h) block computes t[b,h,:] from xpart (f32 exact) ----
__global__ __launch_bounds__(256) void k_qt(const float* __restrict__ xpart,
                                            const float* __restrict__ qw,
                                            const float* __restrict__ qb,
                                            const float* __restrict__ kw,
                                            float* __restrict__ tb) {
    __shared__ float xs[1024];
    __shared__ float pr[256];
    __shared__ float qs[64];
    int bh = blockIdx.x;              // grid 32
    int b = bh >> 4, h = bh & 15;
    int tid = threadIdx.x;
    for (int j = tid; j < 1024; j += 256) {
        float s = 0.f;
#pragma unroll
        for (int c = 0; c < 64; ++c) s += xpart[c * (B_ * E_) + b * E_ + j];
        xs[j] = s;
    }
    __syncthreads();
    int fl = tid >> 2, eq = tid & 3;
    int f = h * 64 + fl;
    float s = 0.f;
    for (int e = eq * 256; e < eq * 256 + 256; ++e) s += xs[e] * qw[(size_t)f * E_ + e];
    pr[tid] = s;
    __syncthreads();
    if (eq == 0)
        qs[fl] = ((pr[tid] + pr[tid + 1]) + pr[tid + 2]) + pr[tid + 3] + (float)L_ * qb[f];
    __syncthreads();
    float acc[4] = {0.f, 0.f, 0.f, 0.f};
    for (int d = 0; d < 64; ++d) {
        float qv = qs[d];
        float4 kv = *reinterpret_cast<const float4*>(kw + (size_t)(h * 64 + d) * E_ + tid * 4);
        acc[0] += qv * kv.x; acc[1] += qv * kv.y; acc[2] += qv * kv.z; acc[3] += qv * kv.w;
    }
    float4 o; o.x = acc[0]; o.y = acc[1]; o.z = acc[2]; o.w = acc[3];
    *reinterpret_cast<float4*>(tb + (size_t)bh * E_ + tid * 4) = o;
}

// ---- partial scores over e-quarters ----
__global__ __launch_bounds__(256) void k_score(const float* __restrict__ query,
                                               const float* __restrict__ tb,
                                               float* __restrict__ scorp) {
    __shared__ float xs[64][68];
    __shared__ float ts[16][68];
    int id = blockIdx.x;
    int eq = id >> 6;
    int b = (id >> 5) & 1;
    int n0 = (id & 31) * 64;
    int tid = threadIdx.x;
    int hg = tid & 3, rg = tid >> 2;
    float acc[4] = {0.f, 0.f, 0.f, 0.f};
    for (int e0 = eq * 256; e0 < eq * 256 + 256; e0 += 64) {
        __syncthreads();
        for (int j = tid; j < 1024; j += 256) {
            int r = j >> 4, c4 = (j & 15) * 4;
            float4 v = *reinterpret_cast<const float4*>(
                &query[(size_t)(n0 + r) * (B_ * E_) + b * E_ + e0 + c4]);
            *reinterpret_cast<float4*>(&xs[r][c4]) = v;
        }
        {
            int hh = tid >> 4, c4 = (tid & 15) * 4;
            float4 v = *reinterpret_cast<const float4*>(&tb[(size_t)(b * 16 + hh) * E_ + e0 + c4]);
            *reinterpret_cast<float4*>(&ts[hh][c4]) = v;
        }
        __syncthreads();
        for (int c = 0; c < 64; ++c) {
            float x0 = xs[rg][c];
#pragma unroll
            for (int j = 0; j < 4; ++j) acc[j] += x0 * ts[hg + 4 * j][c];
        }
    }
#pragma unroll
    for (int j = 0; j < 4; ++j) {
        int h = hg + 4 * j;
        scorp[(size_t)eq * 65536 + (size_t)(b * 16 + h) * L_ + n0 + rg] = acc[j];
    }
}

// ---- fused: top-64 select+gather (blocks 0..7)  +  v transpose (blocks 8..1031) ----
__global__ __launch_bounds__(256) void k_sel(const float* __restrict__ scorp,
                                             const short* __restrict__ kb,
                                             const short* __restrict__ vb,
                                             short* __restrict__ selkb,
                                             short* __restrict__ vtb) {
    __shared__ int sel[4][64];
    __shared__ short ts[64][68];
    int blk = blockIdx.x;
    int tid = threadIdx.x;
    if (blk < 8) {
        int wid = tid >> 6, lane = tid & 63;
        int bh = blk * 4 + wid;
        int b = bh >> 4, h = bh & 15;

        unsigned u[32];
#pragma unroll
        for (int j = 0; j < 32; ++j) {
            int base = bh * L_ + j * 64 + lane;
            float sc = ((scorp[base] + scorp[base + 65536]) + scorp[base + 131072]) + scorp[base + 196608];
            sc *= SCALE;
            unsigned bits = __float_as_uint(sc);
            u[j] = (bits & 0x80000000u) ? ~bits : (bits | 0x80000000u);
        }
        unsigned prefix = 0;
        int k = TOPK_;
        for (int bit = 31; bit >= 0; --bit) {
            unsigned cand = prefix | (1u << bit);
            int c = 0;
#pragma unroll
            for (int j = 0; j < 32; ++j) c += ((u[j] >> bit) == (cand >> bit)) ? 1 : 0;
#pragma unroll
            for (int off = 32; off; off >>= 1) c += __shfl_xor(c, off);
            if (c >= k) prefix = cand; else k -= c;
        }
        unsigned T = prefix;
        int nStrict = 0;
#pragma unroll
        for (int j = 0; j < 32; ++j) nStrict += (u[j] > T) ? 1 : 0;
#pragma unroll
        for (int off = 32; off; off >>= 1) nStrict += __shfl_xor(nStrict, off);
        int nTies = TOPK_ - nStrict;

        int strictBase = 0, tieBase = 0;
        unsigned long long below = (lane == 0) ? 0ull : ((~0ull) >> (64 - lane));
#pragma unroll
        for (int j = 0; j < 32; ++j) {
            unsigned long long mS = __ballot(u[j] > T);
            unsigned long long mT = __ballot(u[j] == T);
            if (u[j] > T) {
                int slot = strictBase + __popcll(mS & below);
                sel[wid][slot] = j * 64 + lane;
            } else if (u[j] == T) {
                int r = tieBase + __popcll(mT & below);
                if (r < nTies) sel[wid][nStrict + r] = j * 64 + lane;
            }
            strictBase += __popcll(mS);
            tieBase += __popcll(mT);
        }
        __syncthreads();

        int idx8[8];
#pragma unroll
        for (int it = 0; it < 8; ++it) idx8[it] = sel[wid][it * 8 + (lane >> 3)];
#pragma unroll
        for (int it = 0; it < 8; ++it) {
            int m = it * 8 + (lane >> 3);
            const short* src = kb + ((size_t)b * L_ + idx8[it]) * E_ + h * HD_ + (lane & 7) * 8;
            short8 v = *reinterpret_cast<const short8*>(src);
            *reinterpret_cast<short8*>(
                selkb + (size_t)bh * 4096 + m * 64 + (((lane & 7) ^ (m & 7)) * 8)) = v;
        }
    } else {
        int vblk = blk - 8;
        int bh = vblk >> 5, l0 = (vblk & 31) * 64;
        int b = bh >> 4, h = bh & 15;
        int l = tid >> 2, d0 = (tid & 3) * 16;
        const short* src = vb + ((size_t)(b * L_ + l0 + l)) * E_ + h * 64 + d0;
        short8 v0 = *reinterpret_cast<const short8*>(src);
        short8 v1 = *reinterpret_cast<const short8*>(src + 8);
#pragma unroll
        for (int j = 0; j < 8; ++j) ts[d0 + j][l] = v0[j];
#pragma unroll
        for (int j = 0; j < 8; ++j) ts[d0 + 8 + j][l] = v1[j];
        __syncthreads();
        int d = tid >> 2, lp = (tid & 3) * 16;
        short* dst = vtb + ((size_t)(bh * 64 + d)) * 2048 + l0 + lp;
#pragma unroll
        for (int j = 0; j < 4; ++j)
            *reinterpret_cast<short4v*>(dst + j * 4) =
                *reinterpret_cast<const short4v*>(&ts[d][lp + j * 4]);
    }
}

// ---- attW: S_k = k.selk^T (MFMA) -> softmax -> Wpart = P2^T v (MFMA) ----
__global__ __launch_bounds__(256) void k_attW(const short* __restrict__ kb,
                                              const short* __restrict__ vtb,
                                              const short* __restrict__ selkb,
                                              float* __restrict__ wpart) {
    __shared__ short sk[4096], kt[4096], vt[4096], pt[4096];
    int wg = blockIdx.x;
    int sw = (wg & 7) * 64 + (wg >> 3);
    int bh = sw & 31, ch = sw >> 5;
    int b = bh >> 4, h = bh & 15;
    int tid = threadIdx.x, w = tid >> 6, lane = tid & 63;
    int lr = lane & 15, kg = lane >> 4;

#pragma unroll
    for (int j = 0; j < 2; ++j) {
        int off = (w * 2 + j) * 512;
        __builtin_amdgcn_global_load_lds(
            (const __attribute__((address_space(1))) void*)(selkb + (size_t)bh * 4096 + off + lane * 8),
            (__attribute__((address_space(3))) void*)(sk + off), 16, 0, 0);
    }

    f32x4 accw[4];
#pragma unroll
    for (int i = 0; i < 4; ++i) accw[i] = (f32x4){0.f, 0.f, 0.f, 0.f};

    for (int t = 0; t < 2; ++t) {
        int lt = ch * 128 + t * 64;
#pragma unroll
        for (int j = 0; j < 2; ++j) {
            int r = w * 16 + j * 8 + (lane >> 3);
            int s = lane & 7;
            const short* src = kb + ((size_t)(b * L_ + lt + r)) * E_ + h * 64 + ((s ^ (r & 7)) * 8);
            __builtin_amdgcn_global_load_lds(
                (const __attribute__((address_space(1))) void*)src,
                (__attribute__((address_space(3))) void*)(kt + (w * 16 + j * 8) * 64), 16, 0, 0);
        }
        __syncthreads();

        f32x4 s4[4];
#pragma unroll
        for (int i = 0; i < 4; ++i) s4[i] = (f32x4){0.f, 0.f, 0.f, 0.f};
#pragma unroll
        for (int kk = 0; kk < 2; ++kk) {
            int row = w * 16 + lr;
            short8 a = *reinterpret_cast<const short8*>(
                kt + row * 64 + (((kk * 4 + kg) ^ (row & 7)) * 8));
#pragma unroll
            for (int ni = 0; ni < 4; ++ni) {
                int m = ni * 16 + lr;
                short8 bb = *reinterpret_cast<const short8*>(
                    sk + m * 64 + (((kk * 4 + kg) ^ (m & 7)) * 8));
                s4[ni] = __builtin_amdgcn_mfma_f32_16x16x32_bf16(a, bb, s4[ni], 0, 0, 0);
            }
        }
        float p[4][4];
#pragma unroll
        for (int r = 0; r < 4; ++r) {
            float v0 = s4[0][r] * SCALE, v1 = s4[1][r] * SCALE;
            float v2 = s4[2][r] * SCALE, v3 = s4[3][r] * SCALE;
            float mx = fmaxf(fmaxf(v0, v1), fmaxf(v2, v3));
            mx = fmaxf(mx, __shfl_xor(mx, 1));
            mx = fmaxf(mx, __shfl_xor(mx, 2));
            mx = fmaxf(mx, __shfl_xor(mx, 4));
            mx = fmaxf(mx, __shfl_xor(mx, 8));
            float e0 = __expf(v0 - mx), e1 = __expf(v1 - mx);
            float e2 = __expf(v2 - mx), e3 = __expf(v3 - mx);
            float sm = e0 + e1 + e2 + e3;
            sm += __shfl_xor(sm, 1);
            sm += __shfl_xor(sm, 2);
            sm += __shfl_xor(sm, 4);
            sm += __shfl_xor(sm, 8);
            float inv = 1.f / sm;
            p[0][r] = e0 * inv; p[1][r] = e1 * inv; p[2][r] = e2 * inv; p[3][r] = e3 * inv;
        }
#pragma unroll
        for (int ni = 0; ni < 4; ++ni)
#pragma unroll
            for (int r = 0; r < 4; ++r) {
                int m = ni * 16 + lr;
                int ll = w * 16 + kg * 4 + r;
                pt[m * 64 + (((ll >> 3) ^ (m & 7)) * 8) + (ll & 7)] = f2bf(p[ni][r]);
            }
#pragma unroll
        for (int j = 0; j < 2; ++j) {
            int d = w * 16 + j * 8 + (lane >> 3);
            int s = lane & 7;
            const short* src = vtb + ((size_t)(bh * 64 + d)) * 2048 + lt + ((s ^ (d & 7)) * 8);
            __builtin_amdgcn_global_load_lds(
                (const __attribute__((address_space(1))) void*)src,
                (__attribute__((address_space(3))) void*)(vt + (w * 16 + j * 8) * 64), 16, 0, 0);
        }
        __syncthreads();
#pragma unroll
        for (int kk = 0; kk < 2; ++kk) {
            int mm = w * 16 + lr;
            short8 a = *reinterpret_cast<const short8*>(
                pt + mm * 64 + (((kk * 4 + kg) ^ (mm & 7)) * 8));
#pragma unroll
            for (int ni = 0; ni < 4; ++ni) {
                int d = ni * 16 + lr;
                short8 bb = *reinterpret_cast<const short8*>(
                    vt + d * 64 + (((kk * 4 + kg) ^ (d & 7)) * 8));
                accw[ni] = __builtin_amdgcn_mfma_f32_16x16x32_bf16(a, bb, accw[ni], 0, 0, 0);
            }
        }
    }
#pragma unroll
    for (int ni = 0; ni < 4; ++ni)
#pragma unroll
        for (int r = 0; r < 4; ++r) {
            int m = w * 16 + kg * 4 + r;
            int d = ni * 16 + lr;
            wpart[((size_t)(ch * 32 + bh)) * 4096 + m * 64 + d] = accw[ni][r];
        }
}

// ---- reduce wpart chunks -> Wt global bf16, transposed + pre-swizzled ----
__global__ void k_wreduce(const float* __restrict__ wpart, short* __restrict__ wtg) {
    int i = blockIdx.x * 256 + threadIdx.x;  // 131072, grid 512
    float s = 0.f;
#pragma unroll
    for (int c = 0; c < 16; ++c) s += wpart[(size_t)c * 131072 + i];
    int bh = i >> 12, m = (i >> 6) & 63, d = i & 63;
    wtg[(size_t)bh * 4096 + d * 64 + (((m >> 3) ^ (d & 7)) * 8) + (m & 7)] = f2bf(s);
}

// ---- attO: S_q = q.selk^T (MFMA) -> softmax -> att = P1.W (MFMA) -> bf16 ----
__global__ __launch_bounds__(256) void k_attO(const short* __restrict__ qb,
                                              const short* __restrict__ selkb,
                                              const short* __restrict__ wtg,
                                              short* __restrict__ att) {
    __shared__ short sk[4096], wt[4096], qt[4096], p1[4096];
    int wg = blockIdx.x;
    int sw = (wg & 7) * 64 + (wg >> 3);
    int bh = sw & 31, ch = sw >> 5;
    int b = bh >> 4, h = bh & 15;
    int tid = threadIdx.x, w = tid >> 6, lane = tid & 63;
    int lr = lane & 15, kg = lane >> 4;

#pragma unroll
    for (int j = 0; j < 2; ++j) {
        int off = (w * 2 + j) * 512;
        __builtin_amdgcn_global_load_lds(
            (const __attribute__((address_space(1))) void*)(selkb + (size_t)bh * 4096 + off + lane * 8),
            (__attribute__((address_space(3))) void*)(sk + off), 16, 0, 0);
        __builtin_amdgcn_global_load_lds(
            (const __attribute__((address_space(1))) void*)(wtg + (size_t)bh * 4096 + off + lane * 8),
            (__attribute__((address_space(3))) void*)(wt + off), 16, 0, 0);
    }

    for (int t = 0; t < 2; ++t) {
        int lt = ch * 128 + t * 64;
#pragma unroll
        for (int j = 0; j < 2; ++j) {
            int r = w * 16 + j * 8 + (lane >> 3);
            int s = lane & 7;
            const short* src = qb + ((size_t)(b * L_ + lt + r)) * E_ + h * 64 + ((s ^ (r & 7)) * 8);
            __builtin_amdgcn_global_load_lds(
                (const __attribute__((address_space(1))) void*)src,
                (__attribute__((address_space(3))) void*)(qt + (w * 16 + j * 8) * 64), 16, 0, 0);
        }
        __syncthreads();

        f32x4 s4[4];
#pragma unroll
        for (int i = 0; i < 4; ++i) s4[i] = (f32x4){0.f, 0.f, 0.f, 0.f};
#pragma unroll
        for (int kk = 0; kk < 2; ++kk) {
            int row = w * 16 + lr;
            short8 a = *reinterpret_cast<const short8*>(
                qt + row * 64 + (((kk * 4 + kg) ^ (row & 7)) * 8));
#pragma unroll
            for (int ni = 0; ni < 4; ++ni) {
                int m = ni * 16 + lr;
                short8 bb = *reinterpret_cast<const short8*>(
                    sk + m * 64 + (((kk * 4 + kg) ^ (m & 7)) * 8));
                s4[ni] = __builtin_amdgcn_mfma_f32_16x16x32_bf16(a, bb, s4[ni], 0, 0, 0);
            }
        }
        float p[4][4];
#pragma unroll
        for (int r = 0; r < 4; ++r) {
            float v0 = s4[0][r] * SCALE, v1 = s4[1][r] * SCALE;
            float v2 = s4[2][r] * SCALE, v3 = s4[3][r] * SCALE;
            float mx = fmaxf(fmaxf(v0, v1), fmaxf(v2, v3));
            mx = fmaxf(mx, __shfl_xor(mx, 1));
            mx = fmaxf(mx, __shfl_xor(mx, 2));
            mx = fmaxf(mx, __shfl_xor(mx, 4));
            mx = fmaxf(mx, __shfl_xor(mx, 8));
            float e0 = __expf(v0 - mx), e1 = __expf(v1 - mx);
            float e2 = __expf(v2 - mx), e3 = __expf(v3 - mx);
            float sm = e0 + e1 + e2 + e3;
            sm += __shfl_xor(sm, 1);
            sm += __shfl_xor(sm, 2);
            sm += __shfl_xor(sm, 4);
            sm += __shfl_xor(sm, 8);
            float inv = 1.f / sm;
            p[0][r] = e0 * inv; p[1][r] = e1 * inv; p[2][r] = e2 * inv; p[3][r] = e3 * inv;
        }
#pragma unroll
        for (int ni = 0; ni < 4; ++ni)
#pragma unroll
            for (int r = 0; r < 4; ++r) {
                int m = ni * 16 + lr;
                int ll = w * 16 + kg * 4 + r;
                p1[ll * 64 + (((m >> 3) ^ (ll & 7)) * 8) + (m & 7)] = f2bf(p[ni][r]);
            }
        __syncthreads();
        f32x4 ao[4];
#pragma unroll
        for (int i = 0; i < 4; ++i) ao[i] = (f32x4){0.f, 0.f, 0.f, 0.f};
#pragma unroll
        for (int kk = 0; kk < 2; ++kk) {
            int row = w * 16 + lr;
            short8 a = *reinterpret_cast<const short8*>(
                p1 + row * 64 + (((kk * 4 + kg) ^ (row & 7)) * 8));
#pragma unroll
            for (int ni = 0; ni < 4; ++ni) {
                int d = ni * 16 + lr;
                short8 bb = *reinterpret_cast<const short8*>(
                    wt + d * 64 + (((kk * 4 + kg) ^ (d & 7)) * 8));
                ao[ni] = __builtin_amdgcn_mfma_f32_16x16x32_bf16(a, bb, ao[ni], 0, 0, 0);
            }
        }
#pragma unroll
        for (int ni = 0; ni < 4; ++ni)
#pragma unroll
            for (int r = 0; r < 4; ++r) {
                int l = lt + w * 16 + kg * 4 + r;
                int d = ni * 16 + lr;
                att[((size_t)(b * L_ + l)) * E_ + h * 64 + d] = f2bf(ao[ni][r]);
            }
    }
}

extern "C" void kernel_launch(void* const* d_in, const int* in_sizes, int n_in,
                              void* d_out, int out_size, void* d_ws, size_t ws_size,
                              hipStream_t stream) {
    const float* query = (const float*)d_in[0];
    const float* q_w = (const float*)d_in[1];
    const float* q_b = (const float*)d_in[2];
    const float* k_w = (const float*)d_in[3];
    const float* k_b = (const float*)d_in[4];
    const float* v_w = (const float*)d_in[5];
    const float* v_b = (const float*)d_in[6];
    const float* o_w = (const float*)d_in[7];
    const float* o_b = (const float*)d_in[8];
    float* out = (float*)d_out;

    char* p = (char*)d_ws;
    auto alloc = [&](size_t bytes) {
        char* r = p;
        p += (bytes + 255) & ~(size_t)255;
        return r;
    };
    short* xb    = (short*)alloc((size_t)MROWS * E_ * 2);
    short* qwb   = (short*)alloc((size_t)E_ * E_ * 2);
    short* kwb   = (short*)alloc((size_t)E_ * E_ * 2);
    short* vwb   = (short*)alloc((size_t)E_ * E_ * 2);
    short* owb   = (short*)alloc((size_t)E_ * E_ * 2);
    short* qbuf  = (short*)alloc((size_t)MROWS * E_ * 2);
    short* kbuf  = (short*)alloc((size_t)MROWS * E_ * 2);
    short* vbuf  = (short*)alloc((size_t)MROWS * E_ * 2);
    short* vtb   = (short*)alloc((size_t)32 * 64 * 2048 * 2);
    float* xpart = (float*)alloc((size_t)64 * B_ * E_ * 4);
    float* tb    = (float*)alloc((size_t)B_ * H_ * E_ * 4);
    float* scorp = (float*)alloc((size_t)4 * B_ * H_ * L_ * 4);
    short* selkb = (short*)alloc((size_t)32 * 4096 * 2);
    short* wtg   = (short*)alloc((size_t)32 * 4096 * 2);
    float* wpart = (float*)alloc((size_t)16 * 32 * 4096 * 4);
    short* att   = (short*)alloc((size_t)MROWS * E_ * 2);

    // stage 1: xsum-first merged prep; score path
    k_prep<<<8704, 256, 0, stream>>>(query, q_w, k_w, v_w, o_w, xb, qwb, kwb, vwb, owb, xpart);
    k_qt<<<32, 256, 0, stream>>>(xpart, q_w, q_b, k_w, tb);
    k_score<<<256, 256, 0, stream>>>(query, tb, scorp);

    // stage 2: fused q/k/v projections (dbuf 2-phase, 8 waves/block)
    k_gemm3<<<768, 512, 0, stream>>>(xb, qwb, kwb, vwb, q_b, k_b, v_b, qbuf, kbuf, vbuf);

    // stage 3: fused top-k gather + v transpose
    k_sel<<<1032, 256, 0, stream>>>(scorp, kbuf, vbuf, selkb, vtb);

    // stage 4: MFMA attention core
    k_attW<<<512, 256, 0, stream>>>(kbuf, vtb, selkb, wpart);
    k_wreduce<<<512, 256, 0, stream>>>(wpart, wtg);
    k_attO<<<512, 256, 0, stream>>>(qbuf, selkb, wtg, att);

    // stage 5: o-projection fused with bias + residual + transpose back
    k_gemmo<<<512, 512, 0, stream>>>(att, owb, o_b, out, query);
}